// Round 1
// baseline (405.334 us; speedup 1.0000x reference)
//
#include <hip/hip_runtime.h>
#include <math.h>

#define IMG_B 16
#define IMG_H 512
#define IMG_W 512
#define IMG_HW (IMG_H * IMG_W)

struct Scal {
    double simsum;                 // similarity accumulator
    double area[IMG_B];            // per-sample sum of pred
    unsigned gmag_min, gmag_max;   // order-encoded float atomics
    unsigned dem_min, dem_max;
    int fgcnt[IMG_B];              // per-sample foreground pixel count
    int maxcnt[IMG_B];             // per-sample largest component size
};

// monotone order-preserving float<->uint encoding for atomicMin/Max on floats
__device__ __forceinline__ unsigned f2ord(float f) {
    unsigned u = __float_as_uint(f);
    return (u & 0x80000000u) ? ~u : (u | 0x80000000u);
}
__device__ __forceinline__ float ord2f(unsigned u) {
    return __uint_as_float((u & 0x80000000u) ? (u & 0x7FFFFFFFu) : ~u);
}

__global__ void k_init_scal(Scal* s) {
    if (threadIdx.x == 0) {
        s->simsum = 0.0;
        s->gmag_min = 0xFFFFFFFFu; s->gmag_max = 0u;
        s->dem_min  = 0xFFFFFFFFu; s->dem_max  = 0u;
    }
    if (threadIdx.x < IMG_B) {
        s->area[threadIdx.x] = 0.0;
        s->fgcnt[threadIdx.x] = 0;
        s->maxcnt[threadIdx.x] = 0;
    }
}

// Pass 1: gmag min/max, dem min/max (global), per-sample area + fg count.
// grid (128, B), block 256, 8 px/thread (2048 px per block, contiguous).
__global__ void k_feat_reduce(const float* __restrict__ dem,
                              const float* __restrict__ pred, Scal* s) {
    const int b = blockIdx.y;
    const float* d = dem + (size_t)b * IMG_HW;
    const float* p = pred + (size_t)b * IMG_HW;
    float gmn = __FLT_MAX__, gmx = -__FLT_MAX__;
    float dmn = __FLT_MAX__, dmx = -__FLT_MAX__;
    double ar = 0.0; int fg = 0;
    const int base = blockIdx.x * 2048 + threadIdx.x;
#pragma unroll
    for (int k = 0; k < 8; ++k) {
        const int i = base + k * 256;
        const int y = i >> 9, x = i & 511;
        const float d11 = d[i];
        const float d00 = (y > 0 && x > 0)                 ? d[i - IMG_W - 1] : 0.f;
        const float d01 = (y > 0)                          ? d[i - IMG_W]     : 0.f;
        const float d02 = (y > 0 && x < IMG_W - 1)         ? d[i - IMG_W + 1] : 0.f;
        const float d10 = (x > 0)                          ? d[i - 1]         : 0.f;
        const float d12 = (x < IMG_W - 1)                  ? d[i + 1]         : 0.f;
        const float d20 = (y < IMG_H - 1 && x > 0)         ? d[i + IMG_W - 1] : 0.f;
        const float d21 = (y < IMG_H - 1)                  ? d[i + IMG_W]     : 0.f;
        const float d22 = (y < IMG_H - 1 && x < IMG_W - 1) ? d[i + IMG_W + 1] : 0.f;
        const float gx = (d02 - d00) + 2.f * (d12 - d10) + (d22 - d20);
        const float gy = (d20 - d00) + 2.f * (d21 - d01) + (d22 - d02);
        const float gm = sqrtf(gx * gx + gy * gy + 1e-8f);
        gmn = fminf(gmn, gm); gmx = fmaxf(gmx, gm);
        dmn = fminf(dmn, d11); dmx = fmaxf(dmx, d11);
        const float pv = p[i];
        ar += (double)pv; fg += (pv > 0.5f) ? 1 : 0;
    }
    for (int o = 32; o > 0; o >>= 1) {
        gmn = fminf(gmn, __shfl_down(gmn, o));
        gmx = fmaxf(gmx, __shfl_down(gmx, o));
        dmn = fminf(dmn, __shfl_down(dmn, o));
        dmx = fmaxf(dmx, __shfl_down(dmx, o));
        ar += __shfl_down(ar, o);
        fg += __shfl_down(fg, o);
    }
    __shared__ float sg0[4], sg1[4], sd0[4], sd1[4];
    __shared__ double sa[4];
    __shared__ int sf[4];
    const int wid = threadIdx.x >> 6, lane = threadIdx.x & 63;
    if (lane == 0) { sg0[wid] = gmn; sg1[wid] = gmx; sd0[wid] = dmn; sd1[wid] = dmx; sa[wid] = ar; sf[wid] = fg; }
    __syncthreads();
    if (threadIdx.x == 0) {
        for (int w = 1; w < 4; ++w) {
            gmn = fminf(gmn, sg0[w]); gmx = fmaxf(gmx, sg1[w]);
            dmn = fminf(dmn, sd0[w]); dmx = fmaxf(dmx, sd1[w]);
            ar += sa[w]; fg += sf[w];
        }
        atomicMin(&s->gmag_min, f2ord(gmn));
        atomicMax(&s->gmag_max, f2ord(gmx));
        atomicMin(&s->dem_min, f2ord(dmn));
        atomicMax(&s->dem_max, f2ord(dmx));
        atomicAdd(&s->area[b], ar);
        atomicAdd(&s->fgcnt[b], fg);
    }
}

// ---- connected components: lock-free union-find (4-connectivity) ----
__device__ __forceinline__ int uf_find(const int* L, int x) {
    int p = L[x];
    while (p != x) { x = p; p = L[x]; }   // parents only ever decrease -> terminates
    return x;
}
__device__ void uf_merge(int* L, int a, int b) {
    while (true) {
        a = uf_find(L, a);
        b = uf_find(L, b);
        if (a == b) return;
        if (a < b) { int t = a; a = b; b = t; }  // a > b
        const int old = atomicMin(&L[a], b);
        if (old == a) return;  // a was root and is now linked to b
        a = old;               // someone else linked a; merge its old parent with b
    }
}

// grid (1024, nimg), block 256. labels chunk-local (img slot = blockIdx.y).
__global__ void k_ccl_init(const float* __restrict__ pred, int* __restrict__ labels, int b0) {
    const int img = blockIdx.y;
    const int i = blockIdx.x * 256 + threadIdx.x;
    const float pv = pred[((size_t)(b0 + img)) * IMG_HW + i];
    labels[(size_t)img * IMG_HW + i] = (pv > 0.5f) ? i : -1;
}

__global__ void k_ccl_merge(int* __restrict__ labels) {
    const int img = blockIdx.y;
    const int i = blockIdx.x * 256 + threadIdx.x;
    int* L = labels + (size_t)img * IMG_HW;
    if (L[i] < 0) return;
    const int x = i & 511;
    if (x < IMG_W - 1 && L[i + 1] >= 0) uf_merge(L, i, i + 1);
    if (i + IMG_W < IMG_HW && L[i + IMG_W] >= 0) uf_merge(L, i, i + IMG_W);
}

__global__ void k_ccl_count(const int* __restrict__ labels, int* __restrict__ counts) {
    const int img = blockIdx.y;
    const int i = blockIdx.x * 256 + threadIdx.x;
    const int* L = labels + (size_t)img * IMG_HW;
    if (L[i] < 0) return;
    const int r = uf_find(L, i);
    atomicAdd(&counts[(size_t)img * IMG_HW + r], 1);
}

// grid (128, nimg), block 256, 8 elems/thread
__global__ void k_ccl_max(const int* __restrict__ counts, Scal* s, int b0) {
    const int img = blockIdx.y;
    const int* C = counts + (size_t)img * IMG_HW;
    const int base = blockIdx.x * 2048 + threadIdx.x;
    int m = 0;
#pragma unroll
    for (int k = 0; k < 8; ++k) m = max(m, C[base + k * 256]);
    for (int o = 32; o > 0; o >>= 1) m = max(m, __shfl_down(m, o));
    __shared__ int sm[4];
    const int wid = threadIdx.x >> 6, lane = threadIdx.x & 63;
    if (lane == 0) sm[wid] = m;
    __syncthreads();
    if (threadIdx.x == 0) {
        for (int w = 1; w < 4; ++w) m = max(m, sm[w]);
        atomicMax(&s->maxcnt[b0 + img], m);
    }
}

// Pass 2: similarity MSE using global min/max from pass 1.
__global__ void k_sim(const float* __restrict__ dem,
                      const float* __restrict__ pred, Scal* s) {
    const int b = blockIdx.y;
    const float* d = dem + (size_t)b * IMG_HW;
    const float* p = pred + (size_t)b * IMG_HW;
    const float gmin = ord2f(s->gmag_min), gmax = ord2f(s->gmag_max);
    const float dmin = ord2f(s->dem_min),  dmax = ord2f(s->dem_max);
    const float gden = gmax - gmin + 1e-8f;
    const float dden = dmax - dmin + 1e-8f;
    double acc = 0.0;
    const int base = blockIdx.x * 2048 + threadIdx.x;
#pragma unroll
    for (int k = 0; k < 8; ++k) {
        const int i = base + k * 256;
        const int y = i >> 9, x = i & 511;
        const float d11 = d[i];
        const float d00 = (y > 0 && x > 0)                 ? d[i - IMG_W - 1] : 0.f;
        const float d01 = (y > 0)                          ? d[i - IMG_W]     : 0.f;
        const float d02 = (y > 0 && x < IMG_W - 1)         ? d[i - IMG_W + 1] : 0.f;
        const float d10 = (x > 0)                          ? d[i - 1]         : 0.f;
        const float d12 = (x < IMG_W - 1)                  ? d[i + 1]         : 0.f;
        const float d20 = (y < IMG_H - 1 && x > 0)         ? d[i + IMG_W - 1] : 0.f;
        const float d21 = (y < IMG_H - 1)                  ? d[i + IMG_W]     : 0.f;
        const float d22 = (y < IMG_H - 1 && x < IMG_W - 1) ? d[i + IMG_W + 1] : 0.f;
        const float gx = (d02 - d00) + 2.f * (d12 - d10) + (d22 - d20);
        const float gy = (d20 - d00) + 2.f * (d21 - d01) + (d22 - d02);
        const float gm = sqrtf(gx * gx + gy * gy + 1e-8f);
        const float lap = d01 + d10 + d12 + d21 - 4.f * d11;
        const float gn = (gm - gmin) / gden;
        const float hn = (d11 - dmin) / dden;
        const float cv = tanhf(lap * 0.1f);
        const float pv = p[i];
        const float e0 = pv - gn, e1 = pv - hn, e2 = pv - cv;
        acc += (double)(e0 * e0) + (double)(e1 * e1) + (double)(e2 * e2);
    }
    for (int o = 32; o > 0; o >>= 1) acc += __shfl_down(acc, o);
    __shared__ double sa[4];
    const int wid = threadIdx.x >> 6, lane = threadIdx.x & 63;
    if (lane == 0) sa[wid] = acc;
    __syncthreads();
    if (threadIdx.x == 0) {
        for (int w = 1; w < 4; ++w) acc += sa[w];
        atomicAdd(&s->simsum, acc);
    }
}

__global__ void k_final(const Scal* __restrict__ s, float* __restrict__ out) {
    const double tp = (double)IMG_HW;
    const double tmin = 0.1 * tp, tmax = 0.3 * tp;
    const double sim = s->simsum / ((double)IMG_B * 3.0 * (double)IMG_HW);
    double conn = 0.0, scale = 0.0;
    for (int b = 0; b < IMG_B; ++b) {
        const int total = s->fgcnt[b];
        if (total > 0) conn += 1.0 - (double)s->maxcnt[b] / (double)total;
        const double a = s->area[b];
        scale += fmax(a - tmax, 0.0) + fmax(tmin - a, 0.0);
    }
    conn /= (double)IMG_B;
    scale = (scale / (double)IMG_B) / tp;
    const double total = sim + 0.1 * conn + 0.05 * scale;
    out[0] = (float)(0.1 * total);
}

extern "C" void kernel_launch(void* const* d_in, const int* in_sizes, int n_in,
                              void* d_out, int out_size, void* d_ws, size_t ws_size,
                              hipStream_t stream) {
    const float* pred = (const float*)d_in[0];  // [16,1,512,512]
    const float* dem  = (const float*)d_in[1];  // [16,1,512,512]
    float* out = (float*)d_out;

    char* ws = (char*)d_ws;
    Scal* s = (Scal*)ws;
    int* scratch = (int*)(ws + 512);
    const size_t avail = (ws_size > 512) ? ws_size - 512 : 0;
    long long chunk = (long long)(avail / (2ull * IMG_HW * 4ull));  // labels + counts per image
    if (chunk < 1) chunk = 1;
    if (chunk > IMG_B) chunk = IMG_B;

    hipLaunchKernelGGL(k_init_scal, dim3(1), dim3(64), 0, stream, s);
    hipLaunchKernelGGL(k_feat_reduce, dim3(128, IMG_B), dim3(256), 0, stream, dem, pred, s);

    for (int b0 = 0; b0 < IMG_B; b0 += (int)chunk) {
        const int n = (int)((b0 + chunk <= IMG_B) ? chunk : (IMG_B - b0));
        int* labels = scratch;
        int* counts = scratch + (size_t)chunk * IMG_HW;
        hipMemsetAsync(counts, 0, (size_t)n * IMG_HW * sizeof(int), stream);
        hipLaunchKernelGGL(k_ccl_init,  dim3(1024, n), dim3(256), 0, stream, pred, labels, b0);
        hipLaunchKernelGGL(k_ccl_merge, dim3(1024, n), dim3(256), 0, stream, labels);
        hipLaunchKernelGGL(k_ccl_count, dim3(1024, n), dim3(256), 0, stream, labels, counts);
        hipLaunchKernelGGL(k_ccl_max,   dim3(128, n),  dim3(256), 0, stream, counts, s, b0);
    }

    hipLaunchKernelGGL(k_sim, dim3(128, IMG_B), dim3(256), 0, stream, dem, pred, s);
    hipLaunchKernelGGL(k_final, dim3(1), dim3(1), 0, stream, s, out);
}

// Round 2
// 361.381 us; speedup vs baseline: 1.1216x; 1.1216x over previous
//
#include <hip/hip_runtime.h>
#include <math.h>

#define IMG_B 16
#define IMG_H 512
#define IMG_W 512
#define IMG_HW (IMG_H * IMG_W)

struct Scal {
    double simsum;
    double area[IMG_B];
    unsigned gmag_min, gmag_max, dem_min, dem_max;
    int fgcnt[IMG_B];
    int maxcnt[IMG_B];
};

__device__ __forceinline__ unsigned f2ord(float f) {
    unsigned u = __float_as_uint(f);
    return (u & 0x80000000u) ? ~u : (u | 0x80000000u);
}
__device__ __forceinline__ float ord2f(unsigned u) {
    return __uint_as_float((u & 0x80000000u) ? (u & 0x7FFFFFFFu) : ~u);
}

__global__ void k_init_scal(Scal* s) {
    if (threadIdx.x == 0) {
        s->simsum = 0.0;
        s->gmag_min = 0xFFFFFFFFu; s->gmag_max = 0u;
        s->dem_min  = 0xFFFFFFFFu; s->dem_max  = 0u;
    }
    if (threadIdx.x < IMG_B) {
        s->area[threadIdx.x] = 0.0;
        s->fgcnt[threadIdx.x] = 0;
        s->maxcnt[threadIdx.x] = 0;
    }
}

// Pass 1: fused stencil-reduce + CCL label init + counts zeroing.
// grid (128, B), block 256. Thread handles 8 contiguous px (one partial row).
__global__ void k_feat(const float* __restrict__ dem, const float* __restrict__ pred,
                       int* __restrict__ labels, int* __restrict__ counts, Scal* s) {
    const int b = blockIdx.y;
    const size_t off = (size_t)b * IMG_HW;
    const float* d = dem + off;
    const float* p = pred + off;
    const int base = blockIdx.x * 2048 + threadIdx.x * 8;
    const int y = base >> 9, x0 = base & 511;

    const float4 z4 = make_float4(0.f, 0.f, 0.f, 0.f);
    float4 m0 = *(const float4*)(d + base);
    float4 m1 = *(const float4*)(d + base + 4);
    float4 u0 = z4, u1 = z4, w0 = z4, w1 = z4;
    if (y > 0)         { u0 = *(const float4*)(d + base - 512); u1 = *(const float4*)(d + base - 508); }
    if (y < IMG_H - 1) { w0 = *(const float4*)(d + base + 512); w1 = *(const float4*)(d + base + 516); }

    float uu[10], mm[10], ww[10];
    mm[0] = (x0 > 0)              ? d[base - 1]   : 0.f;
    mm[9] = (x0 != 504)           ? d[base + 8]   : 0.f;
    uu[0] = (y > 0 && x0 > 0)     ? d[base - 513] : 0.f;
    uu[9] = (y > 0 && x0 != 504)  ? d[base - 504] : 0.f;
    ww[0] = (y < 511 && x0 > 0)   ? d[base + 511] : 0.f;
    ww[9] = (y < 511 && x0 != 504)? d[base + 520] : 0.f;
    uu[1]=u0.x; uu[2]=u0.y; uu[3]=u0.z; uu[4]=u0.w; uu[5]=u1.x; uu[6]=u1.y; uu[7]=u1.z; uu[8]=u1.w;
    mm[1]=m0.x; mm[2]=m0.y; mm[3]=m0.z; mm[4]=m0.w; mm[5]=m1.x; mm[6]=m1.y; mm[7]=m1.z; mm[8]=m1.w;
    ww[1]=w0.x; ww[2]=w0.y; ww[3]=w0.z; ww[4]=w0.w; ww[5]=w1.x; ww[6]=w1.y; ww[7]=w1.z; ww[8]=w1.w;

    const float4 p0 = *(const float4*)(p + base);
    const float4 p1 = *(const float4*)(p + base + 4);
    const float pv[8] = {p0.x, p0.y, p0.z, p0.w, p1.x, p1.y, p1.z, p1.w};

    float gmn = 3.4e38f, gmx = -3.4e38f, dmn = 3.4e38f, dmx = -3.4e38f;
    double ar = 0.0; int fg = 0;
    int lab[8];
#pragma unroll
    for (int j = 0; j < 8; ++j) {
        const float gx = (uu[j+2] - uu[j]) + 2.f * (mm[j+2] - mm[j]) + (ww[j+2] - ww[j]);
        const float gy = (ww[j] - uu[j]) + 2.f * (ww[j+1] - uu[j+1]) + (ww[j+2] - uu[j+2]);
        const float gm = sqrtf(gx * gx + gy * gy + 1e-8f);
        gmn = fminf(gmn, gm); gmx = fmaxf(gmx, gm);
        dmn = fminf(dmn, mm[j+1]); dmx = fmaxf(dmx, mm[j+1]);
        ar += (double)pv[j];
        const bool f = pv[j] > 0.5f;
        fg += f ? 1 : 0;
        lab[j] = f ? (base + j) : -1;
    }
    if (labels) {
        int* Lb = labels + off;
        int* Cb = counts + off;
        *(int4*)(Lb + base)     = make_int4(lab[0], lab[1], lab[2], lab[3]);
        *(int4*)(Lb + base + 4) = make_int4(lab[4], lab[5], lab[6], lab[7]);
        const int4 zi = make_int4(0, 0, 0, 0);
        *(int4*)(Cb + base) = zi; *(int4*)(Cb + base + 4) = zi;
    }

    for (int o = 32; o > 0; o >>= 1) {
        gmn = fminf(gmn, __shfl_down(gmn, o));
        gmx = fmaxf(gmx, __shfl_down(gmx, o));
        dmn = fminf(dmn, __shfl_down(dmn, o));
        dmx = fmaxf(dmx, __shfl_down(dmx, o));
        ar += __shfl_down(ar, o);
        fg += __shfl_down(fg, o);
    }
    __shared__ float sg0[4], sg1[4], sd0[4], sd1[4];
    __shared__ double sa[4];
    __shared__ int sf[4];
    const int wid = threadIdx.x >> 6, lane = threadIdx.x & 63;
    if (lane == 0) { sg0[wid] = gmn; sg1[wid] = gmx; sd0[wid] = dmn; sd1[wid] = dmx; sa[wid] = ar; sf[wid] = fg; }
    __syncthreads();
    if (threadIdx.x == 0) {
        for (int w = 1; w < 4; ++w) {
            gmn = fminf(gmn, sg0[w]); gmx = fmaxf(gmx, sg1[w]);
            dmn = fminf(dmn, sd0[w]); dmx = fmaxf(dmx, sd1[w]);
            ar += sa[w]; fg += sf[w];
        }
        atomicMin(&s->gmag_min, f2ord(gmn));
        atomicMax(&s->gmag_max, f2ord(gmx));
        atomicMin(&s->dem_min, f2ord(dmn));
        atomicMax(&s->dem_max, f2ord(dmx));
        atomicAdd(&s->area[b], ar);
        atomicAdd(&s->fgcnt[b], fg);
    }
}

// ---- union-find ----
__device__ __forceinline__ int uf_findv(const int* L, int p) {
    while (true) { const int q = L[p]; if (q == p) return p; p = q; }
}
__device__ void uf_merge(int* L, int a, int b) {
    while (true) {
        a = uf_findv(L, a);
        b = uf_findv(L, b);
        if (a == b) return;
        if (a < b) { int t = a; a = b; b = t; }
        const int old = atomicMin(&L[a], b);
        if (old == a) return;
        a = old;
    }
}

// fallback path only (small ws): label init
__global__ void k_ccl_init(const float* __restrict__ pred, int* __restrict__ labels, int b0) {
    const int img = blockIdx.y;
    const int i = (blockIdx.x * 256 + threadIdx.x) * 4;
    const float4 pv = *(const float4*)(pred + (size_t)(b0 + img) * IMG_HW + i);
    *(int4*)(labels + (size_t)img * IMG_HW + i) =
        make_int4(pv.x > 0.5f ? i : -1, pv.y > 0.5f ? i + 1 : -1,
                  pv.z > 0.5f ? i + 2 : -1, pv.w > 0.5f ? i + 3 : -1);
}

// grid (256, nimg), block 256, 4 px/thread
__global__ void k_merge(int* __restrict__ labels) {
    const int img = blockIdx.y;
    int* L = labels + (size_t)img * IMG_HW;
    const int i = (blockIdx.x * 256 + threadIdx.x) * 4;
    const int4 v = *(const int4*)(L + i);
    const int x0 = i & 511, y = i >> 9;
    if (v.x >= 0 && v.y >= 0) uf_merge(L, i, i + 1);
    if (v.y >= 0 && v.z >= 0) uf_merge(L, i + 1, i + 2);
    if (v.z >= 0 && v.w >= 0) uf_merge(L, i + 2, i + 3);
    if (x0 != 508 && v.w >= 0 && L[i + 4] >= 0) uf_merge(L, i + 3, i + 4);
    if (y < IMG_H - 1) {
        const int4 dn = *(const int4*)(L + i + 512);
        if (v.x >= 0 && dn.x >= 0) uf_merge(L, i,     i + 512);
        if (v.y >= 0 && dn.y >= 0) uf_merge(L, i + 1, i + 513);
        if (v.z >= 0 && dn.z >= 0) uf_merge(L, i + 2, i + 514);
        if (v.w >= 0 && dn.w >= 0) uf_merge(L, i + 3, i + 515);
    }
}

// grid (256, nimg), block 256, 4 px/thread; run-combined atomics
__global__ void k_count(const int* __restrict__ labels, int* __restrict__ counts) {
    const int img = blockIdx.y;
    const int* L = labels + (size_t)img * IMG_HW;
    int* C = counts + (size_t)img * IMG_HW;
    const int i = (blockIdx.x * 256 + threadIdx.x) * 4;
    const int4 v = *(const int4*)(L + i);
    int r[4];
    r[0] = v.x >= 0 ? uf_findv(L, v.x) : -1;
    r[1] = v.y >= 0 ? uf_findv(L, v.y) : -1;
    r[2] = v.z >= 0 ? uf_findv(L, v.z) : -1;
    r[3] = v.w >= 0 ? uf_findv(L, v.w) : -1;
    int prev = -1, cnt = 0;
#pragma unroll
    for (int j = 0; j < 4; ++j) {
        if (r[j] == prev) { ++cnt; }
        else {
            if (prev >= 0) atomicAdd(&C[prev], cnt);
            prev = r[j]; cnt = 1;
        }
    }
    if (prev >= 0) atomicAdd(&C[prev], cnt);
}

// grid (128, nimg), block 256, 8 elems/thread
__global__ void k_max(const int* __restrict__ counts, Scal* s, int b0) {
    const int img = blockIdx.y;
    const int* C = counts + (size_t)img * IMG_HW;
    const int i = (blockIdx.x * 256 + threadIdx.x) * 8;
    const int4 a = *(const int4*)(C + i);
    const int4 c = *(const int4*)(C + i + 4);
    int m = max(max(max(a.x, a.y), max(a.z, a.w)), max(max(c.x, c.y), max(c.z, c.w)));
    for (int o = 32; o > 0; o >>= 1) m = max(m, __shfl_down(m, o));
    __shared__ int sm[4];
    const int wid = threadIdx.x >> 6, lane = threadIdx.x & 63;
    if (lane == 0) sm[wid] = m;
    __syncthreads();
    if (threadIdx.x == 0) {
        for (int w = 1; w < 4; ++w) m = max(m, sm[w]);
        atomicMax(&s->maxcnt[b0 + img], m);
    }
}

// Pass 2: similarity MSE (needs global min/max from pass 1)
__global__ void k_sim(const float* __restrict__ dem, const float* __restrict__ pred, Scal* s) {
    const int b = blockIdx.y;
    const size_t off = (size_t)b * IMG_HW;
    const float* d = dem + off;
    const float* p = pred + off;
    const float gmin = ord2f(s->gmag_min), gmax = ord2f(s->gmag_max);
    const float dmin = ord2f(s->dem_min),  dmax = ord2f(s->dem_max);
    const float gden = gmax - gmin + 1e-8f;
    const float dden = dmax - dmin + 1e-8f;
    const int base = blockIdx.x * 2048 + threadIdx.x * 8;
    const int y = base >> 9, x0 = base & 511;

    const float4 z4 = make_float4(0.f, 0.f, 0.f, 0.f);
    float4 m0 = *(const float4*)(d + base);
    float4 m1 = *(const float4*)(d + base + 4);
    float4 u0 = z4, u1 = z4, w0 = z4, w1 = z4;
    if (y > 0)         { u0 = *(const float4*)(d + base - 512); u1 = *(const float4*)(d + base - 508); }
    if (y < IMG_H - 1) { w0 = *(const float4*)(d + base + 512); w1 = *(const float4*)(d + base + 516); }

    float uu[10], mm[10], ww[10];
    mm[0] = (x0 > 0)              ? d[base - 1]   : 0.f;
    mm[9] = (x0 != 504)           ? d[base + 8]   : 0.f;
    uu[0] = (y > 0 && x0 > 0)     ? d[base - 513] : 0.f;
    uu[9] = (y > 0 && x0 != 504)  ? d[base - 504] : 0.f;
    ww[0] = (y < 511 && x0 > 0)   ? d[base + 511] : 0.f;
    ww[9] = (y < 511 && x0 != 504)? d[base + 520] : 0.f;
    uu[1]=u0.x; uu[2]=u0.y; uu[3]=u0.z; uu[4]=u0.w; uu[5]=u1.x; uu[6]=u1.y; uu[7]=u1.z; uu[8]=u1.w;
    mm[1]=m0.x; mm[2]=m0.y; mm[3]=m0.z; mm[4]=m0.w; mm[5]=m1.x; mm[6]=m1.y; mm[7]=m1.z; mm[8]=m1.w;
    ww[1]=w0.x; ww[2]=w0.y; ww[3]=w0.z; ww[4]=w0.w; ww[5]=w1.x; ww[6]=w1.y; ww[7]=w1.z; ww[8]=w1.w;

    const float4 p0 = *(const float4*)(p + base);
    const float4 p1 = *(const float4*)(p + base + 4);
    const float pv[8] = {p0.x, p0.y, p0.z, p0.w, p1.x, p1.y, p1.z, p1.w};

    double acc = 0.0;
#pragma unroll
    for (int j = 0; j < 8; ++j) {
        const float gx = (uu[j+2] - uu[j]) + 2.f * (mm[j+2] - mm[j]) + (ww[j+2] - ww[j]);
        const float gy = (ww[j] - uu[j]) + 2.f * (ww[j+1] - uu[j+1]) + (ww[j+2] - uu[j+2]);
        const float gm = sqrtf(gx * gx + gy * gy + 1e-8f);
        const float lap = uu[j+1] + mm[j] + mm[j+2] + ww[j+1] - 4.f * mm[j+1];
        const float gn = (gm - gmin) / gden;
        const float hn = (mm[j+1] - dmin) / dden;
        const float cv = tanhf(lap * 0.1f);
        const float e0 = pv[j] - gn, e1 = pv[j] - hn, e2 = pv[j] - cv;
        acc += (double)(e0 * e0) + (double)(e1 * e1) + (double)(e2 * e2);
    }
    for (int o = 32; o > 0; o >>= 1) acc += __shfl_down(acc, o);
    __shared__ double sa[4];
    const int wid = threadIdx.x >> 6, lane = threadIdx.x & 63;
    if (lane == 0) sa[wid] = acc;
    __syncthreads();
    if (threadIdx.x == 0) {
        for (int w = 1; w < 4; ++w) acc += sa[w];
        atomicAdd(&s->simsum, acc);
    }
}

__global__ void k_final(const Scal* __restrict__ s, float* __restrict__ out) {
    const double tp = (double)IMG_HW;
    const double tmin = 0.1 * tp, tmax = 0.3 * tp;
    const double sim = s->simsum / ((double)IMG_B * 3.0 * (double)IMG_HW);
    double conn = 0.0, scale = 0.0;
    for (int b = 0; b < IMG_B; ++b) {
        const int total = s->fgcnt[b];
        if (total > 0) conn += 1.0 - (double)s->maxcnt[b] / (double)total;
        const double a = s->area[b];
        scale += fmax(a - tmax, 0.0) + fmax(tmin - a, 0.0);
    }
    conn /= (double)IMG_B;
    scale = (scale / (double)IMG_B) / tp;
    const double total = sim + 0.1 * conn + 0.05 * scale;
    out[0] = (float)(0.1 * total);
}

extern "C" void kernel_launch(void* const* d_in, const int* in_sizes, int n_in,
                              void* d_out, int out_size, void* d_ws, size_t ws_size,
                              hipStream_t stream) {
    const float* pred = (const float*)d_in[0];  // [16,1,512,512]
    const float* dem  = (const float*)d_in[1];  // [16,1,512,512]
    float* out = (float*)d_out;

    char* ws = (char*)d_ws;
    Scal* s = (Scal*)ws;
    int* scratch = (int*)(ws + 512);
    const size_t avail = (ws_size > 512) ? ws_size - 512 : 0;
    const size_t need_full = 2ull * IMG_B * IMG_HW * 4ull;  // labels + counts, all images

    hipLaunchKernelGGL(k_init_scal, dim3(1), dim3(64), 0, stream, s);

    if (avail >= need_full) {
        int* labels = scratch;
        int* counts = scratch + (size_t)IMG_B * IMG_HW;
        hipLaunchKernelGGL(k_feat,  dim3(128, IMG_B), dim3(256), 0, stream, dem, pred, labels, counts, s);
        hipLaunchKernelGGL(k_merge, dim3(256, IMG_B), dim3(256), 0, stream, labels);
        hipLaunchKernelGGL(k_count, dim3(256, IMG_B), dim3(256), 0, stream, labels, counts);
        hipLaunchKernelGGL(k_max,   dim3(128, IMG_B), dim3(256), 0, stream, counts, s, 0);
    } else {
        hipLaunchKernelGGL(k_feat, dim3(128, IMG_B), dim3(256), 0, stream, dem, pred,
                           (int*)nullptr, (int*)nullptr, s);
        long long chunk = (long long)(avail / (2ull * IMG_HW * 4ull));
        if (chunk < 1) chunk = 1;
        if (chunk > IMG_B) chunk = IMG_B;
        for (int b0 = 0; b0 < IMG_B; b0 += (int)chunk) {
            const int n = (int)((b0 + chunk <= IMG_B) ? chunk : (IMG_B - b0));
            int* labels = scratch;
            int* counts = scratch + (size_t)chunk * IMG_HW;
            hipMemsetAsync(counts, 0, (size_t)n * IMG_HW * sizeof(int), stream);
            hipLaunchKernelGGL(k_ccl_init, dim3(256, n), dim3(256), 0, stream, pred, labels, b0);
            hipLaunchKernelGGL(k_merge,    dim3(256, n), dim3(256), 0, stream, labels);
            hipLaunchKernelGGL(k_count,    dim3(256, n), dim3(256), 0, stream, labels, counts);
            hipLaunchKernelGGL(k_max,      dim3(128, n), dim3(256), 0, stream, counts, s, b0);
        }
    }

    hipLaunchKernelGGL(k_sim, dim3(128, IMG_B), dim3(256), 0, stream, dem, pred, s);
    hipLaunchKernelGGL(k_final, dim3(1), dim3(1), 0, stream, s, out);
}

// Round 3
// 251.646 us; speedup vs baseline: 1.6107x; 1.4361x over previous
//
#include <hip/hip_runtime.h>
#include <math.h>

#define IMG_B 16
#define IMG_H 512
#define IMG_W 512
#define IMG_HW (IMG_H * IMG_W)
#define NPART 2048            // 128 blocks/image * 16 images

struct Scal {
    float gmin, gmax, dmin, dmax;   // global gmag / dem min-max
    double area[IMG_B];
    int fgcnt[IMG_B];
    int maxcnt[IMG_B];
};

// ws layout (bytes):
//   0      Scal (padded to 512)
//   512    float4 pmm[NPART]   (32768)   per-block {gmn,gmx,dmn,dmx}
//   33280  double parea[NPART] (16384)
//   49664  int    pfg[NPART]   (8192)
//   57856  double psim[NPART]  (16384)
//   74240  int scratch: labels / counts
#define OFF_PMM   512
#define OFF_AREA  33280
#define OFF_FG    49664
#define OFF_SIM   57856
#define OFF_SCR   74240

__global__ void k_init_scal(Scal* s) {
    if (threadIdx.x < IMG_B) {
        s->area[threadIdx.x] = 0.0;
        s->fgcnt[threadIdx.x] = 0;
        s->maxcnt[threadIdx.x] = 0;
    }
}

// Pass 1: fused stencil-reduce + CCL label init + counts zeroing.
// grid (128, B), block 256. Thread handles 8 contiguous px. NO global atomics:
// per-block partials are plain-stored to scratch.
__global__ void k_feat(const float* __restrict__ dem, const float* __restrict__ pred,
                       int* __restrict__ labels, int* __restrict__ counts,
                       float4* __restrict__ pmm, double* __restrict__ parea,
                       int* __restrict__ pfg) {
    const int b = blockIdx.y;
    const size_t off = (size_t)b * IMG_HW;
    const float* d = dem + off;
    const float* p = pred + off;
    const int base = blockIdx.x * 2048 + threadIdx.x * 8;
    const int y = base >> 9, x0 = base & 511;

    const float4 z4 = make_float4(0.f, 0.f, 0.f, 0.f);
    float4 m0 = *(const float4*)(d + base);
    float4 m1 = *(const float4*)(d + base + 4);
    float4 u0 = z4, u1 = z4, w0 = z4, w1 = z4;
    if (y > 0)         { u0 = *(const float4*)(d + base - 512); u1 = *(const float4*)(d + base - 508); }
    if (y < IMG_H - 1) { w0 = *(const float4*)(d + base + 512); w1 = *(const float4*)(d + base + 516); }

    float uu[10], mm[10], ww[10];
    mm[0] = (x0 > 0)              ? d[base - 1]   : 0.f;
    mm[9] = (x0 != 504)           ? d[base + 8]   : 0.f;
    uu[0] = (y > 0 && x0 > 0)     ? d[base - 513] : 0.f;
    uu[9] = (y > 0 && x0 != 504)  ? d[base - 504] : 0.f;
    ww[0] = (y < 511 && x0 > 0)   ? d[base + 511] : 0.f;
    ww[9] = (y < 511 && x0 != 504)? d[base + 520] : 0.f;
    uu[1]=u0.x; uu[2]=u0.y; uu[3]=u0.z; uu[4]=u0.w; uu[5]=u1.x; uu[6]=u1.y; uu[7]=u1.z; uu[8]=u1.w;
    mm[1]=m0.x; mm[2]=m0.y; mm[3]=m0.z; mm[4]=m0.w; mm[5]=m1.x; mm[6]=m1.y; mm[7]=m1.z; mm[8]=m1.w;
    ww[1]=w0.x; ww[2]=w0.y; ww[3]=w0.z; ww[4]=w0.w; ww[5]=w1.x; ww[6]=w1.y; ww[7]=w1.z; ww[8]=w1.w;

    const float4 p0 = *(const float4*)(p + base);
    const float4 p1 = *(const float4*)(p + base + 4);
    const float pv[8] = {p0.x, p0.y, p0.z, p0.w, p1.x, p1.y, p1.z, p1.w};

    float gmn = 3.4e38f, gmx = -3.4e38f, dmn = 3.4e38f, dmx = -3.4e38f;
    double ar = 0.0; int fg = 0;
    int lab[8];
#pragma unroll
    for (int j = 0; j < 8; ++j) {
        const float gx = (uu[j+2] - uu[j]) + 2.f * (mm[j+2] - mm[j]) + (ww[j+2] - ww[j]);
        const float gy = (ww[j] - uu[j]) + 2.f * (ww[j+1] - uu[j+1]) + (ww[j+2] - uu[j+2]);
        const float gm = sqrtf(gx * gx + gy * gy + 1e-8f);
        gmn = fminf(gmn, gm); gmx = fmaxf(gmx, gm);
        dmn = fminf(dmn, mm[j+1]); dmx = fmaxf(dmx, mm[j+1]);
        ar += (double)pv[j];
        const bool f = pv[j] > 0.5f;
        fg += f ? 1 : 0;
        lab[j] = f ? (base + j) : -1;
    }
    if (labels) {
        int* Lb = labels + off;
        int* Cb = counts + off;
        *(int4*)(Lb + base)     = make_int4(lab[0], lab[1], lab[2], lab[3]);
        *(int4*)(Lb + base + 4) = make_int4(lab[4], lab[5], lab[6], lab[7]);
        const int4 zi = make_int4(0, 0, 0, 0);
        *(int4*)(Cb + base) = zi; *(int4*)(Cb + base + 4) = zi;
    }

    for (int o = 32; o > 0; o >>= 1) {
        gmn = fminf(gmn, __shfl_down(gmn, o));
        gmx = fmaxf(gmx, __shfl_down(gmx, o));
        dmn = fminf(dmn, __shfl_down(dmn, o));
        dmx = fmaxf(dmx, __shfl_down(dmx, o));
        ar += __shfl_down(ar, o);
        fg += __shfl_down(fg, o);
    }
    __shared__ float sg0[4], sg1[4], sd0[4], sd1[4];
    __shared__ double sa[4];
    __shared__ int sf[4];
    const int wid = threadIdx.x >> 6, lane = threadIdx.x & 63;
    if (lane == 0) { sg0[wid] = gmn; sg1[wid] = gmx; sd0[wid] = dmn; sd1[wid] = dmx; sa[wid] = ar; sf[wid] = fg; }
    __syncthreads();
    if (threadIdx.x == 0) {
        for (int w = 1; w < 4; ++w) {
            gmn = fminf(gmn, sg0[w]); gmx = fmaxf(gmx, sg1[w]);
            dmn = fminf(dmn, sd0[w]); dmx = fmaxf(dmx, sd1[w]);
            ar += sa[w]; fg += sf[w];
        }
        const int bid = blockIdx.y * gridDim.x + blockIdx.x;
        pmm[bid] = make_float4(gmn, gmx, dmn, dmx);
        parea[bid] = ar;
        pfg[bid] = fg;
    }
}

// Stage-2 reduce: blocks 0..15 -> per-image area/fg; block 16 -> global min/max.
__global__ void k_red(const float4* __restrict__ pmm, const double* __restrict__ parea,
                      const int* __restrict__ pfg, Scal* s) {
    const int wid = threadIdx.x >> 6, lane = threadIdx.x & 63;
    if (blockIdx.x == IMG_B) {
        float gmn = 3.4e38f, gmx = -3.4e38f, dmn = 3.4e38f, dmx = -3.4e38f;
        for (int k = threadIdx.x; k < NPART; k += 256) {
            const float4 v = pmm[k];
            gmn = fminf(gmn, v.x); gmx = fmaxf(gmx, v.y);
            dmn = fminf(dmn, v.z); dmx = fmaxf(dmx, v.w);
        }
        for (int o = 32; o > 0; o >>= 1) {
            gmn = fminf(gmn, __shfl_down(gmn, o));
            gmx = fmaxf(gmx, __shfl_down(gmx, o));
            dmn = fminf(dmn, __shfl_down(dmn, o));
            dmx = fmaxf(dmx, __shfl_down(dmx, o));
        }
        __shared__ float sg0[4], sg1[4], sd0[4], sd1[4];
        if (lane == 0) { sg0[wid] = gmn; sg1[wid] = gmx; sd0[wid] = dmn; sd1[wid] = dmx; }
        __syncthreads();
        if (threadIdx.x == 0) {
            for (int w = 1; w < 4; ++w) {
                gmn = fminf(gmn, sg0[w]); gmx = fmaxf(gmx, sg1[w]);
                dmn = fminf(dmn, sd0[w]); dmx = fmaxf(dmx, sd1[w]);
            }
            s->gmin = gmn; s->gmax = gmx; s->dmin = dmn; s->dmax = dmx;
        }
    } else {
        const int b = blockIdx.x;
        double ar = 0.0; int fg = 0;
        if (threadIdx.x < 128) { ar = parea[b * 128 + threadIdx.x]; fg = pfg[b * 128 + threadIdx.x]; }
        for (int o = 32; o > 0; o >>= 1) { ar += __shfl_down(ar, o); fg += __shfl_down(fg, o); }
        __shared__ double sa[4];
        __shared__ int sf[4];
        if (lane == 0) { sa[wid] = ar; sf[wid] = fg; }
        __syncthreads();
        if (threadIdx.x == 0) {
            ar += sa[1]; fg += sf[1];
            s->area[b] = ar; s->fgcnt[b] = fg;
        }
    }
}

// ---- union-find ----
__device__ __forceinline__ int uf_findv(const int* L, int p) {
    while (true) { const int q = L[p]; if (q == p) return p; p = q; }
}
__device__ void uf_merge(int* L, int a, int b) {
    while (true) {
        a = uf_findv(L, a);
        b = uf_findv(L, b);
        if (a == b) return;
        if (a < b) { int t = a; a = b; b = t; }
        const int old = atomicMin(&L[a], b);
        if (old == a) return;
        a = old;
    }
}

// fallback path only (small ws): label init
__global__ void k_ccl_init(const float* __restrict__ pred, int* __restrict__ labels, int b0) {
    const int img = blockIdx.y;
    const int i = (blockIdx.x * 256 + threadIdx.x) * 4;
    const float4 pv = *(const float4*)(pred + (size_t)(b0 + img) * IMG_HW + i);
    *(int4*)(labels + (size_t)img * IMG_HW + i) =
        make_int4(pv.x > 0.5f ? i : -1, pv.y > 0.5f ? i + 1 : -1,
                  pv.z > 0.5f ? i + 2 : -1, pv.w > 0.5f ? i + 3 : -1);
}

// grid (256, nimg), block 256, 4 px/thread
__global__ void k_merge(int* __restrict__ labels) {
    const int img = blockIdx.y;
    int* L = labels + (size_t)img * IMG_HW;
    const int i = (blockIdx.x * 256 + threadIdx.x) * 4;
    const int4 v = *(const int4*)(L + i);
    const int x0 = i & 511, y = i >> 9;
    if (v.x >= 0 && v.y >= 0) uf_merge(L, i, i + 1);
    if (v.y >= 0 && v.z >= 0) uf_merge(L, i + 1, i + 2);
    if (v.z >= 0 && v.w >= 0) uf_merge(L, i + 2, i + 3);
    if (x0 != 508 && v.w >= 0 && L[i + 4] >= 0) uf_merge(L, i + 3, i + 4);
    if (y < IMG_H - 1) {
        const int4 dn = *(const int4*)(L + i + 512);
        if (v.x >= 0 && dn.x >= 0) uf_merge(L, i,     i + 512);
        if (v.y >= 0 && dn.y >= 0) uf_merge(L, i + 1, i + 513);
        if (v.z >= 0 && dn.z >= 0) uf_merge(L, i + 2, i + 514);
        if (v.w >= 0 && dn.w >= 0) uf_merge(L, i + 3, i + 515);
    }
}

// grid (256, nimg), block 256, 4 px/thread; run-combined atomics
__global__ void k_count(const int* __restrict__ labels, int* __restrict__ counts) {
    const int img = blockIdx.y;
    const int* L = labels + (size_t)img * IMG_HW;
    int* C = counts + (size_t)img * IMG_HW;
    const int i = (blockIdx.x * 256 + threadIdx.x) * 4;
    const int4 v = *(const int4*)(L + i);
    int r[4];
    r[0] = v.x >= 0 ? uf_findv(L, v.x) : -1;
    r[1] = v.y >= 0 ? uf_findv(L, v.y) : -1;
    r[2] = v.z >= 0 ? uf_findv(L, v.z) : -1;
    r[3] = v.w >= 0 ? uf_findv(L, v.w) : -1;
    int prev = -1, cnt = 0;
#pragma unroll
    for (int j = 0; j < 4; ++j) {
        if (r[j] == prev) { ++cnt; }
        else {
            if (prev >= 0) atomicAdd(&C[prev], cnt);
            prev = r[j]; cnt = 1;
        }
    }
    if (prev >= 0) atomicAdd(&C[prev], cnt);
}

// grid (128, nimg), block 256, 8 elems/thread
__global__ void k_max(const int* __restrict__ counts, Scal* s, int b0) {
    const int img = blockIdx.y;
    const int* C = counts + (size_t)img * IMG_HW;
    const int i = (blockIdx.x * 256 + threadIdx.x) * 8;
    const int4 a = *(const int4*)(C + i);
    const int4 c = *(const int4*)(C + i + 4);
    int m = max(max(max(a.x, a.y), max(a.z, a.w)), max(max(c.x, c.y), max(c.z, c.w)));
    for (int o = 32; o > 0; o >>= 1) m = max(m, __shfl_down(m, o));
    __shared__ int sm[4];
    const int wid = threadIdx.x >> 6, lane = threadIdx.x & 63;
    if (lane == 0) sm[wid] = m;
    __syncthreads();
    if (threadIdx.x == 0) {
        for (int w = 1; w < 4; ++w) m = max(m, sm[w]);
        atomicMax(&s->maxcnt[b0 + img], m);
    }
}

// Pass 2: similarity MSE (global min/max from Scal); per-block partial to psim.
__global__ void k_sim(const float* __restrict__ dem, const float* __restrict__ pred,
                      const Scal* __restrict__ s, double* __restrict__ psim) {
    const int b = blockIdx.y;
    const size_t off = (size_t)b * IMG_HW;
    const float* d = dem + off;
    const float* p = pred + off;
    const float gmin = s->gmin, gmax = s->gmax;
    const float dmin = s->dmin, dmax = s->dmax;
    const float gden = gmax - gmin + 1e-8f;
    const float dden = dmax - dmin + 1e-8f;
    const int base = blockIdx.x * 2048 + threadIdx.x * 8;
    const int y = base >> 9, x0 = base & 511;

    const float4 z4 = make_float4(0.f, 0.f, 0.f, 0.f);
    float4 m0 = *(const float4*)(d + base);
    float4 m1 = *(const float4*)(d + base + 4);
    float4 u0 = z4, u1 = z4, w0 = z4, w1 = z4;
    if (y > 0)         { u0 = *(const float4*)(d + base - 512); u1 = *(const float4*)(d + base - 508); }
    if (y < IMG_H - 1) { w0 = *(const float4*)(d + base + 512); w1 = *(const float4*)(d + base + 516); }

    float uu[10], mm[10], ww[10];
    mm[0] = (x0 > 0)              ? d[base - 1]   : 0.f;
    mm[9] = (x0 != 504)           ? d[base + 8]   : 0.f;
    uu[0] = (y > 0 && x0 > 0)     ? d[base - 513] : 0.f;
    uu[9] = (y > 0 && x0 != 504)  ? d[base - 504] : 0.f;
    ww[0] = (y < 511 && x0 > 0)   ? d[base + 511] : 0.f;
    ww[9] = (y < 511 && x0 != 504)? d[base + 520] : 0.f;
    uu[1]=u0.x; uu[2]=u0.y; uu[3]=u0.z; uu[4]=u0.w; uu[5]=u1.x; uu[6]=u1.y; uu[7]=u1.z; uu[8]=u1.w;
    mm[1]=m0.x; mm[2]=m0.y; mm[3]=m0.z; mm[4]=m0.w; mm[5]=m1.x; mm[6]=m1.y; mm[7]=m1.z; mm[8]=m1.w;
    ww[1]=w0.x; ww[2]=w0.y; ww[3]=w0.z; ww[4]=w0.w; ww[5]=w1.x; ww[6]=w1.y; ww[7]=w1.z; ww[8]=w1.w;

    const float4 p0 = *(const float4*)(p + base);
    const float4 p1 = *(const float4*)(p + base + 4);
    const float pv[8] = {p0.x, p0.y, p0.z, p0.w, p1.x, p1.y, p1.z, p1.w};

    double acc = 0.0;
#pragma unroll
    for (int j = 0; j < 8; ++j) {
        const float gx = (uu[j+2] - uu[j]) + 2.f * (mm[j+2] - mm[j]) + (ww[j+2] - ww[j]);
        const float gy = (ww[j] - uu[j]) + 2.f * (ww[j+1] - uu[j+1]) + (ww[j+2] - uu[j+2]);
        const float gm = sqrtf(gx * gx + gy * gy + 1e-8f);
        const float lap = uu[j+1] + mm[j] + mm[j+2] + ww[j+1] - 4.f * mm[j+1];
        const float gn = (gm - gmin) / gden;
        const float hn = (mm[j+1] - dmin) / dden;
        const float cv = tanhf(lap * 0.1f);
        const float e0 = pv[j] - gn, e1 = pv[j] - hn, e2 = pv[j] - cv;
        acc += (double)(e0 * e0) + (double)(e1 * e1) + (double)(e2 * e2);
    }
    for (int o = 32; o > 0; o >>= 1) acc += __shfl_down(acc, o);
    __shared__ double sa[4];
    const int wid = threadIdx.x >> 6, lane = threadIdx.x & 63;
    if (lane == 0) sa[wid] = acc;
    __syncthreads();
    if (threadIdx.x == 0) {
        for (int w = 1; w < 4; ++w) acc += sa[w];
        psim[blockIdx.y * gridDim.x + blockIdx.x] = acc;
    }
}

// Final: reduce psim (2048 doubles) + compose loss. 1 block, 256 threads.
__global__ void k_final(const double* __restrict__ psim, const Scal* __restrict__ s,
                        float* __restrict__ out) {
    double acc = 0.0;
    for (int k = threadIdx.x; k < NPART; k += 256) acc += psim[k];
    for (int o = 32; o > 0; o >>= 1) acc += __shfl_down(acc, o);
    __shared__ double sa[4];
    const int wid = threadIdx.x >> 6, lane = threadIdx.x & 63;
    if (lane == 0) sa[wid] = acc;
    __syncthreads();
    if (threadIdx.x == 0) {
        for (int w = 1; w < 4; ++w) acc += sa[w];
        const double tp = (double)IMG_HW;
        const double tmin = 0.1 * tp, tmax = 0.3 * tp;
        const double sim = acc / ((double)IMG_B * 3.0 * (double)IMG_HW);
        double conn = 0.0, scale = 0.0;
        for (int b = 0; b < IMG_B; ++b) {
            const int total = s->fgcnt[b];
            if (total > 0) conn += 1.0 - (double)s->maxcnt[b] / (double)total;
            const double a = s->area[b];
            scale += fmax(a - tmax, 0.0) + fmax(tmin - a, 0.0);
        }
        conn /= (double)IMG_B;
        scale = (scale / (double)IMG_B) / tp;
        const double total = sim + 0.1 * conn + 0.05 * scale;
        out[0] = (float)(0.1 * total);
    }
}

extern "C" void kernel_launch(void* const* d_in, const int* in_sizes, int n_in,
                              void* d_out, int out_size, void* d_ws, size_t ws_size,
                              hipStream_t stream) {
    const float* pred = (const float*)d_in[0];  // [16,1,512,512]
    const float* dem  = (const float*)d_in[1];  // [16,1,512,512]
    float* out = (float*)d_out;

    char* ws = (char*)d_ws;
    Scal* s = (Scal*)ws;
    float4* pmm  = (float4*)(ws + OFF_PMM);
    double* parea = (double*)(ws + OFF_AREA);
    int*    pfg   = (int*)(ws + OFF_FG);
    double* psim  = (double*)(ws + OFF_SIM);
    int* scratch = (int*)(ws + OFF_SCR);
    const size_t avail = (ws_size > OFF_SCR) ? ws_size - OFF_SCR : 0;
    const size_t need_full = 2ull * IMG_B * IMG_HW * 4ull;  // labels + counts, all images

    hipLaunchKernelGGL(k_init_scal, dim3(1), dim3(64), 0, stream, s);

    if (avail >= need_full) {
        int* labels = scratch;
        int* counts = scratch + (size_t)IMG_B * IMG_HW;
        hipLaunchKernelGGL(k_feat,  dim3(128, IMG_B), dim3(256), 0, stream,
                           dem, pred, labels, counts, pmm, parea, pfg);
        hipLaunchKernelGGL(k_red,   dim3(IMG_B + 1), dim3(256), 0, stream, pmm, parea, pfg, s);
        hipLaunchKernelGGL(k_merge, dim3(256, IMG_B), dim3(256), 0, stream, labels);
        hipLaunchKernelGGL(k_count, dim3(256, IMG_B), dim3(256), 0, stream, labels, counts);
        hipLaunchKernelGGL(k_max,   dim3(128, IMG_B), dim3(256), 0, stream, counts, s, 0);
    } else {
        hipLaunchKernelGGL(k_feat, dim3(128, IMG_B), dim3(256), 0, stream, dem, pred,
                           (int*)nullptr, (int*)nullptr, pmm, parea, pfg);
        hipLaunchKernelGGL(k_red, dim3(IMG_B + 1), dim3(256), 0, stream, pmm, parea, pfg, s);
        long long chunk = (long long)(avail / (2ull * IMG_HW * 4ull));
        if (chunk < 1) chunk = 1;
        if (chunk > IMG_B) chunk = IMG_B;
        for (int b0 = 0; b0 < IMG_B; b0 += (int)chunk) {
            const int n = (int)((b0 + chunk <= IMG_B) ? chunk : (IMG_B - b0));
            int* labels = scratch;
            int* counts = scratch + (size_t)chunk * IMG_HW;
            hipMemsetAsync(counts, 0, (size_t)n * IMG_HW * sizeof(int), stream);
            hipLaunchKernelGGL(k_ccl_init, dim3(256, n), dim3(256), 0, stream, pred, labels, b0);
            hipLaunchKernelGGL(k_merge,    dim3(256, n), dim3(256), 0, stream, labels);
            hipLaunchKernelGGL(k_count,    dim3(256, n), dim3(256), 0, stream, labels, counts);
            hipLaunchKernelGGL(k_max,      dim3(128, n), dim3(256), 0, stream, counts, s, b0);
        }
    }

    hipLaunchKernelGGL(k_sim, dim3(128, IMG_B), dim3(256), 0, stream, dem, pred, s, psim);
    hipLaunchKernelGGL(k_final, dim3(1), dim3(256), 0, stream, psim, s, out);
}

// Round 4
// 182.147 us; speedup vs baseline: 2.2253x; 1.3816x over previous
//
#include <hip/hip_runtime.h>
#include <math.h>

#define IMG_B 16
#define IMG_H 512
#define IMG_W 512
#define IMG_HW (IMG_H * IMG_W)
#define NPART 2048            // 128 blocks/image * 16 images

struct Scal {
    float gmin, gmax, dmin, dmax;   // global gmag / dem min-max
    double area[IMG_B];
    int fgcnt[IMG_B];
    int maxcnt[IMG_B];
};

// ws layout (bytes):
//   0      Scal (padded to 512)
//   512    float4 pmm[NPART]   (32768)   per-block {gmn,gmx,dmn,dmx}
//   33280  double parea[NPART] (16384)
//   49664  int    pfg[NPART]   (8192)
//   57856  double psim[NPART]  (16384)
//   74240  int scratch: labels / counts
#define OFF_PMM   512
#define OFF_AREA  33280
#define OFF_FG    49664
#define OFF_SIM   57856
#define OFF_SCR   74240

__global__ void k_init_scal(Scal* s) {
    if (threadIdx.x < IMG_B) {
        s->area[threadIdx.x] = 0.0;
        s->fgcnt[threadIdx.x] = 0;
        s->maxcnt[threadIdx.x] = 0;
    }
}

// Pass 1: stencil-reduce only (labels moved to k_local).
// grid (128, B), block 256. Thread handles 8 contiguous px. No global atomics.
__global__ void k_feat(const float* __restrict__ dem, const float* __restrict__ pred,
                       float4* __restrict__ pmm, double* __restrict__ parea,
                       int* __restrict__ pfg) {
    const int b = blockIdx.y;
    const size_t off = (size_t)b * IMG_HW;
    const float* d = dem + off;
    const float* p = pred + off;
    const int base = blockIdx.x * 2048 + threadIdx.x * 8;
    const int y = base >> 9, x0 = base & 511;

    const float4 z4 = make_float4(0.f, 0.f, 0.f, 0.f);
    float4 m0 = *(const float4*)(d + base);
    float4 m1 = *(const float4*)(d + base + 4);
    float4 u0 = z4, u1 = z4, w0 = z4, w1 = z4;
    if (y > 0)         { u0 = *(const float4*)(d + base - 512); u1 = *(const float4*)(d + base - 508); }
    if (y < IMG_H - 1) { w0 = *(const float4*)(d + base + 512); w1 = *(const float4*)(d + base + 516); }

    float uu[10], mm[10], ww[10];
    mm[0] = (x0 > 0)              ? d[base - 1]   : 0.f;
    mm[9] = (x0 != 504)           ? d[base + 8]   : 0.f;
    uu[0] = (y > 0 && x0 > 0)     ? d[base - 513] : 0.f;
    uu[9] = (y > 0 && x0 != 504)  ? d[base - 504] : 0.f;
    ww[0] = (y < 511 && x0 > 0)   ? d[base + 511] : 0.f;
    ww[9] = (y < 511 && x0 != 504)? d[base + 520] : 0.f;
    uu[1]=u0.x; uu[2]=u0.y; uu[3]=u0.z; uu[4]=u0.w; uu[5]=u1.x; uu[6]=u1.y; uu[7]=u1.z; uu[8]=u1.w;
    mm[1]=m0.x; mm[2]=m0.y; mm[3]=m0.z; mm[4]=m0.w; mm[5]=m1.x; mm[6]=m1.y; mm[7]=m1.z; mm[8]=m1.w;
    ww[1]=w0.x; ww[2]=w0.y; ww[3]=w0.z; ww[4]=w0.w; ww[5]=w1.x; ww[6]=w1.y; ww[7]=w1.z; ww[8]=w1.w;

    const float4 p0 = *(const float4*)(p + base);
    const float4 p1 = *(const float4*)(p + base + 4);
    const float pv[8] = {p0.x, p0.y, p0.z, p0.w, p1.x, p1.y, p1.z, p1.w};

    float gmn = 3.4e38f, gmx = -3.4e38f, dmn = 3.4e38f, dmx = -3.4e38f;
    double ar = 0.0; int fg = 0;
#pragma unroll
    for (int j = 0; j < 8; ++j) {
        const float gx = (uu[j+2] - uu[j]) + 2.f * (mm[j+2] - mm[j]) + (ww[j+2] - ww[j]);
        const float gy = (ww[j] - uu[j]) + 2.f * (ww[j+1] - uu[j+1]) + (ww[j+2] - uu[j+2]);
        const float gm = sqrtf(gx * gx + gy * gy + 1e-8f);
        gmn = fminf(gmn, gm); gmx = fmaxf(gmx, gm);
        dmn = fminf(dmn, mm[j+1]); dmx = fmaxf(dmx, mm[j+1]);
        ar += (double)pv[j];
        fg += (pv[j] > 0.5f) ? 1 : 0;
    }

    for (int o = 32; o > 0; o >>= 1) {
        gmn = fminf(gmn, __shfl_down(gmn, o));
        gmx = fmaxf(gmx, __shfl_down(gmx, o));
        dmn = fminf(dmn, __shfl_down(dmn, o));
        dmx = fmaxf(dmx, __shfl_down(dmx, o));
        ar += __shfl_down(ar, o);
        fg += __shfl_down(fg, o);
    }
    __shared__ float sg0[4], sg1[4], sd0[4], sd1[4];
    __shared__ double sa[4];
    __shared__ int sf[4];
    const int wid = threadIdx.x >> 6, lane = threadIdx.x & 63;
    if (lane == 0) { sg0[wid] = gmn; sg1[wid] = gmx; sd0[wid] = dmn; sd1[wid] = dmx; sa[wid] = ar; sf[wid] = fg; }
    __syncthreads();
    if (threadIdx.x == 0) {
        for (int w = 1; w < 4; ++w) {
            gmn = fminf(gmn, sg0[w]); gmx = fmaxf(gmx, sg1[w]);
            dmn = fminf(dmn, sd0[w]); dmx = fmaxf(dmx, sd1[w]);
            ar += sa[w]; fg += sf[w];
        }
        const int bid = blockIdx.y * gridDim.x + blockIdx.x;
        pmm[bid] = make_float4(gmn, gmx, dmn, dmx);
        parea[bid] = ar;
        pfg[bid] = fg;
    }
}

// Stage-2 reduce: blocks 0..15 -> per-image area/fg; block 16 -> global min/max.
__global__ void k_red(const float4* __restrict__ pmm, const double* __restrict__ parea,
                      const int* __restrict__ pfg, Scal* s) {
    const int wid = threadIdx.x >> 6, lane = threadIdx.x & 63;
    if (blockIdx.x == IMG_B) {
        float gmn = 3.4e38f, gmx = -3.4e38f, dmn = 3.4e38f, dmx = -3.4e38f;
        for (int k = threadIdx.x; k < NPART; k += 256) {
            const float4 v = pmm[k];
            gmn = fminf(gmn, v.x); gmx = fmaxf(gmx, v.y);
            dmn = fminf(dmn, v.z); dmx = fmaxf(dmx, v.w);
        }
        for (int o = 32; o > 0; o >>= 1) {
            gmn = fminf(gmn, __shfl_down(gmn, o));
            gmx = fmaxf(gmx, __shfl_down(gmx, o));
            dmn = fminf(dmn, __shfl_down(dmn, o));
            dmx = fmaxf(dmx, __shfl_down(dmx, o));
        }
        __shared__ float sg0[4], sg1[4], sd0[4], sd1[4];
        if (lane == 0) { sg0[wid] = gmn; sg1[wid] = gmx; sd0[wid] = dmn; sd1[wid] = dmx; }
        __syncthreads();
        if (threadIdx.x == 0) {
            for (int w = 1; w < 4; ++w) {
                gmn = fminf(gmn, sg0[w]); gmx = fmaxf(gmx, sg1[w]);
                dmn = fminf(dmn, sd0[w]); dmx = fmaxf(dmx, sd1[w]);
            }
            s->gmin = gmn; s->gmax = gmx; s->dmin = dmn; s->dmax = dmx;
        }
    } else {
        const int b = blockIdx.x;
        double ar = 0.0; int fg = 0;
        if (threadIdx.x < 128) { ar = parea[b * 128 + threadIdx.x]; fg = pfg[b * 128 + threadIdx.x]; }
        for (int o = 32; o > 0; o >>= 1) { ar += __shfl_down(ar, o); fg += __shfl_down(fg, o); }
        __shared__ double sa[4];
        __shared__ int sf[4];
        if (lane == 0) { sa[wid] = ar; sf[wid] = fg; }
        __syncthreads();
        if (threadIdx.x == 0) {
            ar += sa[1]; fg += sf[1];
            s->area[b] = ar; s->fgcnt[b] = fg;
        }
    }
}

// ---- union-find (works on LDS or global int arrays) ----
__device__ __forceinline__ int uf_findv(const int* L, int p) {
    while (true) { const int q = ((volatile const int*)L)[p]; if (q == p) return p; p = q; }
}
__device__ __forceinline__ void uf_merge(int* L, int a, int b) {
    while (true) {
        a = uf_findv(L, a);
        b = uf_findv(L, b);
        if (a == b) return;
        if (a < b) { int t = a; a = b; b = t; }
        const int old = atomicMin(&L[a], b);
        if (old == a) return;
        a = old;
    }
}

// Local CCL: one 64x64 tile per block (256 thr, 16 px/thr), union-find in LDS.
// Writes labels[g] = global index of tile-local root (path-compressed), -1 bg.
// Also zeroes counts. grid (64, nimg).
__global__ void k_local(const float* __restrict__ pred, int* __restrict__ labels,
                        int* __restrict__ counts, int b0) {
    const int slot = blockIdx.y;
    const float* p = pred + (size_t)(b0 + slot) * IMG_HW;
    int* Lb = labels + (size_t)slot * IMG_HW;
    int* Cb = counts + (size_t)slot * IMG_HW;
    const int tile = blockIdx.x;
    const int tx = (tile & 7) * 64, ty = (tile >> 3) * 64;

    __shared__ int lab[4096];
    const int l0 = threadIdx.x * 16;
    const int ly0 = l0 >> 6, lx0 = l0 & 63;
    const int g0 = (ty + ly0) * IMG_W + tx + lx0;

#pragma unroll
    for (int k = 0; k < 4; ++k) {
        const float4 pv = *(const float4*)(p + g0 + k * 4);
        const int l = l0 + k * 4;
        lab[l]     = pv.x > 0.5f ? l     : -1;
        lab[l + 1] = pv.y > 0.5f ? l + 1 : -1;
        lab[l + 2] = pv.z > 0.5f ? l + 2 : -1;
        lab[l + 3] = pv.w > 0.5f ? l + 3 : -1;
    }
    __syncthreads();

#pragma unroll
    for (int k = 0; k < 16; ++k) {
        const int l = l0 + k;
        if (lab[l] < 0) continue;
        const int lx = l & 63, ly = l >> 6;
        if (lx < 63 && lab[l + 1] >= 0)  uf_merge(lab, l, l + 1);
        if (ly < 63 && lab[l + 64] >= 0) uf_merge(lab, l, l + 64);
    }
    __syncthreads();

    const int4 zi = make_int4(0, 0, 0, 0);
#pragma unroll
    for (int k = 0; k < 4; ++k) {
        const int l = l0 + k * 4;
        int o[4];
#pragma unroll
        for (int j = 0; j < 4; ++j) {
            if (lab[l + j] < 0) { o[j] = -1; continue; }
            const int r = uf_findv(lab, l + j);
            lab[l + j] = r;  // path compression (root is a valid parent)
            o[j] = (ty + (r >> 6)) * IMG_W + tx + (r & 63);
        }
        *(int4*)(Lb + g0 + k * 4) = make_int4(o[0], o[1], o[2], o[3]);
        *(int4*)(Cb + g0 + k * 4) = zi;
    }
}

// Boundary merges: vertical (x=63 mod 64) + horizontal (y=63 mod 64) tile edges.
// 7*512*2 = 7168 edges/image. grid (28, nimg), block 256.
__global__ void k_bmerge(int* __restrict__ labels) {
    const int slot = blockIdx.y;
    int* L = labels + (size_t)slot * IMG_HW;
    const int e = blockIdx.x * 256 + threadIdx.x;
    int i, j;
    if (e < 3584) {             // vertical: (y, x=c*64+63) -- (y, x+1)
        const int c = e / 512, y = e % 512;
        i = y * IMG_W + c * 64 + 63;
        j = i + 1;
    } else {                    // horizontal: (y=r*64+63, x) -- (y+1, x)
        const int e2 = e - 3584;
        const int r = e2 / 512, x = e2 % 512;
        i = (r * 64 + 63) * IMG_W + x;
        j = i + IMG_W;
    }
    if (L[i] >= 0 && L[j] >= 0) uf_merge(L, i, j);
}

// grid (256, nimg), block 256, 4 px/thread; run-combined atomics
__global__ void k_count(const int* __restrict__ labels, int* __restrict__ counts) {
    const int img = blockIdx.y;
    const int* L = labels + (size_t)img * IMG_HW;
    int* C = counts + (size_t)img * IMG_HW;
    const int i = (blockIdx.x * 256 + threadIdx.x) * 4;
    const int4 v = *(const int4*)(L + i);
    int r[4];
    r[0] = v.x >= 0 ? uf_findv(L, v.x) : -1;
    r[1] = v.y >= 0 ? uf_findv(L, v.y) : -1;
    r[2] = v.z >= 0 ? uf_findv(L, v.z) : -1;
    r[3] = v.w >= 0 ? uf_findv(L, v.w) : -1;
    int prev = -1, cnt = 0;
#pragma unroll
    for (int j = 0; j < 4; ++j) {
        if (r[j] == prev) { ++cnt; }
        else {
            if (prev >= 0) atomicAdd(&C[prev], cnt);
            prev = r[j]; cnt = 1;
        }
    }
    if (prev >= 0) atomicAdd(&C[prev], cnt);
}

// grid (128, nimg), block 256, 8 elems/thread
__global__ void k_max(const int* __restrict__ counts, Scal* s, int b0) {
    const int img = blockIdx.y;
    const int* C = counts + (size_t)img * IMG_HW;
    const int i = (blockIdx.x * 256 + threadIdx.x) * 8;
    const int4 a = *(const int4*)(C + i);
    const int4 c = *(const int4*)(C + i + 4);
    int m = max(max(max(a.x, a.y), max(a.z, a.w)), max(max(c.x, c.y), max(c.z, c.w)));
    for (int o = 32; o > 0; o >>= 1) m = max(m, __shfl_down(m, o));
    __shared__ int sm[4];
    const int wid = threadIdx.x >> 6, lane = threadIdx.x & 63;
    if (lane == 0) sm[wid] = m;
    __syncthreads();
    if (threadIdx.x == 0) {
        for (int w = 1; w < 4; ++w) m = max(m, sm[w]);
        atomicMax(&s->maxcnt[b0 + img], m);
    }
}

// Pass 2: similarity MSE (global min/max from Scal); per-block partial to psim.
__global__ void k_sim(const float* __restrict__ dem, const float* __restrict__ pred,
                      const Scal* __restrict__ s, double* __restrict__ psim) {
    const int b = blockIdx.y;
    const size_t off = (size_t)b * IMG_HW;
    const float* d = dem + off;
    const float* p = pred + off;
    const float gmin = s->gmin, gmax = s->gmax;
    const float dmin = s->dmin, dmax = s->dmax;
    const float gden = gmax - gmin + 1e-8f;
    const float dden = dmax - dmin + 1e-8f;
    const int base = blockIdx.x * 2048 + threadIdx.x * 8;
    const int y = base >> 9, x0 = base & 511;

    const float4 z4 = make_float4(0.f, 0.f, 0.f, 0.f);
    float4 m0 = *(const float4*)(d + base);
    float4 m1 = *(const float4*)(d + base + 4);
    float4 u0 = z4, u1 = z4, w0 = z4, w1 = z4;
    if (y > 0)         { u0 = *(const float4*)(d + base - 512); u1 = *(const float4*)(d + base - 508); }
    if (y < IMG_H - 1) { w0 = *(const float4*)(d + base + 512); w1 = *(const float4*)(d + base + 516); }

    float uu[10], mm[10], ww[10];
    mm[0] = (x0 > 0)              ? d[base - 1]   : 0.f;
    mm[9] = (x0 != 504)           ? d[base + 8]   : 0.f;
    uu[0] = (y > 0 && x0 > 0)     ? d[base - 513] : 0.f;
    uu[9] = (y > 0 && x0 != 504)  ? d[base - 504] : 0.f;
    ww[0] = (y < 511 && x0 > 0)   ? d[base + 511] : 0.f;
    ww[9] = (y < 511 && x0 != 504)? d[base + 520] : 0.f;
    uu[1]=u0.x; uu[2]=u0.y; uu[3]=u0.z; uu[4]=u0.w; uu[5]=u1.x; uu[6]=u1.y; uu[7]=u1.z; uu[8]=u1.w;
    mm[1]=m0.x; mm[2]=m0.y; mm[3]=m0.z; mm[4]=m0.w; mm[5]=m1.x; mm[6]=m1.y; mm[7]=m1.z; mm[8]=m1.w;
    ww[1]=w0.x; ww[2]=w0.y; ww[3]=w0.z; ww[4]=w0.w; ww[5]=w1.x; ww[6]=w1.y; ww[7]=w1.z; ww[8]=w1.w;

    const float4 p0 = *(const float4*)(p + base);
    const float4 p1 = *(const float4*)(p + base + 4);
    const float pv[8] = {p0.x, p0.y, p0.z, p0.w, p1.x, p1.y, p1.z, p1.w};

    double acc = 0.0;
#pragma unroll
    for (int j = 0; j < 8; ++j) {
        const float gx = (uu[j+2] - uu[j]) + 2.f * (mm[j+2] - mm[j]) + (ww[j+2] - ww[j]);
        const float gy = (ww[j] - uu[j]) + 2.f * (ww[j+1] - uu[j+1]) + (ww[j+2] - uu[j+2]);
        const float gm = sqrtf(gx * gx + gy * gy + 1e-8f);
        const float lap = uu[j+1] + mm[j] + mm[j+2] + ww[j+1] - 4.f * mm[j+1];
        const float gn = (gm - gmin) / gden;
        const float hn = (mm[j+1] - dmin) / dden;
        const float cv = tanhf(lap * 0.1f);
        const float e0 = pv[j] - gn, e1 = pv[j] - hn, e2 = pv[j] - cv;
        acc += (double)(e0 * e0) + (double)(e1 * e1) + (double)(e2 * e2);
    }
    for (int o = 32; o > 0; o >>= 1) acc += __shfl_down(acc, o);
    __shared__ double sa[4];
    const int wid = threadIdx.x >> 6, lane = threadIdx.x & 63;
    if (lane == 0) sa[wid] = acc;
    __syncthreads();
    if (threadIdx.x == 0) {
        for (int w = 1; w < 4; ++w) acc += sa[w];
        psim[blockIdx.y * gridDim.x + blockIdx.x] = acc;
    }
}

// Final: reduce psim (2048 doubles) + compose loss. 1 block, 256 threads.
__global__ void k_final(const double* __restrict__ psim, const Scal* __restrict__ s,
                        float* __restrict__ out) {
    double acc = 0.0;
    for (int k = threadIdx.x; k < NPART; k += 256) acc += psim[k];
    for (int o = 32; o > 0; o >>= 1) acc += __shfl_down(acc, o);
    __shared__ double sa[4];
    const int wid = threadIdx.x >> 6, lane = threadIdx.x & 63;
    if (lane == 0) sa[wid] = acc;
    __syncthreads();
    if (threadIdx.x == 0) {
        for (int w = 1; w < 4; ++w) acc += sa[w];
        const double tp = (double)IMG_HW;
        const double tmin = 0.1 * tp, tmax = 0.3 * tp;
        const double sim = acc / ((double)IMG_B * 3.0 * (double)IMG_HW);
        double conn = 0.0, scale = 0.0;
        for (int b = 0; b < IMG_B; ++b) {
            const int total = s->fgcnt[b];
            if (total > 0) conn += 1.0 - (double)s->maxcnt[b] / (double)total;
            const double a = s->area[b];
            scale += fmax(a - tmax, 0.0) + fmax(tmin - a, 0.0);
        }
        conn /= (double)IMG_B;
        scale = (scale / (double)IMG_B) / tp;
        const double total = sim + 0.1 * conn + 0.05 * scale;
        out[0] = (float)(0.1 * total);
    }
}

extern "C" void kernel_launch(void* const* d_in, const int* in_sizes, int n_in,
                              void* d_out, int out_size, void* d_ws, size_t ws_size,
                              hipStream_t stream) {
    const float* pred = (const float*)d_in[0];  // [16,1,512,512]
    const float* dem  = (const float*)d_in[1];  // [16,1,512,512]
    float* out = (float*)d_out;

    char* ws = (char*)d_ws;
    Scal* s = (Scal*)ws;
    float4* pmm  = (float4*)(ws + OFF_PMM);
    double* parea = (double*)(ws + OFF_AREA);
    int*    pfg   = (int*)(ws + OFF_FG);
    double* psim  = (double*)(ws + OFF_SIM);
    int* scratch = (int*)(ws + OFF_SCR);
    const size_t avail = (ws_size > OFF_SCR) ? ws_size - OFF_SCR : 0;
    const size_t need_full = 2ull * IMG_B * IMG_HW * 4ull;  // labels + counts, all images

    hipLaunchKernelGGL(k_init_scal, dim3(1), dim3(64), 0, stream, s);
    hipLaunchKernelGGL(k_feat, dim3(128, IMG_B), dim3(256), 0, stream,
                       dem, pred, pmm, parea, pfg);
    hipLaunchKernelGGL(k_red, dim3(IMG_B + 1), dim3(256), 0, stream, pmm, parea, pfg, s);

    if (avail >= need_full) {
        int* labels = scratch;
        int* counts = scratch + (size_t)IMG_B * IMG_HW;
        hipLaunchKernelGGL(k_local,  dim3(64, IMG_B),  dim3(256), 0, stream, pred, labels, counts, 0);
        hipLaunchKernelGGL(k_bmerge, dim3(28, IMG_B),  dim3(256), 0, stream, labels);
        hipLaunchKernelGGL(k_count,  dim3(256, IMG_B), dim3(256), 0, stream, labels, counts);
        hipLaunchKernelGGL(k_max,    dim3(128, IMG_B), dim3(256), 0, stream, counts, s, 0);
    } else {
        long long chunk = (long long)(avail / (2ull * IMG_HW * 4ull));
        if (chunk < 1) chunk = 1;
        if (chunk > IMG_B) chunk = IMG_B;
        for (int b0 = 0; b0 < IMG_B; b0 += (int)chunk) {
            const int n = (int)((b0 + chunk <= IMG_B) ? chunk : (IMG_B - b0));
            int* labels = scratch;
            int* counts = scratch + (size_t)chunk * IMG_HW;
            hipLaunchKernelGGL(k_local,  dim3(64, n),  dim3(256), 0, stream, pred, labels, counts, b0);
            hipLaunchKernelGGL(k_bmerge, dim3(28, n),  dim3(256), 0, stream, labels);
            hipLaunchKernelGGL(k_count,  dim3(256, n), dim3(256), 0, stream, labels, counts);
            hipLaunchKernelGGL(k_max,    dim3(128, n), dim3(256), 0, stream, counts, s, b0);
        }
    }

    hipLaunchKernelGGL(k_sim, dim3(128, IMG_B), dim3(256), 0, stream, dem, pred, s, psim);
    hipLaunchKernelGGL(k_final, dim3(1), dim3(256), 0, stream, psim, s, out);
}

// Round 5
// 136.689 us; speedup vs baseline: 2.9654x; 1.3326x over previous
//
#include <hip/hip_runtime.h>
#include <math.h>

#define IMG_B 16
#define IMG_H 512
#define IMG_W 512
#define IMG_HW (IMG_H * IMG_W)
#define NPART 2048            // 128 blocks/image * 16 images

struct Scal {
    float gmin, gmax, dmin, dmax;   // global gmag / dem min-max
    double area[IMG_B];
    int fgcnt[IMG_B];
    int maxcnt[IMG_B];
};

// ws layout (bytes):
//   0      Scal (padded to 512)
//   512    float4 pmm[NPART]   (32768)   per-block {gmn,gmx,dmn,dmx}
//   33280  double parea[NPART] (16384)
//   49664  int    pfg[NPART]   (8192)
//   57856  double psim[NPART]  (16384)
//   74240  int scratch: labels / counts
#define OFF_PMM   512
#define OFF_AREA  33280
#define OFF_FG    49664
#define OFF_SIM   57856
#define OFF_SCR   74240

__global__ void k_init_scal(Scal* s) {
    if (threadIdx.x < IMG_B) {
        s->area[threadIdx.x] = 0.0;
        s->fgcnt[threadIdx.x] = 0;
        s->maxcnt[threadIdx.x] = 0;
    }
}

// Pass 1: stencil-reduce. grid (128, B), block 256, 8 contiguous px/thread.
__global__ void k_feat(const float* __restrict__ dem, const float* __restrict__ pred,
                       float4* __restrict__ pmm, double* __restrict__ parea,
                       int* __restrict__ pfg) {
    const int b = blockIdx.y;
    const size_t off = (size_t)b * IMG_HW;
    const float* d = dem + off;
    const float* p = pred + off;
    const int base = blockIdx.x * 2048 + threadIdx.x * 8;
    const int y = base >> 9, x0 = base & 511;

    const float4 z4 = make_float4(0.f, 0.f, 0.f, 0.f);
    float4 m0 = *(const float4*)(d + base);
    float4 m1 = *(const float4*)(d + base + 4);
    float4 u0 = z4, u1 = z4, w0 = z4, w1 = z4;
    if (y > 0)         { u0 = *(const float4*)(d + base - 512); u1 = *(const float4*)(d + base - 508); }
    if (y < IMG_H - 1) { w0 = *(const float4*)(d + base + 512); w1 = *(const float4*)(d + base + 516); }

    float uu[10], mm[10], ww[10];
    mm[0] = (x0 > 0)              ? d[base - 1]   : 0.f;
    mm[9] = (x0 != 504)           ? d[base + 8]   : 0.f;
    uu[0] = (y > 0 && x0 > 0)     ? d[base - 513] : 0.f;
    uu[9] = (y > 0 && x0 != 504)  ? d[base - 504] : 0.f;
    ww[0] = (y < 511 && x0 > 0)   ? d[base + 511] : 0.f;
    ww[9] = (y < 511 && x0 != 504)? d[base + 520] : 0.f;
    uu[1]=u0.x; uu[2]=u0.y; uu[3]=u0.z; uu[4]=u0.w; uu[5]=u1.x; uu[6]=u1.y; uu[7]=u1.z; uu[8]=u1.w;
    mm[1]=m0.x; mm[2]=m0.y; mm[3]=m0.z; mm[4]=m0.w; mm[5]=m1.x; mm[6]=m1.y; mm[7]=m1.z; mm[8]=m1.w;
    ww[1]=w0.x; ww[2]=w0.y; ww[3]=w0.z; ww[4]=w0.w; ww[5]=w1.x; ww[6]=w1.y; ww[7]=w1.z; ww[8]=w1.w;

    const float4 p0 = *(const float4*)(p + base);
    const float4 p1 = *(const float4*)(p + base + 4);
    const float pv[8] = {p0.x, p0.y, p0.z, p0.w, p1.x, p1.y, p1.z, p1.w};

    float gmn = 3.4e38f, gmx = -3.4e38f, dmn = 3.4e38f, dmx = -3.4e38f;
    double ar = 0.0; int fg = 0;
#pragma unroll
    for (int j = 0; j < 8; ++j) {
        const float gx = (uu[j+2] - uu[j]) + 2.f * (mm[j+2] - mm[j]) + (ww[j+2] - ww[j]);
        const float gy = (ww[j] - uu[j]) + 2.f * (ww[j+1] - uu[j+1]) + (ww[j+2] - uu[j+2]);
        const float gm = sqrtf(gx * gx + gy * gy + 1e-8f);
        gmn = fminf(gmn, gm); gmx = fmaxf(gmx, gm);
        dmn = fminf(dmn, mm[j+1]); dmx = fmaxf(dmx, mm[j+1]);
        ar += (double)pv[j];
        fg += (pv[j] > 0.5f) ? 1 : 0;
    }

    for (int o = 32; o > 0; o >>= 1) {
        gmn = fminf(gmn, __shfl_down(gmn, o));
        gmx = fmaxf(gmx, __shfl_down(gmx, o));
        dmn = fminf(dmn, __shfl_down(dmn, o));
        dmx = fmaxf(dmx, __shfl_down(dmx, o));
        ar += __shfl_down(ar, o);
        fg += __shfl_down(fg, o);
    }
    __shared__ float sg0[4], sg1[4], sd0[4], sd1[4];
    __shared__ double sa[4];
    __shared__ int sf[4];
    const int wid = threadIdx.x >> 6, lane = threadIdx.x & 63;
    if (lane == 0) { sg0[wid] = gmn; sg1[wid] = gmx; sd0[wid] = dmn; sd1[wid] = dmx; sa[wid] = ar; sf[wid] = fg; }
    __syncthreads();
    if (threadIdx.x == 0) {
        for (int w = 1; w < 4; ++w) {
            gmn = fminf(gmn, sg0[w]); gmx = fmaxf(gmx, sg1[w]);
            dmn = fminf(dmn, sd0[w]); dmx = fmaxf(dmx, sd1[w]);
            ar += sa[w]; fg += sf[w];
        }
        const int bid = blockIdx.y * gridDim.x + blockIdx.x;
        pmm[bid] = make_float4(gmn, gmx, dmn, dmx);
        parea[bid] = ar;
        pfg[bid] = fg;
    }
}

// Stage-2 reduce: blocks 0..15 -> per-image area/fg; block 16 -> global min/max.
__global__ void k_red(const float4* __restrict__ pmm, const double* __restrict__ parea,
                      const int* __restrict__ pfg, Scal* s) {
    const int wid = threadIdx.x >> 6, lane = threadIdx.x & 63;
    if (blockIdx.x == IMG_B) {
        float gmn = 3.4e38f, gmx = -3.4e38f, dmn = 3.4e38f, dmx = -3.4e38f;
        for (int k = threadIdx.x; k < NPART; k += 256) {
            const float4 v = pmm[k];
            gmn = fminf(gmn, v.x); gmx = fmaxf(gmx, v.y);
            dmn = fminf(dmn, v.z); dmx = fmaxf(dmx, v.w);
        }
        for (int o = 32; o > 0; o >>= 1) {
            gmn = fminf(gmn, __shfl_down(gmn, o));
            gmx = fmaxf(gmx, __shfl_down(gmx, o));
            dmn = fminf(dmn, __shfl_down(dmn, o));
            dmx = fmaxf(dmx, __shfl_down(dmx, o));
        }
        __shared__ float sg0[4], sg1[4], sd0[4], sd1[4];
        if (lane == 0) { sg0[wid] = gmn; sg1[wid] = gmx; sd0[wid] = dmn; sd1[wid] = dmx; }
        __syncthreads();
        if (threadIdx.x == 0) {
            for (int w = 1; w < 4; ++w) {
                gmn = fminf(gmn, sg0[w]); gmx = fmaxf(gmx, sg1[w]);
                dmn = fminf(dmn, sd0[w]); dmx = fmaxf(dmx, sd1[w]);
            }
            s->gmin = gmn; s->gmax = gmx; s->dmin = dmn; s->dmax = dmx;
        }
    } else {
        const int b = blockIdx.x;
        double ar = 0.0; int fg = 0;
        if (threadIdx.x < 128) { ar = parea[b * 128 + threadIdx.x]; fg = pfg[b * 128 + threadIdx.x]; }
        for (int o = 32; o > 0; o >>= 1) { ar += __shfl_down(ar, o); fg += __shfl_down(fg, o); }
        __shared__ double sa[4];
        __shared__ int sf[4];
        if (lane == 0) { sa[wid] = ar; sf[wid] = fg; }
        __syncthreads();
        if (threadIdx.x == 0) {
            ar += sa[1]; fg += sf[1];
            s->area[b] = ar; s->fgcnt[b] = fg;
        }
    }
}

// ---- union-find (works on LDS or global int arrays) ----
__device__ __forceinline__ int uf_findv(const int* L, int p) {
    while (true) { const int q = ((volatile const int*)L)[p]; if (q == p) return p; p = q; }
}
__device__ __forceinline__ void uf_merge(int* L, int a, int b) {
    while (true) {
        a = uf_findv(L, a);
        b = uf_findv(L, b);
        if (a == b) return;
        if (a < b) { int t = a; a = b; b = t; }
        const int old = atomicMin(&L[a], b);
        if (old == a) return;
        a = old;
    }
}

// Local CCL: one 64x64 tile per block (256 thr, 16 px/thr), union-find in LDS.
// Writes labels[g] = global index of tile-local root; counts[g] = local
// component size at tile-local roots, 0 elsewhere. grid (64, nimg).
__global__ void k_local(const float* __restrict__ pred, int* __restrict__ labels,
                        int* __restrict__ counts, int b0) {
    const int slot = blockIdx.y;
    const float* p = pred + (size_t)(b0 + slot) * IMG_HW;
    int* Lb = labels + (size_t)slot * IMG_HW;
    int* Cb = counts + (size_t)slot * IMG_HW;
    const int tile = blockIdx.x;
    const int tx = (tile & 7) * 64, ty = (tile >> 3) * 64;

    __shared__ int lab[4096];
    __shared__ int lcnt[4096];
    const int l0 = threadIdx.x * 16;
    const int ly0 = l0 >> 6, lx0 = l0 & 63;
    const int g0 = (ty + ly0) * IMG_W + tx + lx0;

#pragma unroll
    for (int k = 0; k < 4; ++k) {
        const float4 pv = *(const float4*)(p + g0 + k * 4);
        const int l = l0 + k * 4;
        lab[l]     = pv.x > 0.5f ? l     : -1;
        lab[l + 1] = pv.y > 0.5f ? l + 1 : -1;
        lab[l + 2] = pv.z > 0.5f ? l + 2 : -1;
        lab[l + 3] = pv.w > 0.5f ? l + 3 : -1;
        lcnt[l] = 0; lcnt[l + 1] = 0; lcnt[l + 2] = 0; lcnt[l + 3] = 0;
    }
    __syncthreads();

#pragma unroll
    for (int k = 0; k < 16; ++k) {
        const int l = l0 + k;
        if (lab[l] < 0) continue;
        const int lx = l & 63, ly = l >> 6;
        if (lx < 63 && lab[l + 1] >= 0)  uf_merge(lab, l, l + 1);
        if (ly < 63 && lab[l + 64] >= 0) uf_merge(lab, l, l + 64);
    }
    __syncthreads();

    // find + path-compress + local size histogram (LDS atomics)
#pragma unroll
    for (int k = 0; k < 16; ++k) {
        const int l = l0 + k;
        if (lab[l] < 0) continue;
        const int r = uf_findv(lab, l);
        lab[l] = r;                 // root's parent stays itself: still valid
        atomicAdd(&lcnt[r], 1);
    }
    __syncthreads();

#pragma unroll
    for (int k = 0; k < 4; ++k) {
        const int l = l0 + k * 4;
        int o[4], c[4];
#pragma unroll
        for (int j = 0; j < 4; ++j) {
            const int r = lab[l + j];
            if (r < 0) { o[j] = -1; c[j] = 0; continue; }
            o[j] = (ty + (r >> 6)) * IMG_W + tx + (r & 63);
            c[j] = (r == l + j) ? lcnt[l + j] : 0;
        }
        *(int4*)(Lb + g0 + k * 4) = make_int4(o[0], o[1], o[2], o[3]);
        *(int4*)(Cb + g0 + k * 4) = make_int4(c[0], c[1], c[2], c[3]);
    }
}

// Boundary merges: vertical (x=63 mod 64) + horizontal (y=63 mod 64) tile edges.
// 7*512*2 = 7168 edges/image. grid (28, nimg), block 256.
__global__ void k_bmerge(int* __restrict__ labels) {
    const int slot = blockIdx.y;
    int* L = labels + (size_t)slot * IMG_HW;
    const int e = blockIdx.x * 256 + threadIdx.x;
    int i, j;
    if (e < 3584) {             // vertical: (y, x=c*64+63) -- (y, x+1)
        const int c = e / 512, y = e % 512;
        i = y * IMG_W + c * 64 + 63;
        j = i + 1;
    } else {                    // horizontal: (y=r*64+63, x) -- (y+1, x)
        const int e2 = e - 3584;
        const int r = e2 / 512, x = e2 % 512;
        i = (r * 64 + 63) * IMG_W + x;
        j = i + IMG_W;
    }
    if (L[i] >= 0 && L[j] >= 0) uf_merge(L, i, j);
}

// Flush: each tile-local root that is NOT a global root sends its local size
// to its global root. Stale local sizes at non-roots are <= their component
// total, so a subsequent max over counts is still the max component size.
// grid (256, nimg), block 256, 4 px/thread.
__global__ void k_flush(const int* __restrict__ labels, int* __restrict__ counts) {
    const int img = blockIdx.y;
    const int* L = labels + (size_t)img * IMG_HW;
    int* C = counts + (size_t)img * IMG_HW;
    const int i = (blockIdx.x * 256 + threadIdx.x) * 4;
    const int4 c = *(const int4*)(C + i);
    if ((c.x | c.y | c.z | c.w) == 0) return;
    const int cv[4] = {c.x, c.y, c.z, c.w};
#pragma unroll
    for (int j = 0; j < 4; ++j) {
        if (cv[j] <= 0) continue;
        const int g = i + j;
        const int r = uf_findv(L, g);
        if (r != g) atomicAdd(&C[r], cv[j]);
    }
}

// grid (128, nimg), block 256, 8 elems/thread
__global__ void k_max(const int* __restrict__ counts, Scal* s, int b0) {
    const int img = blockIdx.y;
    const int* C = counts + (size_t)img * IMG_HW;
    const int i = (blockIdx.x * 256 + threadIdx.x) * 8;
    const int4 a = *(const int4*)(C + i);
    const int4 c = *(const int4*)(C + i + 4);
    int m = max(max(max(a.x, a.y), max(a.z, a.w)), max(max(c.x, c.y), max(c.z, c.w)));
    for (int o = 32; o > 0; o >>= 1) m = max(m, __shfl_down(m, o));
    __shared__ int sm[4];
    const int wid = threadIdx.x >> 6, lane = threadIdx.x & 63;
    if (lane == 0) sm[wid] = m;
    __syncthreads();
    if (threadIdx.x == 0) {
        for (int w = 1; w < 4; ++w) m = max(m, sm[w]);
        atomicMax(&s->maxcnt[b0 + img], m);
    }
}

// Pass 2: similarity MSE (global min/max from Scal); per-block partial to psim.
__global__ void k_sim(const float* __restrict__ dem, const float* __restrict__ pred,
                      const Scal* __restrict__ s, double* __restrict__ psim) {
    const int b = blockIdx.y;
    const size_t off = (size_t)b * IMG_HW;
    const float* d = dem + off;
    const float* p = pred + off;
    const float gmin = s->gmin, gmax = s->gmax;
    const float dmin = s->dmin, dmax = s->dmax;
    const float gden = gmax - gmin + 1e-8f;
    const float dden = dmax - dmin + 1e-8f;
    const int base = blockIdx.x * 2048 + threadIdx.x * 8;
    const int y = base >> 9, x0 = base & 511;

    const float4 z4 = make_float4(0.f, 0.f, 0.f, 0.f);
    float4 m0 = *(const float4*)(d + base);
    float4 m1 = *(const float4*)(d + base + 4);
    float4 u0 = z4, u1 = z4, w0 = z4, w1 = z4;
    if (y > 0)         { u0 = *(const float4*)(d + base - 512); u1 = *(const float4*)(d + base - 508); }
    if (y < IMG_H - 1) { w0 = *(const float4*)(d + base + 512); w1 = *(const float4*)(d + base + 516); }

    float uu[10], mm[10], ww[10];
    mm[0] = (x0 > 0)              ? d[base - 1]   : 0.f;
    mm[9] = (x0 != 504)           ? d[base + 8]   : 0.f;
    uu[0] = (y > 0 && x0 > 0)     ? d[base - 513] : 0.f;
    uu[9] = (y > 0 && x0 != 504)  ? d[base - 504] : 0.f;
    ww[0] = (y < 511 && x0 > 0)   ? d[base + 511] : 0.f;
    ww[9] = (y < 511 && x0 != 504)? d[base + 520] : 0.f;
    uu[1]=u0.x; uu[2]=u0.y; uu[3]=u0.z; uu[4]=u0.w; uu[5]=u1.x; uu[6]=u1.y; uu[7]=u1.z; uu[8]=u1.w;
    mm[1]=m0.x; mm[2]=m0.y; mm[3]=m0.z; mm[4]=m0.w; mm[5]=m1.x; mm[6]=m1.y; mm[7]=m1.z; mm[8]=m1.w;
    ww[1]=w0.x; ww[2]=w0.y; ww[3]=w0.z; ww[4]=w0.w; ww[5]=w1.x; ww[6]=w1.y; ww[7]=w1.z; ww[8]=w1.w;

    const float4 p0 = *(const float4*)(p + base);
    const float4 p1 = *(const float4*)(p + base + 4);
    const float pv[8] = {p0.x, p0.y, p0.z, p0.w, p1.x, p1.y, p1.z, p1.w};

    double acc = 0.0;
#pragma unroll
    for (int j = 0; j < 8; ++j) {
        const float gx = (uu[j+2] - uu[j]) + 2.f * (mm[j+2] - mm[j]) + (ww[j+2] - ww[j]);
        const float gy = (ww[j] - uu[j]) + 2.f * (ww[j+1] - uu[j+1]) + (ww[j+2] - uu[j+2]);
        const float gm = sqrtf(gx * gx + gy * gy + 1e-8f);
        const float lap = uu[j+1] + mm[j] + mm[j+2] + ww[j+1] - 4.f * mm[j+1];
        const float gn = (gm - gmin) / gden;
        const float hn = (mm[j+1] - dmin) / dden;
        const float cv = tanhf(lap * 0.1f);
        const float e0 = pv[j] - gn, e1 = pv[j] - hn, e2 = pv[j] - cv;
        acc += (double)(e0 * e0) + (double)(e1 * e1) + (double)(e2 * e2);
    }
    for (int o = 32; o > 0; o >>= 1) acc += __shfl_down(acc, o);
    __shared__ double sa[4];
    const int wid = threadIdx.x >> 6, lane = threadIdx.x & 63;
    if (lane == 0) sa[wid] = acc;
    __syncthreads();
    if (threadIdx.x == 0) {
        for (int w = 1; w < 4; ++w) acc += sa[w];
        psim[blockIdx.y * gridDim.x + blockIdx.x] = acc;
    }
}

// Final: reduce psim (2048 doubles) + compose loss. 1 block, 256 threads.
__global__ void k_final(const double* __restrict__ psim, const Scal* __restrict__ s,
                        float* __restrict__ out) {
    double acc = 0.0;
    for (int k = threadIdx.x; k < NPART; k += 256) acc += psim[k];
    for (int o = 32; o > 0; o >>= 1) acc += __shfl_down(acc, o);
    __shared__ double sa[4];
    const int wid = threadIdx.x >> 6, lane = threadIdx.x & 63;
    if (lane == 0) sa[wid] = acc;
    __syncthreads();
    if (threadIdx.x == 0) {
        for (int w = 1; w < 4; ++w) acc += sa[w];
        const double tp = (double)IMG_HW;
        const double tmin = 0.1 * tp, tmax = 0.3 * tp;
        const double sim = acc / ((double)IMG_B * 3.0 * (double)IMG_HW);
        double conn = 0.0, scale = 0.0;
        for (int b = 0; b < IMG_B; ++b) {
            const int total = s->fgcnt[b];
            if (total > 0) conn += 1.0 - (double)s->maxcnt[b] / (double)total;
            const double a = s->area[b];
            scale += fmax(a - tmax, 0.0) + fmax(tmin - a, 0.0);
        }
        conn /= (double)IMG_B;
        scale = (scale / (double)IMG_B) / tp;
        const double total = sim + 0.1 * conn + 0.05 * scale;
        out[0] = (float)(0.1 * total);
    }
}

extern "C" void kernel_launch(void* const* d_in, const int* in_sizes, int n_in,
                              void* d_out, int out_size, void* d_ws, size_t ws_size,
                              hipStream_t stream) {
    const float* pred = (const float*)d_in[0];  // [16,1,512,512]
    const float* dem  = (const float*)d_in[1];  // [16,1,512,512]
    float* out = (float*)d_out;

    char* ws = (char*)d_ws;
    Scal* s = (Scal*)ws;
    float4* pmm  = (float4*)(ws + OFF_PMM);
    double* parea = (double*)(ws + OFF_AREA);
    int*    pfg   = (int*)(ws + OFF_FG);
    double* psim  = (double*)(ws + OFF_SIM);
    int* scratch = (int*)(ws + OFF_SCR);
    const size_t avail = (ws_size > OFF_SCR) ? ws_size - OFF_SCR : 0;
    const size_t need_full = 2ull * IMG_B * IMG_HW * 4ull;  // labels + counts, all images

    hipLaunchKernelGGL(k_init_scal, dim3(1), dim3(64), 0, stream, s);
    hipLaunchKernelGGL(k_feat, dim3(128, IMG_B), dim3(256), 0, stream,
                       dem, pred, pmm, parea, pfg);
    hipLaunchKernelGGL(k_red, dim3(IMG_B + 1), dim3(256), 0, stream, pmm, parea, pfg, s);

    if (avail >= need_full) {
        int* labels = scratch;
        int* counts = scratch + (size_t)IMG_B * IMG_HW;
        hipLaunchKernelGGL(k_local,  dim3(64, IMG_B),  dim3(256), 0, stream, pred, labels, counts, 0);
        hipLaunchKernelGGL(k_bmerge, dim3(28, IMG_B),  dim3(256), 0, stream, labels);
        hipLaunchKernelGGL(k_flush,  dim3(256, IMG_B), dim3(256), 0, stream, labels, counts);
        hipLaunchKernelGGL(k_max,    dim3(128, IMG_B), dim3(256), 0, stream, counts, s, 0);
    } else {
        long long chunk = (long long)(avail / (2ull * IMG_HW * 4ull));
        if (chunk < 1) chunk = 1;
        if (chunk > IMG_B) chunk = IMG_B;
        for (int b0 = 0; b0 < IMG_B; b0 += (int)chunk) {
            const int n = (int)((b0 + chunk <= IMG_B) ? chunk : (IMG_B - b0));
            int* labels = scratch;
            int* counts = scratch + (size_t)chunk * IMG_HW;
            hipLaunchKernelGGL(k_local,  dim3(64, n),  dim3(256), 0, stream, pred, labels, counts, b0);
            hipLaunchKernelGGL(k_bmerge, dim3(28, n),  dim3(256), 0, stream, labels);
            hipLaunchKernelGGL(k_flush,  dim3(256, n), dim3(256), 0, stream, labels, counts);
            hipLaunchKernelGGL(k_max,    dim3(128, n), dim3(256), 0, stream, counts, s, b0);
        }
    }

    hipLaunchKernelGGL(k_sim, dim3(128, IMG_B), dim3(256), 0, stream, dem, pred, s, psim);
    hipLaunchKernelGGL(k_final, dim3(1), dim3(256), 0, stream, psim, s, out);
}

// Round 6
// 123.754 us; speedup vs baseline: 3.2753x; 1.1045x over previous
//
#include <hip/hip_runtime.h>
#include <math.h>

#define IMG_B 16
#define IMG_H 512
#define IMG_W 512
#define IMG_HW (IMG_H * IMG_W)
#define NPART 2048            // 128 blocks/image * 16 images

// moment indices: 0:S_p 1:S_pp 2:S_g 3:S_gg 4:S_pg 5:S_d 6:S_dd 7:S_pd 8:S_t
#define NMOM 9

struct Scal {
    float gmin, gmax, dmin, dmax;
    double mom[NMOM];
    double area[IMG_B];
    int fgcnt[IMG_B];
    int maxcnt[IMG_B];
};

// ws layout (bytes):
//   0       Scal (padded to 512)
//   512     float4 pmm[NPART]            (32768)  per-block {gmn,gmx,dmn,dmx}
//   33280   double pblk[NPART][NMOM]     (147456) per-block moment partials
//   180736  int    pfg[NPART]            (8192)
//   188928  int scratch: labels / counts
#define OFF_PMM   512
#define OFF_MOM   33280
#define OFF_FG    180736
#define OFF_SCR   188928

__global__ void k_init_scal(Scal* s) {
    if (threadIdx.x < IMG_B) {
        s->area[threadIdx.x] = 0.0;
        s->fgcnt[threadIdx.x] = 0;
        s->maxcnt[threadIdx.x] = 0;
    }
}

// Pass 1: stencil + ALL similarity moments + min/max + per-image area/fg.
// grid (128, B), block 256, 8 contiguous px/thread. No global atomics.
__global__ void k_feat(const float* __restrict__ dem, const float* __restrict__ pred,
                       float4* __restrict__ pmm, double* __restrict__ pblk,
                       int* __restrict__ pfg) {
    const int b = blockIdx.y;
    const size_t off = (size_t)b * IMG_HW;
    const float* d = dem + off;
    const float* p = pred + off;
    const int base = blockIdx.x * 2048 + threadIdx.x * 8;
    const int y = base >> 9, x0 = base & 511;

    const float4 z4 = make_float4(0.f, 0.f, 0.f, 0.f);
    float4 m0 = *(const float4*)(d + base);
    float4 m1 = *(const float4*)(d + base + 4);
    float4 u0 = z4, u1 = z4, w0 = z4, w1 = z4;
    if (y > 0)         { u0 = *(const float4*)(d + base - 512); u1 = *(const float4*)(d + base - 508); }
    if (y < IMG_H - 1) { w0 = *(const float4*)(d + base + 512); w1 = *(const float4*)(d + base + 516); }

    float uu[10], mm[10], ww[10];
    mm[0] = (x0 > 0)              ? d[base - 1]   : 0.f;
    mm[9] = (x0 != 504)           ? d[base + 8]   : 0.f;
    uu[0] = (y > 0 && x0 > 0)     ? d[base - 513] : 0.f;
    uu[9] = (y > 0 && x0 != 504)  ? d[base - 504] : 0.f;
    ww[0] = (y < 511 && x0 > 0)   ? d[base + 511] : 0.f;
    ww[9] = (y < 511 && x0 != 504)? d[base + 520] : 0.f;
    uu[1]=u0.x; uu[2]=u0.y; uu[3]=u0.z; uu[4]=u0.w; uu[5]=u1.x; uu[6]=u1.y; uu[7]=u1.z; uu[8]=u1.w;
    mm[1]=m0.x; mm[2]=m0.y; mm[3]=m0.z; mm[4]=m0.w; mm[5]=m1.x; mm[6]=m1.y; mm[7]=m1.z; mm[8]=m1.w;
    ww[1]=w0.x; ww[2]=w0.y; ww[3]=w0.z; ww[4]=w0.w; ww[5]=w1.x; ww[6]=w1.y; ww[7]=w1.z; ww[8]=w1.w;

    const float4 p0 = *(const float4*)(p + base);
    const float4 p1 = *(const float4*)(p + base + 4);
    const float pv[8] = {p0.x, p0.y, p0.z, p0.w, p1.x, p1.y, p1.z, p1.w};

    float gmn = 3.4e38f, gmx = -3.4e38f, dmn = 3.4e38f, dmx = -3.4e38f;
    double mo[NMOM];
#pragma unroll
    for (int m = 0; m < NMOM; ++m) mo[m] = 0.0;
    int fg = 0;
#pragma unroll
    for (int j = 0; j < 8; ++j) {
        const float gx = (uu[j+2] - uu[j]) + 2.f * (mm[j+2] - mm[j]) + (ww[j+2] - ww[j]);
        const float gy = (ww[j] - uu[j]) + 2.f * (ww[j+1] - uu[j+1]) + (ww[j+2] - uu[j+2]);
        const float gm = sqrtf(gx * gx + gy * gy + 1e-8f);
        const float lap = uu[j+1] + mm[j] + mm[j+2] + ww[j+1] - 4.f * mm[j+1];
        const float cv = tanhf(lap * 0.1f);
        const float pj = pv[j], dj = mm[j+1];
        gmn = fminf(gmn, gm); gmx = fmaxf(gmx, gm);
        dmn = fminf(dmn, dj); dmx = fmaxf(dmx, dj);
        fg += (pj > 0.5f) ? 1 : 0;
        const double pd = pj, gd = gm, dd = dj;
        const double et = (double)(pj - cv);
        mo[0] += pd;        mo[1] += pd * pd;
        mo[2] += gd;        mo[3] += gd * gd;   mo[4] += pd * gd;
        mo[5] += dd;        mo[6] += dd * dd;   mo[7] += pd * dd;
        mo[8] += et * et;
    }

    for (int o = 32; o > 0; o >>= 1) {
        gmn = fminf(gmn, __shfl_down(gmn, o));
        gmx = fmaxf(gmx, __shfl_down(gmx, o));
        dmn = fminf(dmn, __shfl_down(dmn, o));
        dmx = fmaxf(dmx, __shfl_down(dmx, o));
#pragma unroll
        for (int m = 0; m < NMOM; ++m) mo[m] += __shfl_down(mo[m], o);
        fg += __shfl_down(fg, o);
    }
    __shared__ float sg0[4], sg1[4], sd0[4], sd1[4];
    __shared__ double sa[4][NMOM];
    __shared__ int sf[4];
    const int wid = threadIdx.x >> 6, lane = threadIdx.x & 63;
    if (lane == 0) {
        sg0[wid] = gmn; sg1[wid] = gmx; sd0[wid] = dmn; sd1[wid] = dmx; sf[wid] = fg;
#pragma unroll
        for (int m = 0; m < NMOM; ++m) sa[wid][m] = mo[m];
    }
    __syncthreads();
    if (threadIdx.x == 0) {
        for (int w = 1; w < 4; ++w) {
            gmn = fminf(gmn, sg0[w]); gmx = fmaxf(gmx, sg1[w]);
            dmn = fminf(dmn, sd0[w]); dmx = fmaxf(dmx, sd1[w]);
            fg += sf[w];
#pragma unroll
            for (int m = 0; m < NMOM; ++m) mo[m] += sa[w][m];
        }
        const int bid = blockIdx.y * gridDim.x + blockIdx.x;
        pmm[bid] = make_float4(gmn, gmx, dmn, dmx);
#pragma unroll
        for (int m = 0; m < NMOM; ++m) pblk[(size_t)bid * NMOM + m] = mo[m];
        pfg[bid] = fg;
    }
}

// Stage-2 reduce. grid (IMG_B + 1 + NMOM):
//  blocks 0..15       -> per-image area (moment 0 partial) + fg
//  block  16          -> global min/max
//  blocks 17..17+NMOM -> one global moment each
__global__ void k_red(const float4* __restrict__ pmm, const double* __restrict__ pblk,
                      const int* __restrict__ pfg, Scal* s) {
    const int wid = threadIdx.x >> 6, lane = threadIdx.x & 63;
    if (blockIdx.x < IMG_B) {
        const int b = blockIdx.x;
        double ar = 0.0; int fg = 0;
        if (threadIdx.x < 128) {
            const int k = b * 128 + threadIdx.x;
            ar = pblk[(size_t)k * NMOM + 0];
            fg = pfg[k];
        }
        for (int o = 32; o > 0; o >>= 1) { ar += __shfl_down(ar, o); fg += __shfl_down(fg, o); }
        __shared__ double sa[4];
        __shared__ int sf[4];
        if (lane == 0) { sa[wid] = ar; sf[wid] = fg; }
        __syncthreads();
        if (threadIdx.x == 0) {
            ar += sa[1]; fg += sf[1];
            s->area[b] = ar; s->fgcnt[b] = fg;
        }
    } else if (blockIdx.x == IMG_B) {
        float gmn = 3.4e38f, gmx = -3.4e38f, dmn = 3.4e38f, dmx = -3.4e38f;
        for (int k = threadIdx.x; k < NPART; k += 256) {
            const float4 v = pmm[k];
            gmn = fminf(gmn, v.x); gmx = fmaxf(gmx, v.y);
            dmn = fminf(dmn, v.z); dmx = fmaxf(dmx, v.w);
        }
        for (int o = 32; o > 0; o >>= 1) {
            gmn = fminf(gmn, __shfl_down(gmn, o));
            gmx = fmaxf(gmx, __shfl_down(gmx, o));
            dmn = fminf(dmn, __shfl_down(dmn, o));
            dmx = fmaxf(dmx, __shfl_down(dmx, o));
        }
        __shared__ float sg0[4], sg1[4], sd0[4], sd1[4];
        if (lane == 0) { sg0[wid] = gmn; sg1[wid] = gmx; sd0[wid] = dmn; sd1[wid] = dmx; }
        __syncthreads();
        if (threadIdx.x == 0) {
            for (int w = 1; w < 4; ++w) {
                gmn = fminf(gmn, sg0[w]); gmx = fmaxf(gmx, sg1[w]);
                dmn = fminf(dmn, sd0[w]); dmx = fmaxf(dmx, sd1[w]);
            }
            s->gmin = gmn; s->gmax = gmx; s->dmin = dmn; s->dmax = dmx;
        }
    } else {
        const int m = blockIdx.x - IMG_B - 1;   // 0..NMOM-1
        double acc = 0.0;
        for (int k = threadIdx.x; k < NPART; k += 256) acc += pblk[(size_t)k * NMOM + m];
        for (int o = 32; o > 0; o >>= 1) acc += __shfl_down(acc, o);
        __shared__ double sa[4];
        if (lane == 0) sa[wid] = acc;
        __syncthreads();
        if (threadIdx.x == 0) {
            for (int w = 1; w < 4; ++w) acc += sa[w];
            s->mom[m] = acc;
        }
    }
}

// ---- union-find (works on LDS or global int arrays) ----
__device__ __forceinline__ int uf_findv(const int* L, int p) {
    while (true) { const int q = ((volatile const int*)L)[p]; if (q == p) return p; p = q; }
}
__device__ __forceinline__ void uf_merge(int* L, int a, int b) {
    while (true) {
        a = uf_findv(L, a);
        b = uf_findv(L, b);
        if (a == b) return;
        if (a < b) { int t = a; a = b; b = t; }
        const int old = atomicMin(&L[a], b);
        if (old == a) return;
        a = old;
    }
}

// Local CCL: one 64x64 tile per block, union-find in LDS.
// Pixel mapping l = tid + k*256: LDS bank = tid%32 -> conflict-free (2-way),
// and each wave64 covers one full tile row -> coalesced global access.
// Writes labels[g] = global index of tile-local root; counts[g] = local
// component size at tile-local roots, 0 elsewhere. grid (64, nimg).
__global__ void k_local(const float* __restrict__ pred, int* __restrict__ labels,
                        int* __restrict__ counts, int b0) {
    const int slot = blockIdx.y;
    const float* p = pred + (size_t)(b0 + slot) * IMG_HW;
    int* Lb = labels + (size_t)slot * IMG_HW;
    int* Cb = counts + (size_t)slot * IMG_HW;
    const int tile = blockIdx.x;
    const int tx = (tile & 7) * 64, ty = (tile >> 3) * 64;
    const int tid = threadIdx.x;

    __shared__ int lab[4096];
    __shared__ int lcnt[4096];

#pragma unroll
    for (int k = 0; k < 16; ++k) {
        const int l = tid + k * 256;
        const int g = (ty + (l >> 6)) * IMG_W + tx + (l & 63);
        lab[l] = (p[g] > 0.5f) ? l : -1;
        lcnt[l] = 0;
    }
    __syncthreads();

#pragma unroll
    for (int k = 0; k < 16; ++k) {
        const int l = tid + k * 256;
        if (lab[l] < 0) continue;
        if ((l & 63) < 63 && lab[l + 1] >= 0)  uf_merge(lab, l, l + 1);
        if (l < 4032 && lab[l + 64] >= 0)      uf_merge(lab, l, l + 64);
    }
    __syncthreads();

    // find + path-compress + local size histogram (LDS atomics)
#pragma unroll
    for (int k = 0; k < 16; ++k) {
        const int l = tid + k * 256;
        if (lab[l] < 0) continue;
        const int r = uf_findv(lab, l);
        lab[l] = r;                 // root's parent stays itself: still valid
        atomicAdd(&lcnt[r], 1);
    }
    __syncthreads();

#pragma unroll
    for (int k = 0; k < 16; ++k) {
        const int l = tid + k * 256;
        const int g = (ty + (l >> 6)) * IMG_W + tx + (l & 63);
        const int r = lab[l];
        Lb[g] = (r < 0) ? -1 : (ty + (r >> 6)) * IMG_W + tx + (r & 63);
        Cb[g] = (r == l) ? lcnt[l] : 0;
    }
}

// Boundary merges: vertical (x=63 mod 64) + horizontal (y=63 mod 64) tile edges.
// 7*512*2 = 7168 edges/image. grid (28, nimg), block 256.
__global__ void k_bmerge(int* __restrict__ labels) {
    const int slot = blockIdx.y;
    int* L = labels + (size_t)slot * IMG_HW;
    const int e = blockIdx.x * 256 + threadIdx.x;
    int i, j;
    if (e < 3584) {             // vertical: (y, x=c*64+63) -- (y, x+1)
        const int c = e / 512, y = e % 512;
        i = y * IMG_W + c * 64 + 63;
        j = i + 1;
    } else {                    // horizontal: (y=r*64+63, x) -- (y+1, x)
        const int e2 = e - 3584;
        const int r = e2 / 512, x = e2 % 512;
        i = (r * 64 + 63) * IMG_W + x;
        j = i + IMG_W;
    }
    if (L[i] >= 0 && L[j] >= 0) uf_merge(L, i, j);
}

// Flush: each tile-local root that is NOT a global root sends its local size
// to its global root. Stale local sizes at non-roots are <= their component
// total, so a subsequent max over counts is still the max component size.
// grid (256, nimg), block 256, 4 px/thread.
__global__ void k_flush(const int* __restrict__ labels, int* __restrict__ counts) {
    const int img = blockIdx.y;
    const int* L = labels + (size_t)img * IMG_HW;
    int* C = counts + (size_t)img * IMG_HW;
    const int i = (blockIdx.x * 256 + threadIdx.x) * 4;
    const int4 c = *(const int4*)(C + i);
    if ((c.x | c.y | c.z | c.w) == 0) return;
    const int cv[4] = {c.x, c.y, c.z, c.w};
#pragma unroll
    for (int j = 0; j < 4; ++j) {
        if (cv[j] <= 0) continue;
        const int g = i + j;
        const int r = uf_findv(L, g);
        if (r != g) atomicAdd(&C[r], cv[j]);
    }
}

// grid (128, nimg), block 256, 8 elems/thread
__global__ void k_max(const int* __restrict__ counts, Scal* s, int b0) {
    const int img = blockIdx.y;
    const int* C = counts + (size_t)img * IMG_HW;
    const int i = (blockIdx.x * 256 + threadIdx.x) * 8;
    const int4 a = *(const int4*)(C + i);
    const int4 c = *(const int4*)(C + i + 4);
    int m = max(max(max(a.x, a.y), max(a.z, a.w)), max(max(c.x, c.y), max(c.z, c.w)));
    for (int o = 32; o > 0; o >>= 1) m = max(m, __shfl_down(m, o));
    __shared__ int sm[4];
    const int wid = threadIdx.x >> 6, lane = threadIdx.x & 63;
    if (lane == 0) sm[wid] = m;
    __syncthreads();
    if (threadIdx.x == 0) {
        for (int w = 1; w < 4; ++w) m = max(m, sm[w]);
        atomicMax(&s->maxcnt[b0 + img], m);
    }
}

// Final: closed-form similarity from moments + conn + scale. 1 thread.
__global__ void k_final(const Scal* __restrict__ s, float* __restrict__ out) {
    const double N = (double)IMG_B * (double)IMG_HW;
    const float gdenf = s->gmax - s->gmin + 1e-8f;   // match reference f32 denominator
    const float ddenf = s->dmax - s->dmin + 1e-8f;
    const double a = 1.0 / (double)gdenf, bb = 1.0 / (double)ddenf;
    const double gmin = (double)s->gmin, dmin = (double)s->dmin;
    const double S_p = s->mom[0], S_pp = s->mom[1];
    const double S_g = s->mom[2], S_gg = s->mom[3], S_pg = s->mom[4];
    const double S_d = s->mom[5], S_dd = s->mom[6], S_pd = s->mom[7];
    const double S_t = s->mom[8];
    const double sum_g = S_pp - 2.0 * a * (S_pg - gmin * S_p)
                       + a * a * (S_gg - 2.0 * gmin * S_g + gmin * gmin * N);
    const double sum_d = S_pp - 2.0 * bb * (S_pd - dmin * S_p)
                       + bb * bb * (S_dd - 2.0 * dmin * S_d + dmin * dmin * N);
    const double sim = (sum_g + sum_d + S_t) / (3.0 * N);

    const double tp = (double)IMG_HW;
    const double tmin = 0.1 * tp, tmax = 0.3 * tp;
    double conn = 0.0, scale = 0.0;
    for (int b = 0; b < IMG_B; ++b) {
        const int total = s->fgcnt[b];
        if (total > 0) conn += 1.0 - (double)s->maxcnt[b] / (double)total;
        const double ar = s->area[b];
        scale += fmax(ar - tmax, 0.0) + fmax(tmin - ar, 0.0);
    }
    conn /= (double)IMG_B;
    scale = (scale / (double)IMG_B) / tp;
    const double total = sim + 0.1 * conn + 0.05 * scale;
    out[0] = (float)(0.1 * total);
}

extern "C" void kernel_launch(void* const* d_in, const int* in_sizes, int n_in,
                              void* d_out, int out_size, void* d_ws, size_t ws_size,
                              hipStream_t stream) {
    const float* pred = (const float*)d_in[0];  // [16,1,512,512]
    const float* dem  = (const float*)d_in[1];  // [16,1,512,512]
    float* out = (float*)d_out;

    char* ws = (char*)d_ws;
    Scal* s = (Scal*)ws;
    float4* pmm  = (float4*)(ws + OFF_PMM);
    double* pblk = (double*)(ws + OFF_MOM);
    int*    pfg  = (int*)(ws + OFF_FG);
    int* scratch = (int*)(ws + OFF_SCR);
    const size_t avail = (ws_size > OFF_SCR) ? ws_size - OFF_SCR : 0;
    const size_t need_full = 2ull * IMG_B * IMG_HW * 4ull;  // labels + counts, all images

    hipLaunchKernelGGL(k_init_scal, dim3(1), dim3(64), 0, stream, s);
    hipLaunchKernelGGL(k_feat, dim3(128, IMG_B), dim3(256), 0, stream,
                       dem, pred, pmm, pblk, pfg);
    hipLaunchKernelGGL(k_red, dim3(IMG_B + 1 + NMOM), dim3(256), 0, stream, pmm, pblk, pfg, s);

    if (avail >= need_full) {
        int* labels = scratch;
        int* counts = scratch + (size_t)IMG_B * IMG_HW;
        hipLaunchKernelGGL(k_local,  dim3(64, IMG_B),  dim3(256), 0, stream, pred, labels, counts, 0);
        hipLaunchKernelGGL(k_bmerge, dim3(28, IMG_B),  dim3(256), 0, stream, labels);
        hipLaunchKernelGGL(k_flush,  dim3(256, IMG_B), dim3(256), 0, stream, labels, counts);
        hipLaunchKernelGGL(k_max,    dim3(128, IMG_B), dim3(256), 0, stream, counts, s, 0);
    } else {
        long long chunk = (long long)(avail / (2ull * IMG_HW * 4ull));
        if (chunk < 1) chunk = 1;
        if (chunk > IMG_B) chunk = IMG_B;
        for (int b0 = 0; b0 < IMG_B; b0 += (int)chunk) {
            const int n = (int)((b0 + chunk <= IMG_B) ? chunk : (IMG_B - b0));
            int* labels = scratch;
            int* counts = scratch + (size_t)chunk * IMG_HW;
            hipLaunchKernelGGL(k_local,  dim3(64, n),  dim3(256), 0, stream, pred, labels, counts, b0);
            hipLaunchKernelGGL(k_bmerge, dim3(28, n),  dim3(256), 0, stream, labels);
            hipLaunchKernelGGL(k_flush,  dim3(256, n), dim3(256), 0, stream, labels, counts);
            hipLaunchKernelGGL(k_max,    dim3(128, n), dim3(256), 0, stream, counts, s, b0);
        }
    }

    hipLaunchKernelGGL(k_final, dim3(1), dim3(1), 0, stream, s, out);
}

// Round 7
// 118.497 us; speedup vs baseline: 3.4206x; 1.0444x over previous
//
#include <hip/hip_runtime.h>
#include <math.h>

#define IMG_B 16
#define IMG_H 512
#define IMG_W 512
#define IMG_HW (IMG_H * IMG_W)
#define NPART 2048            // 128 blocks/image * 16 images

// moment indices: 0:S_p 1:S_pp 2:S_g 3:S_gg 4:S_pg 5:S_d 6:S_dd 7:S_pd 8:S_t
#define NMOM 9

// 32x32 tile CCL geometry
#define TILES_X 16
#define TILES 256             // per image
#define SLOTS 64              // max boundary components per tile (<=62 provable)
#define LIST_PER_IMG (TILES * SLOTS)   // 16384
#define TOUCH (1 << 30)

struct Scal {
    float gmin, gmax, dmin, dmax;
    double mom[NMOM];
    double area[IMG_B];
    int fgcnt[IMG_B];
    int maxcnt[IMG_B];
};

// ws layout (bytes):
//   0       Scal (padded to 512)
//   512     float4 pmm[NPART]            (32768)  per-block {gmn,gmx,dmn,dmx}
//   33280   double pblk[NPART][NMOM]     (147456) per-block moment partials
//   180736  int    pfg[NPART]            (8192)
//   188928  scratch: labels / counts / list / nslot
#define OFF_PMM   512
#define OFF_MOM   33280
#define OFF_FG    180736
#define OFF_SCR   188928

__global__ void k_init_scal(Scal* s) {
    if (threadIdx.x < IMG_B) {
        s->area[threadIdx.x] = 0.0;
        s->fgcnt[threadIdx.x] = 0;
        s->maxcnt[threadIdx.x] = 0;
    }
}

// Pass 1: stencil + ALL similarity moments + min/max + per-image area/fg.
// grid (128, B), block 256, 8 contiguous px/thread. No global atomics.
__global__ void k_feat(const float* __restrict__ dem, const float* __restrict__ pred,
                       float4* __restrict__ pmm, double* __restrict__ pblk,
                       int* __restrict__ pfg) {
    const int b = blockIdx.y;
    const size_t off = (size_t)b * IMG_HW;
    const float* d = dem + off;
    const float* p = pred + off;
    const int base = blockIdx.x * 2048 + threadIdx.x * 8;
    const int y = base >> 9, x0 = base & 511;

    const float4 z4 = make_float4(0.f, 0.f, 0.f, 0.f);
    float4 m0 = *(const float4*)(d + base);
    float4 m1 = *(const float4*)(d + base + 4);
    float4 u0 = z4, u1 = z4, w0 = z4, w1 = z4;
    if (y > 0)         { u0 = *(const float4*)(d + base - 512); u1 = *(const float4*)(d + base - 508); }
    if (y < IMG_H - 1) { w0 = *(const float4*)(d + base + 512); w1 = *(const float4*)(d + base + 516); }

    float uu[10], mm[10], ww[10];
    mm[0] = (x0 > 0)              ? d[base - 1]   : 0.f;
    mm[9] = (x0 != 504)           ? d[base + 8]   : 0.f;
    uu[0] = (y > 0 && x0 > 0)     ? d[base - 513] : 0.f;
    uu[9] = (y > 0 && x0 != 504)  ? d[base - 504] : 0.f;
    ww[0] = (y < 511 && x0 > 0)   ? d[base + 511] : 0.f;
    ww[9] = (y < 511 && x0 != 504)? d[base + 520] : 0.f;
    uu[1]=u0.x; uu[2]=u0.y; uu[3]=u0.z; uu[4]=u0.w; uu[5]=u1.x; uu[6]=u1.y; uu[7]=u1.z; uu[8]=u1.w;
    mm[1]=m0.x; mm[2]=m0.y; mm[3]=m0.z; mm[4]=m0.w; mm[5]=m1.x; mm[6]=m1.y; mm[7]=m1.z; mm[8]=m1.w;
    ww[1]=w0.x; ww[2]=w0.y; ww[3]=w0.z; ww[4]=w0.w; ww[5]=w1.x; ww[6]=w1.y; ww[7]=w1.z; ww[8]=w1.w;

    const float4 p0 = *(const float4*)(p + base);
    const float4 p1 = *(const float4*)(p + base + 4);
    const float pv[8] = {p0.x, p0.y, p0.z, p0.w, p1.x, p1.y, p1.z, p1.w};

    float gmn = 3.4e38f, gmx = -3.4e38f, dmn = 3.4e38f, dmx = -3.4e38f;
    double mo[NMOM];
#pragma unroll
    for (int m = 0; m < NMOM; ++m) mo[m] = 0.0;
    int fg = 0;
#pragma unroll
    for (int j = 0; j < 8; ++j) {
        const float gx = (uu[j+2] - uu[j]) + 2.f * (mm[j+2] - mm[j]) + (ww[j+2] - ww[j]);
        const float gy = (ww[j] - uu[j]) + 2.f * (ww[j+1] - uu[j+1]) + (ww[j+2] - uu[j+2]);
        const float gm = sqrtf(gx * gx + gy * gy + 1e-8f);
        const float lap = uu[j+1] + mm[j] + mm[j+2] + ww[j+1] - 4.f * mm[j+1];
        const float cv = tanhf(lap * 0.1f);
        const float pj = pv[j], dj = mm[j+1];
        gmn = fminf(gmn, gm); gmx = fmaxf(gmx, gm);
        dmn = fminf(dmn, dj); dmx = fmaxf(dmx, dj);
        fg += (pj > 0.5f) ? 1 : 0;
        const double pd = pj, gd = gm, dd = dj;
        const double et = (double)(pj - cv);
        mo[0] += pd;        mo[1] += pd * pd;
        mo[2] += gd;        mo[3] += gd * gd;   mo[4] += pd * gd;
        mo[5] += dd;        mo[6] += dd * dd;   mo[7] += pd * dd;
        mo[8] += et * et;
    }

    for (int o = 32; o > 0; o >>= 1) {
        gmn = fminf(gmn, __shfl_down(gmn, o));
        gmx = fmaxf(gmx, __shfl_down(gmx, o));
        dmn = fminf(dmn, __shfl_down(dmn, o));
        dmx = fmaxf(dmx, __shfl_down(dmx, o));
#pragma unroll
        for (int m = 0; m < NMOM; ++m) mo[m] += __shfl_down(mo[m], o);
        fg += __shfl_down(fg, o);
    }
    __shared__ float sg0[4], sg1[4], sd0[4], sd1[4];
    __shared__ double sa[4][NMOM];
    __shared__ int sf[4];
    const int wid = threadIdx.x >> 6, lane = threadIdx.x & 63;
    if (lane == 0) {
        sg0[wid] = gmn; sg1[wid] = gmx; sd0[wid] = dmn; sd1[wid] = dmx; sf[wid] = fg;
#pragma unroll
        for (int m = 0; m < NMOM; ++m) sa[wid][m] = mo[m];
    }
    __syncthreads();
    if (threadIdx.x == 0) {
        for (int w = 1; w < 4; ++w) {
            gmn = fminf(gmn, sg0[w]); gmx = fmaxf(gmx, sg1[w]);
            dmn = fminf(dmn, sd0[w]); dmx = fmaxf(dmx, sd1[w]);
            fg += sf[w];
#pragma unroll
            for (int m = 0; m < NMOM; ++m) mo[m] += sa[w][m];
        }
        const int bid = blockIdx.y * gridDim.x + blockIdx.x;
        pmm[bid] = make_float4(gmn, gmx, dmn, dmx);
#pragma unroll
        for (int m = 0; m < NMOM; ++m) pblk[(size_t)bid * NMOM + m] = mo[m];
        pfg[bid] = fg;
    }
}

// Stage-2 reduce. grid (IMG_B + 1 + NMOM):
//  blocks 0..15       -> per-image area (moment 0 partial) + fg
//  block  16          -> global min/max
//  blocks 17..17+NMOM -> one global moment each
__global__ void k_red(const float4* __restrict__ pmm, const double* __restrict__ pblk,
                      const int* __restrict__ pfg, Scal* s) {
    const int wid = threadIdx.x >> 6, lane = threadIdx.x & 63;
    if (blockIdx.x < IMG_B) {
        const int b = blockIdx.x;
        double ar = 0.0; int fg = 0;
        if (threadIdx.x < 128) {
            const int k = b * 128 + threadIdx.x;
            ar = pblk[(size_t)k * NMOM + 0];
            fg = pfg[k];
        }
        for (int o = 32; o > 0; o >>= 1) { ar += __shfl_down(ar, o); fg += __shfl_down(fg, o); }
        __shared__ double sa[4];
        __shared__ int sf[4];
        if (lane == 0) { sa[wid] = ar; sf[wid] = fg; }
        __syncthreads();
        if (threadIdx.x == 0) {
            ar += sa[1]; fg += sf[1];
            s->area[b] = ar; s->fgcnt[b] = fg;
        }
    } else if (blockIdx.x == IMG_B) {
        float gmn = 3.4e38f, gmx = -3.4e38f, dmn = 3.4e38f, dmx = -3.4e38f;
        for (int k = threadIdx.x; k < NPART; k += 256) {
            const float4 v = pmm[k];
            gmn = fminf(gmn, v.x); gmx = fmaxf(gmx, v.y);
            dmn = fminf(dmn, v.z); dmx = fmaxf(dmx, v.w);
        }
        for (int o = 32; o > 0; o >>= 1) {
            gmn = fminf(gmn, __shfl_down(gmn, o));
            gmx = fmaxf(gmx, __shfl_down(gmx, o));
            dmn = fminf(dmn, __shfl_down(dmn, o));
            dmx = fmaxf(dmx, __shfl_down(dmx, o));
        }
        __shared__ float sg0[4], sg1[4], sd0[4], sd1[4];
        if (lane == 0) { sg0[wid] = gmn; sg1[wid] = gmx; sd0[wid] = dmn; sd1[wid] = dmx; }
        __syncthreads();
        if (threadIdx.x == 0) {
            for (int w = 1; w < 4; ++w) {
                gmn = fminf(gmn, sg0[w]); gmx = fmaxf(gmx, sg1[w]);
                dmn = fminf(dmn, sd0[w]); dmx = fmaxf(dmx, sd1[w]);
            }
            s->gmin = gmn; s->gmax = gmx; s->dmin = dmn; s->dmax = dmx;
        }
    } else {
        const int m = blockIdx.x - IMG_B - 1;   // 0..NMOM-1
        double acc = 0.0;
        for (int k = threadIdx.x; k < NPART; k += 256) acc += pblk[(size_t)k * NMOM + m];
        for (int o = 32; o > 0; o >>= 1) acc += __shfl_down(acc, o);
        __shared__ double sa[4];
        if (lane == 0) sa[wid] = acc;
        __syncthreads();
        if (threadIdx.x == 0) {
            for (int w = 1; w < 4; ++w) acc += sa[w];
            s->mom[m] = acc;
        }
    }
}

// ---- union-find (works on LDS or global int arrays) ----
__device__ __forceinline__ int uf_findv(const int* L, int p) {
    while (true) { const int q = ((volatile const int*)L)[p]; if (q == p) return p; p = q; }
}
__device__ __forceinline__ void uf_merge(int* L, int a, int b) {
    while (true) {
        a = uf_findv(L, a);
        b = uf_findv(L, b);
        if (a == b) return;
        if (a < b) { int t = a; a = b; b = t; }
        const int old = atomicMin(&L[a], b);
        if (old == a) return;
        a = old;
    }
}

// Local CCL on 32x32 tiles, union-find in LDS, 4 px/thread.
// Interior components are max-reduced in-block (never hit HBM). Only
// boundary-ring-touching components emit: ring labels, self-parented root
// entries (labels[gr]=gr, counts[gr]=size), and a compacted root list.
// grid (256, nimg), block 256.
__global__ void k_local(const float* __restrict__ pred, int* __restrict__ labels,
                        int* __restrict__ counts, int* __restrict__ list,
                        int* __restrict__ nslot, Scal* s, int b0) {
    const int slot = blockIdx.y;
    const float* p = pred + (size_t)(b0 + slot) * IMG_HW;
    int* Lb = labels + (size_t)slot * IMG_HW;
    int* Cb = counts + (size_t)slot * IMG_HW;
    const int tile = blockIdx.x;
    const int tx = (tile & 15) * 32, ty = (tile >> 4) * 32;
    const int tid = threadIdx.x;

    __shared__ int lab[1024];
    __shared__ int lcnt[1024];
    __shared__ int ns;
    if (tid == 0) ns = 0;

#pragma unroll
    for (int k = 0; k < 4; ++k) {
        const int l = tid + k * 256;
        const int g = (ty + (l >> 5)) * IMG_W + tx + (l & 31);
        lab[l] = (p[g] > 0.5f) ? l : -1;
        lcnt[l] = 0;
    }
    __syncthreads();

#pragma unroll
    for (int k = 0; k < 4; ++k) {
        const int l = tid + k * 256;
        if (lab[l] < 0) continue;
        if ((l & 31) < 31 && lab[l + 1] >= 0) uf_merge(lab, l, l + 1);
        if (l < 992 && lab[l + 32] >= 0)      uf_merge(lab, l, l + 32);
    }
    __syncthreads();

    // find + path-compress + local size histogram
#pragma unroll
    for (int k = 0; k < 4; ++k) {
        const int l = tid + k * 256;
        if (lab[l] < 0) continue;
        const int r = uf_findv(lab, l);
        lab[l] = r;
        atomicAdd(&lcnt[r], 1);
    }
    __syncthreads();

    // mark ring-touching roots; write ring labels to global
#pragma unroll
    for (int k = 0; k < 4; ++k) {
        const int l = tid + k * 256;
        const int lx = l & 31, ly = l >> 5;
        const bool ring = (lx == 0) | (lx == 31) | (ly == 0) | (ly == 31);
        if (!ring) continue;
        const int r = lab[l];
        if (r >= 0) atomicOr(&lcnt[r], TOUCH);
        const int g = (ty + ly) * IMG_W + tx + lx;
        Lb[g] = (r < 0) ? -1 : (ty + (r >> 5)) * IMG_W + tx + (r & 31);
    }
    __syncthreads();

    // process roots: interior -> local max; touched -> emit to global
    int locmax = 0;
#pragma unroll
    for (int k = 0; k < 4; ++k) {
        const int l = tid + k * 256;
        if (lab[l] != l) continue;     // roots only
        const int c = lcnt[l];
        if (c & TOUCH) {
            const int sz = c & ~TOUCH;
            const int sidx = atomicAdd(&ns, 1);
            const int gr = (ty + (l >> 5)) * IMG_W + tx + (l & 31);
            Lb[gr] = gr;
            Cb[gr] = sz;
            list[((size_t)slot * TILES + tile) * SLOTS + sidx] = gr;
        } else {
            locmax = max(locmax, c);
        }
    }
    for (int o = 32; o > 0; o >>= 1) locmax = max(locmax, __shfl_down(locmax, o));
    __shared__ int sm[4];
    const int wid = tid >> 6, lane = tid & 63;
    if (lane == 0) sm[wid] = locmax;
    __syncthreads();
    if (tid == 0) {
        for (int w = 1; w < 4; ++w) locmax = max(locmax, sm[w]);
        if (locmax > 0) atomicMax(&s->maxcnt[b0 + slot], locmax);
        nslot[slot * TILES + tile] = ns;
    }
}

// Boundary merges between 32x32 tiles: 15 vertical + 15 horizontal seams,
// 15*512*2 = 15360 edges/image. grid (60, nimg), block 256.
__global__ void k_bmerge(int* __restrict__ labels) {
    const int slot = blockIdx.y;
    int* L = labels + (size_t)slot * IMG_HW;
    const int e = blockIdx.x * 256 + threadIdx.x;
    int i, j;
    if (e < 7680) {             // vertical: (y, x=c*32+31) -- (y, x+1)
        const int c = e / 512, y = e - c * 512;
        i = y * IMG_W + c * 32 + 31;
        j = i + 1;
    } else {                    // horizontal: (y=r*32+31, x) -- (y+1, x)
        const int e2 = e - 7680;
        const int r = e2 / 512, x = e2 - r * 512;
        i = (r * 32 + 31) * IMG_W + x;
        j = i + IMG_W;
    }
    if (L[i] >= 0 && L[j] >= 0) uf_merge(L, i, j);
}

// List flush: non-global-root listed roots push their local size to the
// global root. counts[g] of a non-root is never an add target -> safe read.
// grid (64, nimg), block 256 (16384 slots/image).
__global__ void k_lflush(const int* __restrict__ labels, int* __restrict__ counts,
                         const int* __restrict__ list, const int* __restrict__ nslot) {
    const int img = blockIdx.y;
    const int* L = labels + (size_t)img * IMG_HW;
    int* C = counts + (size_t)img * IMG_HW;
    const int sidx = blockIdx.x * 256 + threadIdx.x;
    const int tile = sidx >> 6, sl = sidx & 63;
    if (sl >= nslot[img * TILES + tile]) return;
    const int g = list[(size_t)img * LIST_PER_IMG + sidx];
    const int r = uf_findv(L, g);
    if (r != g) atomicAdd(&C[r], C[g]);
}

// List max: global roots (labels[g]==g) hold full component sizes.
__global__ void k_lmax(const int* __restrict__ labels, const int* __restrict__ counts,
                       const int* __restrict__ list, const int* __restrict__ nslot,
                       Scal* s, int b0) {
    const int img = blockIdx.y;
    const int* L = labels + (size_t)img * IMG_HW;
    const int* C = counts + (size_t)img * IMG_HW;
    const int sidx = blockIdx.x * 256 + threadIdx.x;
    const int tile = sidx >> 6, sl = sidx & 63;
    int m = 0;
    if (sl < nslot[img * TILES + tile]) {
        const int g = list[(size_t)img * LIST_PER_IMG + sidx];
        if (L[g] == g) m = C[g];
    }
    for (int o = 32; o > 0; o >>= 1) m = max(m, __shfl_down(m, o));
    __shared__ int sm[4];
    const int wid = threadIdx.x >> 6, lane = threadIdx.x & 63;
    if (lane == 0) sm[wid] = m;
    __syncthreads();
    if (threadIdx.x == 0) {
        for (int w = 1; w < 4; ++w) m = max(m, sm[w]);
        if (m > 0) atomicMax(&s->maxcnt[b0 + img], m);
    }
}

// Final: closed-form similarity from moments + conn + scale. 1 thread.
__global__ void k_final(const Scal* __restrict__ s, float* __restrict__ out) {
    const double N = (double)IMG_B * (double)IMG_HW;
    const float gdenf = s->gmax - s->gmin + 1e-8f;   // match reference f32 denominator
    const float ddenf = s->dmax - s->dmin + 1e-8f;
    const double a = 1.0 / (double)gdenf, bb = 1.0 / (double)ddenf;
    const double gmin = (double)s->gmin, dmin = (double)s->dmin;
    const double S_p = s->mom[0], S_pp = s->mom[1];
    const double S_g = s->mom[2], S_gg = s->mom[3], S_pg = s->mom[4];
    const double S_d = s->mom[5], S_dd = s->mom[6], S_pd = s->mom[7];
    const double S_t = s->mom[8];
    const double sum_g = S_pp - 2.0 * a * (S_pg - gmin * S_p)
                       + a * a * (S_gg - 2.0 * gmin * S_g + gmin * gmin * N);
    const double sum_d = S_pp - 2.0 * bb * (S_pd - dmin * S_p)
                       + bb * bb * (S_dd - 2.0 * dmin * S_d + dmin * dmin * N);
    const double sim = (sum_g + sum_d + S_t) / (3.0 * N);

    const double tp = (double)IMG_HW;
    const double tmin = 0.1 * tp, tmax = 0.3 * tp;
    double conn = 0.0, scale = 0.0;
    for (int b = 0; b < IMG_B; ++b) {
        const int total = s->fgcnt[b];
        if (total > 0) conn += 1.0 - (double)s->maxcnt[b] / (double)total;
        const double ar = s->area[b];
        scale += fmax(ar - tmax, 0.0) + fmax(tmin - ar, 0.0);
    }
    conn /= (double)IMG_B;
    scale = (scale / (double)IMG_B) / tp;
    const double total = sim + 0.1 * conn + 0.05 * scale;
    out[0] = (float)(0.1 * total);
}

extern "C" void kernel_launch(void* const* d_in, const int* in_sizes, int n_in,
                              void* d_out, int out_size, void* d_ws, size_t ws_size,
                              hipStream_t stream) {
    const float* pred = (const float*)d_in[0];  // [16,1,512,512]
    const float* dem  = (const float*)d_in[1];  // [16,1,512,512]
    float* out = (float*)d_out;

    char* ws = (char*)d_ws;
    Scal* s = (Scal*)ws;
    float4* pmm  = (float4*)(ws + OFF_PMM);
    double* pblk = (double*)(ws + OFF_MOM);
    int*    pfg  = (int*)(ws + OFF_FG);
    int* scratch = (int*)(ws + OFF_SCR);
    const size_t avail_ints = (ws_size > OFF_SCR) ? (ws_size - OFF_SCR) / 4 : 0;
    // per image: labels HW + counts HW + list 16384 + nslot 256
    const size_t per_img = 2ull * IMG_HW + LIST_PER_IMG + TILES;

    hipLaunchKernelGGL(k_init_scal, dim3(1), dim3(64), 0, stream, s);
    hipLaunchKernelGGL(k_feat, dim3(128, IMG_B), dim3(256), 0, stream,
                       dem, pred, pmm, pblk, pfg);
    hipLaunchKernelGGL(k_red, dim3(IMG_B + 1 + NMOM), dim3(256), 0, stream, pmm, pblk, pfg, s);

    long long chunk = (long long)(avail_ints / per_img);
    if (chunk < 1) chunk = 1;
    if (chunk > IMG_B) chunk = IMG_B;
    for (int b0 = 0; b0 < IMG_B; b0 += (int)chunk) {
        const int n = (int)((b0 + chunk <= IMG_B) ? chunk : (IMG_B - b0));
        int* labels = scratch;
        int* counts = scratch + (size_t)chunk * IMG_HW;
        int* list   = scratch + 2ull * chunk * IMG_HW;
        int* nslot  = scratch + 2ull * chunk * IMG_HW + (size_t)chunk * LIST_PER_IMG;
        hipLaunchKernelGGL(k_local,  dim3(TILES, n), dim3(256), 0, stream,
                           pred, labels, counts, list, nslot, s, b0);
        hipLaunchKernelGGL(k_bmerge, dim3(60, n),    dim3(256), 0, stream, labels);
        hipLaunchKernelGGL(k_lflush, dim3(64, n),    dim3(256), 0, stream, labels, counts, list, nslot);
        hipLaunchKernelGGL(k_lmax,   dim3(64, n),    dim3(256), 0, stream, labels, counts, list, nslot, s, b0);
    }

    hipLaunchKernelGGL(k_final, dim3(1), dim3(1), 0, stream, s, out);
}

// Round 8
// 103.044 us; speedup vs baseline: 3.9336x; 1.1500x over previous
//
#include <hip/hip_runtime.h>
#include <math.h>

#define IMG_B 16
#define IMG_H 512
#define IMG_W 512
#define IMG_HW (IMG_H * IMG_W)
#define NPART 2048            // 128 blocks/image * 16 images

// moment indices: 0:S_p 1:S_pp 2:S_g 3:S_gg 4:S_pg 5:S_d 6:S_dd 7:S_pd 8:S_t
#define NMOM 9

// 32x32 tile CCL, packed boundary graph: per tile 192 nodes
//   slots 0..127  : ring pixels (see ring index map below)
//   slots 128..191: boundary-component roots (compacted)
#define TILES 256             // per image (16x16)
#define NODES_PER_TILE 192
#define NODES_PER_IMG (TILES * NODES_PER_TILE)   // 49152
#define TOUCH (1 << 30)

struct Scal {
    float gmin, gmax, dmin, dmax;
    double mom[NMOM];
    double area[IMG_B];
    int fgcnt[IMG_B];
    int maxcnt[IMG_B];
};

// ws layout (bytes):
//   0       Scal (padded to 512)
//   512     float4 pmm[NPART]            (32768)  per-block {gmn,gmx,dmn,dmx}
//   33280   double pblk[NPART][NMOM]     (147456) per-block moment partials
//   180736  int    pfg[NPART]            (8192)
//   188928  scratch: packed labels / counts / nslot
#define OFF_PMM   512
#define OFF_MOM   33280
#define OFF_FG    180736
#define OFF_SCR   188928

__global__ void k_init_scal(Scal* s) {
    if (threadIdx.x < IMG_B) {
        s->area[threadIdx.x] = 0.0;
        s->fgcnt[threadIdx.x] = 0;
        s->maxcnt[threadIdx.x] = 0;
    }
}

// Pass 1: stencil + ALL similarity moments + min/max + per-image area/fg.
// grid (128, B), block 256, 8 contiguous px/thread. No global atomics.
__global__ void k_feat(const float* __restrict__ dem, const float* __restrict__ pred,
                       float4* __restrict__ pmm, double* __restrict__ pblk,
                       int* __restrict__ pfg) {
    const int b = blockIdx.y;
    const size_t off = (size_t)b * IMG_HW;
    const float* d = dem + off;
    const float* p = pred + off;
    const int base = blockIdx.x * 2048 + threadIdx.x * 8;
    const int y = base >> 9, x0 = base & 511;

    const float4 z4 = make_float4(0.f, 0.f, 0.f, 0.f);
    float4 m0 = *(const float4*)(d + base);
    float4 m1 = *(const float4*)(d + base + 4);
    float4 u0 = z4, u1 = z4, w0 = z4, w1 = z4;
    if (y > 0)         { u0 = *(const float4*)(d + base - 512); u1 = *(const float4*)(d + base - 508); }
    if (y < IMG_H - 1) { w0 = *(const float4*)(d + base + 512); w1 = *(const float4*)(d + base + 516); }

    float uu[10], mm[10], ww[10];
    mm[0] = (x0 > 0)              ? d[base - 1]   : 0.f;
    mm[9] = (x0 != 504)           ? d[base + 8]   : 0.f;
    uu[0] = (y > 0 && x0 > 0)     ? d[base - 513] : 0.f;
    uu[9] = (y > 0 && x0 != 504)  ? d[base - 504] : 0.f;
    ww[0] = (y < 511 && x0 > 0)   ? d[base + 511] : 0.f;
    ww[9] = (y < 511 && x0 != 504)? d[base + 520] : 0.f;
    uu[1]=u0.x; uu[2]=u0.y; uu[3]=u0.z; uu[4]=u0.w; uu[5]=u1.x; uu[6]=u1.y; uu[7]=u1.z; uu[8]=u1.w;
    mm[1]=m0.x; mm[2]=m0.y; mm[3]=m0.z; mm[4]=m0.w; mm[5]=m1.x; mm[6]=m1.y; mm[7]=m1.z; mm[8]=m1.w;
    ww[1]=w0.x; ww[2]=w0.y; ww[3]=w0.z; ww[4]=w0.w; ww[5]=w1.x; ww[6]=w1.y; ww[7]=w1.z; ww[8]=w1.w;

    const float4 p0 = *(const float4*)(p + base);
    const float4 p1 = *(const float4*)(p + base + 4);
    const float pv[8] = {p0.x, p0.y, p0.z, p0.w, p1.x, p1.y, p1.z, p1.w};

    float gmn = 3.4e38f, gmx = -3.4e38f, dmn = 3.4e38f, dmx = -3.4e38f;
    double mo[NMOM];
#pragma unroll
    for (int m = 0; m < NMOM; ++m) mo[m] = 0.0;
    int fg = 0;
#pragma unroll
    for (int j = 0; j < 8; ++j) {
        const float gx = (uu[j+2] - uu[j]) + 2.f * (mm[j+2] - mm[j]) + (ww[j+2] - ww[j]);
        const float gy = (ww[j] - uu[j]) + 2.f * (ww[j+1] - uu[j+1]) + (ww[j+2] - uu[j+2]);
        const float gm = sqrtf(gx * gx + gy * gy + 1e-8f);
        const float lap = uu[j+1] + mm[j] + mm[j+2] + ww[j+1] - 4.f * mm[j+1];
        const float cv = tanhf(lap * 0.1f);
        const float pj = pv[j], dj = mm[j+1];
        gmn = fminf(gmn, gm); gmx = fmaxf(gmx, gm);
        dmn = fminf(dmn, dj); dmx = fmaxf(dmx, dj);
        fg += (pj > 0.5f) ? 1 : 0;
        const double pd = pj, gd = gm, dd = dj;
        const double et = (double)(pj - cv);
        mo[0] += pd;        mo[1] += pd * pd;
        mo[2] += gd;        mo[3] += gd * gd;   mo[4] += pd * gd;
        mo[5] += dd;        mo[6] += dd * dd;   mo[7] += pd * dd;
        mo[8] += et * et;
    }

    for (int o = 32; o > 0; o >>= 1) {
        gmn = fminf(gmn, __shfl_down(gmn, o));
        gmx = fmaxf(gmx, __shfl_down(gmx, o));
        dmn = fminf(dmn, __shfl_down(dmn, o));
        dmx = fmaxf(dmx, __shfl_down(dmx, o));
#pragma unroll
        for (int m = 0; m < NMOM; ++m) mo[m] += __shfl_down(mo[m], o);
        fg += __shfl_down(fg, o);
    }
    __shared__ float sg0[4], sg1[4], sd0[4], sd1[4];
    __shared__ double sa[4][NMOM];
    __shared__ int sf[4];
    const int wid = threadIdx.x >> 6, lane = threadIdx.x & 63;
    if (lane == 0) {
        sg0[wid] = gmn; sg1[wid] = gmx; sd0[wid] = dmn; sd1[wid] = dmx; sf[wid] = fg;
#pragma unroll
        for (int m = 0; m < NMOM; ++m) sa[wid][m] = mo[m];
    }
    __syncthreads();
    if (threadIdx.x == 0) {
        for (int w = 1; w < 4; ++w) {
            gmn = fminf(gmn, sg0[w]); gmx = fmaxf(gmx, sg1[w]);
            dmn = fminf(dmn, sd0[w]); dmx = fmaxf(dmx, sd1[w]);
            fg += sf[w];
#pragma unroll
            for (int m = 0; m < NMOM; ++m) mo[m] += sa[w][m];
        }
        const int bid = blockIdx.y * gridDim.x + blockIdx.x;
        pmm[bid] = make_float4(gmn, gmx, dmn, dmx);
#pragma unroll
        for (int m = 0; m < NMOM; ++m) pblk[(size_t)bid * NMOM + m] = mo[m];
        pfg[bid] = fg;
    }
}

// Stage-2 reduce. grid (IMG_B + 1 + NMOM):
__global__ void k_red(const float4* __restrict__ pmm, const double* __restrict__ pblk,
                      const int* __restrict__ pfg, Scal* s) {
    const int wid = threadIdx.x >> 6, lane = threadIdx.x & 63;
    if (blockIdx.x < IMG_B) {
        const int b = blockIdx.x;
        double ar = 0.0; int fg = 0;
        if (threadIdx.x < 128) {
            const int k = b * 128 + threadIdx.x;
            ar = pblk[(size_t)k * NMOM + 0];
            fg = pfg[k];
        }
        for (int o = 32; o > 0; o >>= 1) { ar += __shfl_down(ar, o); fg += __shfl_down(fg, o); }
        __shared__ double sa[4];
        __shared__ int sf[4];
        if (lane == 0) { sa[wid] = ar; sf[wid] = fg; }
        __syncthreads();
        if (threadIdx.x == 0) {
            ar += sa[1]; fg += sf[1];
            s->area[b] = ar; s->fgcnt[b] = fg;
        }
    } else if (blockIdx.x == IMG_B) {
        float gmn = 3.4e38f, gmx = -3.4e38f, dmn = 3.4e38f, dmx = -3.4e38f;
        for (int k = threadIdx.x; k < NPART; k += 256) {
            const float4 v = pmm[k];
            gmn = fminf(gmn, v.x); gmx = fmaxf(gmx, v.y);
            dmn = fminf(dmn, v.z); dmx = fmaxf(dmx, v.w);
        }
        for (int o = 32; o > 0; o >>= 1) {
            gmn = fminf(gmn, __shfl_down(gmn, o));
            gmx = fmaxf(gmx, __shfl_down(gmx, o));
            dmn = fminf(dmn, __shfl_down(dmn, o));
            dmx = fmaxf(dmx, __shfl_down(dmx, o));
        }
        __shared__ float sg0[4], sg1[4], sd0[4], sd1[4];
        if (lane == 0) { sg0[wid] = gmn; sg1[wid] = gmx; sd0[wid] = dmn; sd1[wid] = dmx; }
        __syncthreads();
        if (threadIdx.x == 0) {
            for (int w = 1; w < 4; ++w) {
                gmn = fminf(gmn, sg0[w]); gmx = fmaxf(gmx, sg1[w]);
                dmn = fminf(dmn, sd0[w]); dmx = fmaxf(dmx, sd1[w]);
            }
            s->gmin = gmn; s->gmax = gmx; s->dmin = dmn; s->dmax = dmx;
        }
    } else {
        const int m = blockIdx.x - IMG_B - 1;   // 0..NMOM-1
        double acc = 0.0;
        for (int k = threadIdx.x; k < NPART; k += 256) acc += pblk[(size_t)k * NMOM + m];
        for (int o = 32; o > 0; o >>= 1) acc += __shfl_down(acc, o);
        __shared__ double sa[4];
        if (lane == 0) sa[wid] = acc;
        __syncthreads();
        if (threadIdx.x == 0) {
            for (int w = 1; w < 4; ++w) acc += sa[w];
            s->mom[m] = acc;
        }
    }
}

// ---- union-find (LDS or global) ----
__device__ __forceinline__ int uf_findv(const int* L, int p) {
    while (true) { const int q = ((volatile const int*)L)[p]; if (q == p) return p; p = q; }
}
__device__ __forceinline__ void uf_merge(int* L, int a, int b) {
    while (true) {
        a = uf_findv(L, a);
        b = uf_findv(L, b);
        if (a == b) return;
        if (a < b) { int t = a; a = b; b = t; }
        const int old = atomicMin(&L[a], b);
        if (old == a) return;
        a = old;
    }
}

// ---- run bit helpers (m = 32-bit row mask, bit b set) ----
__device__ __forceinline__ int run_start(unsigned m, int b) {
    const unsigned below = ~m & ((b == 0) ? 0u : ((1u << b) - 1u));
    return below ? (int)(32u - (unsigned)__builtin_clz(below)) : 0;
}
__device__ __forceinline__ int run_len(unsigned m, int s) {
    const unsigned inv = ~(m >> s);
    return inv ? __builtin_ctz(inv) : (32 - s);
}

// ring index map (124 ring px in 128 slots):
//  i in [0,32)   -> (x=i,    y=0)
//  i in [32,64)  -> (x=i-32, y=31)
//  i in [64,94)  -> (x=0,    y=i-63)   y=1..30
//  i in [94,124) -> (x=31,   y=i-93)   y=1..30
__device__ __forceinline__ void ring_decode(int i, int& x, int& y) {
    if (i < 32)      { x = i;      y = 0;      }
    else if (i < 64) { x = i - 32; y = 31;     }
    else if (i < 94) { x = 0;      y = i - 63; }
    else             { x = 31;     y = i - 93; }
}

// Run-based local CCL: ONE WAVE per 32x32 tile (block=256 -> 4 tiles).
// Row masks via ballot (registers); union-find over run-starts in LDS;
// emits only the packed boundary graph. No barriers (wave-lockstep).
// grid (64, nimg), block 256.
__global__ void k_local(const float* __restrict__ pred, int* __restrict__ Lp,
                        int* __restrict__ Cp, int* __restrict__ nslot,
                        Scal* s, int b0) {
    const int slot = blockIdx.y;
    const float* p = pred + (size_t)(b0 + slot) * IMG_HW;
    int* L = Lp + (size_t)slot * NODES_PER_IMG;
    int* C = Cp + (size_t)slot * NODES_PER_IMG;
    const int wid = threadIdx.x >> 6, lane = threadIdx.x & 63;
    const int tile = blockIdx.x * 4 + wid;
    const int tx = (tile & 15) * 32, ty = (tile >> 4) * 32;
    const int tbase = tile * NODES_PER_TILE;
    const int r = lane;              // row index for lanes 0..31

    __shared__ int lab[4][1024];
    __shared__ int lcnt[4][1024];
    __shared__ int ns[4];
    if (lane == 0) ns[wid] = 0;

    // Phase A: build row masks via ballot; lane r keeps row r and row r-1.
    unsigned m = 0u, mp = 0u;
    for (int k = 0; k < 16; ++k) {
        const int l = k * 64 + lane;
        const float pv = p[(ty + (l >> 5)) * IMG_W + tx + (l & 31)];
        const unsigned long long bal = __ballot(pv > 0.5f);
        if ((lane >> 1) == k) m = (lane & 1) ? (unsigned)(bal >> 32) : (unsigned)bal;
        if (lane & 1) { if ((lane >> 1) == k)     mp = (unsigned)bal; }
        else          { if ((lane >> 1) == k + 1) mp = (unsigned)(bal >> 32); }
        lab[wid][l] = l;             // init UF while data streams in
        lcnt[wid][l] = 0;
    }

    // Phase B: vertical merges between overlapping runs of rows r-1, r.
    if (r >= 1 && r < 32) {
        unsigned ov = m & mp;
        while (ov) {
            const int b = __builtin_ctz(ov);
            const int sa = run_start(m, b);
            const int ea = sa + run_len(m, sa) - 1;
            const int sb = run_start(mp, b);
            const int eb = sb + run_len(mp, sb) - 1;
            uf_merge(lab[wid], r * 32 + sa, (r - 1) * 32 + sb);
            const int e = (ea < eb) ? ea : eb;
            ov = (e >= 31) ? 0u : (ov & ~((1u << (e + 1)) - 1u));
        }
    }

    // Phase C: per-run size accumulation + boundary TOUCH marking.
    if (r < 32) {
        unsigned rs = m & ~(m << 1);
        while (rs) {
            const int st = __builtin_ctz(rs); rs &= rs - 1;
            const int len = run_len(m, st);
            const int e = st + len - 1;
            const int root = uf_findv(lab[wid], r * 32 + st);
            atomicAdd(&lcnt[wid][root], len);
            if (r == 0 || r == 31 || st == 0 || e == 31)
                atomicOr(&lcnt[wid][root], TOUCH);
        }
    }

    // Phase D: roots -> interior locmax, or emit packed root node.
    // Overwrites lcnt[root] with the packed node id (ring phase reads it).
    int locmax = 0;
    if (r < 32) {
        unsigned rs = m & ~(m << 1);
        while (rs) {
            const int st = __builtin_ctz(rs); rs &= rs - 1;
            const int node = r * 32 + st;
            if (lab[wid][node] != node) continue;
            const int c = lcnt[wid][node];
            if (c & TOUCH) {
                const int sl = atomicAdd(&ns[wid], 1);
                const int gn = tbase + 128 + sl;
                L[gn] = gn;
                C[gn] = c & ~TOUCH;
                lcnt[wid][node] = gn;       // root -> packed id map
            } else {
                locmax = max(locmax, c);
            }
        }
    }
    for (int o = 32; o > 0; o >>= 1) locmax = max(locmax, __shfl_down(locmax, o));

    // Ring phase: write packed ring labels (2 slots per lane).
#pragma unroll
    for (int t = 0; t < 2; ++t) {
        const int i = lane + t * 64;
        if (i < 124) {
            int x, yy;
            ring_decode(i, x, yy);
            const unsigned my = __shfl(m, yy);
            int val = -1;
            if ((my >> x) & 1u) {
                const int node = yy * 32 + run_start(my, x);
                const int root = uf_findv(lab[wid], node);
                val = lcnt[wid][root];      // packed id (root is boundary-touching)
            }
            L[tbase + i] = val;
        } else if (i < 128) {
            L[tbase + i] = -1;
        }
    }

    if (lane == 0) {
        if (locmax > 0) atomicMax(&s->maxcnt[b0 + slot], locmax);
        nslot[slot * TILES + tile] = ns[wid];
    }
}

// Seam merges on the packed graph: 15*512*2 = 15360 edges/image.
// grid (60, nimg), block 256.
__global__ void k_bmerge(int* __restrict__ Lp) {
    const int slot = blockIdx.y;
    int* L = Lp + (size_t)slot * NODES_PER_IMG;
    const int e = blockIdx.x * 256 + threadIdx.x;
    int a, b;
    if (e < 7680) {             // vertical seam sc (0..14), y (0..511)
        const int sc = e / 512, y = e - sc * 512;
        const int ly = y & 31;
        const int tL = (y >> 5) * 16 + sc;
        const int iL = (ly == 0) ? 31 : (ly == 31) ? 63 : (93 + ly);  // (31,ly)
        const int iR = (ly == 0) ? 0  : (ly == 31) ? 32 : (63 + ly);  // (0,ly)
        a = tL * NODES_PER_TILE + iL;
        b = (tL + 1) * NODES_PER_TILE + iR;
    } else {                    // horizontal seam sr (0..14), x (0..511)
        const int e2 = e - 7680;
        const int sr = e2 / 512, x = e2 - sr * 512;
        const int lx = x & 31;
        const int tT = sr * 16 + (x >> 5);
        a = tT * NODES_PER_TILE + 32 + lx;                 // (lx,31)
        b = (tT + 16) * NODES_PER_TILE + lx;               // (lx,0)
    }
    if (L[a] >= 0 && L[b] >= 0) uf_merge(L, a, b);
}

// Flush: listed roots (slots 128..128+ns) push size to their global root.
// grid (64, nimg), block 256 -> 16384 slots/image.
__global__ void k_lflush(const int* __restrict__ Lp, int* __restrict__ Cp,
                         const int* __restrict__ nslot) {
    const int img = blockIdx.y;
    const int* L = Lp + (size_t)img * NODES_PER_IMG;
    int* C = Cp + (size_t)img * NODES_PER_IMG;
    const int sidx = blockIdx.x * 256 + threadIdx.x;
    const int tile = sidx >> 6, sl = sidx & 63;
    if (sl >= nslot[img * TILES + tile]) return;
    const int g = tile * NODES_PER_TILE + 128 + sl;
    const int rt = uf_findv(L, g);
    if (rt != g) atomicAdd(&C[rt], C[g]);
}

// Max over global roots of the packed graph.
__global__ void k_lmax(const int* __restrict__ Lp, const int* __restrict__ Cp,
                       const int* __restrict__ nslot, Scal* s, int b0) {
    const int img = blockIdx.y;
    const int* L = Lp + (size_t)img * NODES_PER_IMG;
    const int* C = Cp + (size_t)img * NODES_PER_IMG;
    const int sidx = blockIdx.x * 256 + threadIdx.x;
    const int tile = sidx >> 6, sl = sidx & 63;
    int m = 0;
    if (sl < nslot[img * TILES + tile]) {
        const int g = tile * NODES_PER_TILE + 128 + sl;
        if (L[g] == g) m = C[g];
    }
    for (int o = 32; o > 0; o >>= 1) m = max(m, __shfl_down(m, o));
    __shared__ int sm[4];
    const int wid = threadIdx.x >> 6, lane = threadIdx.x & 63;
    if (lane == 0) sm[wid] = m;
    __syncthreads();
    if (threadIdx.x == 0) {
        for (int w = 1; w < 4; ++w) m = max(m, sm[w]);
        if (m > 0) atomicMax(&s->maxcnt[b0 + img], m);
    }
}

// Final: closed-form similarity from moments + conn + scale. 1 thread.
__global__ void k_final(const Scal* __restrict__ s, float* __restrict__ out) {
    const double N = (double)IMG_B * (double)IMG_HW;
    const float gdenf = s->gmax - s->gmin + 1e-8f;
    const float ddenf = s->dmax - s->dmin + 1e-8f;
    const double a = 1.0 / (double)gdenf, bb = 1.0 / (double)ddenf;
    const double gmin = (double)s->gmin, dmin = (double)s->dmin;
    const double S_p = s->mom[0], S_pp = s->mom[1];
    const double S_g = s->mom[2], S_gg = s->mom[3], S_pg = s->mom[4];
    const double S_d = s->mom[5], S_dd = s->mom[6], S_pd = s->mom[7];
    const double S_t = s->mom[8];
    const double sum_g = S_pp - 2.0 * a * (S_pg - gmin * S_p)
                       + a * a * (S_gg - 2.0 * gmin * S_g + gmin * gmin * N);
    const double sum_d = S_pp - 2.0 * bb * (S_pd - dmin * S_p)
                       + bb * bb * (S_dd - 2.0 * dmin * S_d + dmin * dmin * N);
    const double sim = (sum_g + sum_d + S_t) / (3.0 * N);

    const double tp = (double)IMG_HW;
    const double tmin = 0.1 * tp, tmax = 0.3 * tp;
    double conn = 0.0, scale = 0.0;
    for (int b = 0; b < IMG_B; ++b) {
        const int total = s->fgcnt[b];
        if (total > 0) conn += 1.0 - (double)s->maxcnt[b] / (double)total;
        const double ar = s->area[b];
        scale += fmax(ar - tmax, 0.0) + fmax(tmin - ar, 0.0);
    }
    conn /= (double)IMG_B;
    scale = (scale / (double)IMG_B) / tp;
    const double total = sim + 0.1 * conn + 0.05 * scale;
    out[0] = (float)(0.1 * total);
}

extern "C" void kernel_launch(void* const* d_in, const int* in_sizes, int n_in,
                              void* d_out, int out_size, void* d_ws, size_t ws_size,
                              hipStream_t stream) {
    const float* pred = (const float*)d_in[0];  // [16,1,512,512]
    const float* dem  = (const float*)d_in[1];  // [16,1,512,512]
    float* out = (float*)d_out;

    char* ws = (char*)d_ws;
    Scal* s = (Scal*)ws;
    float4* pmm  = (float4*)(ws + OFF_PMM);
    double* pblk = (double*)(ws + OFF_MOM);
    int*    pfg  = (int*)(ws + OFF_FG);
    int* scratch = (int*)(ws + OFF_SCR);
    const size_t avail_ints = (ws_size > OFF_SCR) ? (ws_size - OFF_SCR) / 4 : 0;
    // per image: packed labels + packed counts + nslot
    const size_t per_img = 2ull * NODES_PER_IMG + TILES;

    hipLaunchKernelGGL(k_init_scal, dim3(1), dim3(64), 0, stream, s);
    hipLaunchKernelGGL(k_feat, dim3(128, IMG_B), dim3(256), 0, stream,
                       dem, pred, pmm, pblk, pfg);
    hipLaunchKernelGGL(k_red, dim3(IMG_B + 1 + NMOM), dim3(256), 0, stream, pmm, pblk, pfg, s);

    long long chunk = (long long)(avail_ints / per_img);
    if (chunk < 1) chunk = 1;
    if (chunk > IMG_B) chunk = IMG_B;
    for (int b0 = 0; b0 < IMG_B; b0 += (int)chunk) {
        const int n = (int)((b0 + chunk <= IMG_B) ? chunk : (IMG_B - b0));
        int* Lp    = scratch;
        int* Cp    = scratch + (size_t)chunk * NODES_PER_IMG;
        int* nslot = scratch + 2ull * chunk * NODES_PER_IMG;
        hipLaunchKernelGGL(k_local,  dim3(64, n), dim3(256), 0, stream,
                           pred, Lp, Cp, nslot, s, b0);
        hipLaunchKernelGGL(k_bmerge, dim3(60, n), dim3(256), 0, stream, Lp);
        hipLaunchKernelGGL(k_lflush, dim3(64, n), dim3(256), 0, stream, Lp, Cp, nslot);
        hipLaunchKernelGGL(k_lmax,   dim3(64, n), dim3(256), 0, stream, Lp, Cp, nslot, s, b0);
    }

    hipLaunchKernelGGL(k_final, dim3(1), dim3(1), 0, stream, s, out);
}

// Round 9
// 99.667 us; speedup vs baseline: 4.0669x; 1.0339x over previous
//
#include <hip/hip_runtime.h>
#include <math.h>

#define IMG_B 16
#define IMG_H 512
#define IMG_W 512
#define IMG_HW (IMG_H * IMG_W)
#define NPART 2048            // 128 blocks/image * 16 images

// moment indices: 0:S_p 1:S_pp 2:S_g 3:S_gg 4:S_pg 5:S_d 6:S_dd 7:S_pd 8:S_t
#define NMOM 9

// 32x32 tile CCL, packed boundary graph: per tile 192 nodes
//   slots 0..127  : ring pixels (ring index map below)
//   slots 128..191: boundary-component roots (compacted)
#define TILES 256             // per image (16x16)
#define NODES_PER_TILE 192
#define NODES_PER_IMG (TILES * NODES_PER_TILE)   // 49152
#define TOUCH (1 << 30)

struct Scal {
    float gmin, gmax, dmin, dmax;
    double mom[NMOM];
    double area[IMG_B];
    int fgcnt[IMG_B];
    int maxcnt[IMG_B];
};

// ws layout (bytes):
//   0       Scal (padded to 512)
//   512     float4 pmm[NPART]            (32768)  per-block {gmn,gmx,dmn,dmx}
//   33280   double pblk[NPART][NMOM]     (147456) per-block moment partials
//   180736  int    pfg[NPART]            (8192)
//   188928  scratch: packed labels / counts / nslot
#define OFF_PMM   512
#define OFF_MOM   33280
#define OFF_FG    180736
#define OFF_SCR   188928

// Pass 1: stencil + ALL similarity moments + min/max + per-image area/fg.
// grid (128, B), block 256, 8 contiguous px/thread. No global atomics.
// Moments accumulate f32 per-thread (8 values -> error ~1e-6 abs per partial,
// sqrt(256K) random-walk ~5e-4 abs on ~1e6 sums -> ~4e-11 on the loss), f64 across lanes.
__global__ void k_feat(const float* __restrict__ dem, const float* __restrict__ pred,
                       float4* __restrict__ pmm, double* __restrict__ pblk,
                       int* __restrict__ pfg) {
    const int b = blockIdx.y;
    const size_t off = (size_t)b * IMG_HW;
    const float* d = dem + off;
    const float* p = pred + off;
    const int base = blockIdx.x * 2048 + threadIdx.x * 8;
    const int y = base >> 9, x0 = base & 511;

    const float4 z4 = make_float4(0.f, 0.f, 0.f, 0.f);
    float4 m0 = *(const float4*)(d + base);
    float4 m1 = *(const float4*)(d + base + 4);
    float4 u0 = z4, u1 = z4, w0 = z4, w1 = z4;
    if (y > 0)         { u0 = *(const float4*)(d + base - 512); u1 = *(const float4*)(d + base - 508); }
    if (y < IMG_H - 1) { w0 = *(const float4*)(d + base + 512); w1 = *(const float4*)(d + base + 516); }

    float uu[10], mm[10], ww[10];
    mm[0] = (x0 > 0)              ? d[base - 1]   : 0.f;
    mm[9] = (x0 != 504)           ? d[base + 8]   : 0.f;
    uu[0] = (y > 0 && x0 > 0)     ? d[base - 513] : 0.f;
    uu[9] = (y > 0 && x0 != 504)  ? d[base - 504] : 0.f;
    ww[0] = (y < 511 && x0 > 0)   ? d[base + 511] : 0.f;
    ww[9] = (y < 511 && x0 != 504)? d[base + 520] : 0.f;
    uu[1]=u0.x; uu[2]=u0.y; uu[3]=u0.z; uu[4]=u0.w; uu[5]=u1.x; uu[6]=u1.y; uu[7]=u1.z; uu[8]=u1.w;
    mm[1]=m0.x; mm[2]=m0.y; mm[3]=m0.z; mm[4]=m0.w; mm[5]=m1.x; mm[6]=m1.y; mm[7]=m1.z; mm[8]=m1.w;
    ww[1]=w0.x; ww[2]=w0.y; ww[3]=w0.z; ww[4]=w0.w; ww[5]=w1.x; ww[6]=w1.y; ww[7]=w1.z; ww[8]=w1.w;

    const float4 p0 = *(const float4*)(p + base);
    const float4 p1 = *(const float4*)(p + base + 4);
    const float pv[8] = {p0.x, p0.y, p0.z, p0.w, p1.x, p1.y, p1.z, p1.w};

    float gmn = 3.4e38f, gmx = -3.4e38f, dmn = 3.4e38f, dmx = -3.4e38f;
    float mf[NMOM];
#pragma unroll
    for (int m = 0; m < NMOM; ++m) mf[m] = 0.f;
    int fg = 0;
#pragma unroll
    for (int j = 0; j < 8; ++j) {
        const float gx = (uu[j+2] - uu[j]) + 2.f * (mm[j+2] - mm[j]) + (ww[j+2] - ww[j]);
        const float gy = (ww[j] - uu[j]) + 2.f * (ww[j+1] - uu[j+1]) + (ww[j+2] - uu[j+2]);
        const float gm = sqrtf(gx * gx + gy * gy + 1e-8f);
        const float lap = uu[j+1] + mm[j] + mm[j+2] + ww[j+1] - 4.f * mm[j+1];
        const float cv = tanhf(lap * 0.1f);
        const float pj = pv[j], dj = mm[j+1];
        gmn = fminf(gmn, gm); gmx = fmaxf(gmx, gm);
        dmn = fminf(dmn, dj); dmx = fmaxf(dmx, dj);
        fg += (pj > 0.5f) ? 1 : 0;
        const float et = pj - cv;
        mf[0] += pj;        mf[1] += pj * pj;
        mf[2] += gm;        mf[3] += gm * gm;   mf[4] += pj * gm;
        mf[5] += dj;        mf[6] += dj * dj;   mf[7] += pj * dj;
        mf[8] += et * et;
    }
    double mo[NMOM];
#pragma unroll
    for (int m = 0; m < NMOM; ++m) mo[m] = (double)mf[m];

    for (int o = 32; o > 0; o >>= 1) {
        gmn = fminf(gmn, __shfl_down(gmn, o));
        gmx = fmaxf(gmx, __shfl_down(gmx, o));
        dmn = fminf(dmn, __shfl_down(dmn, o));
        dmx = fmaxf(dmx, __shfl_down(dmx, o));
#pragma unroll
        for (int m = 0; m < NMOM; ++m) mo[m] += __shfl_down(mo[m], o);
        fg += __shfl_down(fg, o);
    }
    __shared__ float sg0[4], sg1[4], sd0[4], sd1[4];
    __shared__ double sa[4][NMOM];
    __shared__ int sf[4];
    const int wid = threadIdx.x >> 6, lane = threadIdx.x & 63;
    if (lane == 0) {
        sg0[wid] = gmn; sg1[wid] = gmx; sd0[wid] = dmn; sd1[wid] = dmx; sf[wid] = fg;
#pragma unroll
        for (int m = 0; m < NMOM; ++m) sa[wid][m] = mo[m];
    }
    __syncthreads();
    if (threadIdx.x == 0) {
        for (int w = 1; w < 4; ++w) {
            gmn = fminf(gmn, sg0[w]); gmx = fmaxf(gmx, sg1[w]);
            dmn = fminf(dmn, sd0[w]); dmx = fmaxf(dmx, sd1[w]);
            fg += sf[w];
#pragma unroll
            for (int m = 0; m < NMOM; ++m) mo[m] += sa[w][m];
        }
        const int bid = blockIdx.y * gridDim.x + blockIdx.x;
        pmm[bid] = make_float4(gmn, gmx, dmn, dmx);
#pragma unroll
        for (int m = 0; m < NMOM; ++m) pblk[(size_t)bid * NMOM + m] = mo[m];
        pfg[bid] = fg;
    }
}

// Stage-2 reduce (also inits per-image maxcnt; replaces k_init_scal).
// grid (IMG_B + 1 + NMOM).
__global__ void k_red(const float4* __restrict__ pmm, const double* __restrict__ pblk,
                      const int* __restrict__ pfg, Scal* s) {
    const int wid = threadIdx.x >> 6, lane = threadIdx.x & 63;
    if (blockIdx.x < IMG_B) {
        const int b = blockIdx.x;
        double ar = 0.0; int fg = 0;
        if (threadIdx.x < 128) {
            const int k = b * 128 + threadIdx.x;
            ar = pblk[(size_t)k * NMOM + 0];
            fg = pfg[k];
        }
        for (int o = 32; o > 0; o >>= 1) { ar += __shfl_down(ar, o); fg += __shfl_down(fg, o); }
        __shared__ double sa[4];
        __shared__ int sf[4];
        if (lane == 0) { sa[wid] = ar; sf[wid] = fg; }
        __syncthreads();
        if (threadIdx.x == 0) {
            ar += sa[1]; fg += sf[1];
            s->area[b] = ar; s->fgcnt[b] = fg;
            s->maxcnt[b] = 0;
        }
    } else if (blockIdx.x == IMG_B) {
        float gmn = 3.4e38f, gmx = -3.4e38f, dmn = 3.4e38f, dmx = -3.4e38f;
        for (int k = threadIdx.x; k < NPART; k += 256) {
            const float4 v = pmm[k];
            gmn = fminf(gmn, v.x); gmx = fmaxf(gmx, v.y);
            dmn = fminf(dmn, v.z); dmx = fmaxf(dmx, v.w);
        }
        for (int o = 32; o > 0; o >>= 1) {
            gmn = fminf(gmn, __shfl_down(gmn, o));
            gmx = fmaxf(gmx, __shfl_down(gmx, o));
            dmn = fminf(dmn, __shfl_down(dmn, o));
            dmx = fmaxf(dmx, __shfl_down(dmx, o));
        }
        __shared__ float sg0[4], sg1[4], sd0[4], sd1[4];
        if (lane == 0) { sg0[wid] = gmn; sg1[wid] = gmx; sd0[wid] = dmn; sd1[wid] = dmx; }
        __syncthreads();
        if (threadIdx.x == 0) {
            for (int w = 1; w < 4; ++w) {
                gmn = fminf(gmn, sg0[w]); gmx = fmaxf(gmx, sg1[w]);
                dmn = fminf(dmn, sd0[w]); dmx = fmaxf(dmx, sd1[w]);
            }
            s->gmin = gmn; s->gmax = gmx; s->dmin = dmn; s->dmax = dmx;
        }
    } else {
        const int m = blockIdx.x - IMG_B - 1;   // 0..NMOM-1
        double acc = 0.0;
        for (int k = threadIdx.x; k < NPART; k += 256) acc += pblk[(size_t)k * NMOM + m];
        for (int o = 32; o > 0; o >>= 1) acc += __shfl_down(acc, o);
        __shared__ double sa[4];
        if (lane == 0) sa[wid] = acc;
        __syncthreads();
        if (threadIdx.x == 0) {
            for (int w = 1; w < 4; ++w) acc += sa[w];
            s->mom[m] = acc;
        }
    }
}

// ---- union-find (LDS or global) ----
__device__ __forceinline__ int uf_findv(const int* L, int p) {
    while (true) { const int q = ((volatile const int*)L)[p]; if (q == p) return p; p = q; }
}
__device__ __forceinline__ void uf_merge(int* L, int a, int b) {
    while (true) {
        a = uf_findv(L, a);
        b = uf_findv(L, b);
        if (a == b) return;
        if (a < b) { int t = a; a = b; b = t; }
        const int old = atomicMin(&L[a], b);
        if (old == a) return;
        a = old;
    }
}

// ---- run bit helpers (m = 32-bit row mask, bit b set) ----
__device__ __forceinline__ int run_start(unsigned m, int b) {
    const unsigned below = ~m & ((b == 0) ? 0u : ((1u << b) - 1u));
    return below ? (int)(32u - (unsigned)__builtin_clz(below)) : 0;
}
__device__ __forceinline__ int run_len(unsigned m, int s) {
    const unsigned inv = ~(m >> s);
    return inv ? __builtin_ctz(inv) : (32 - s);
}
// index of the run containing set-bit column c (sm = run-start mask of m)
__device__ __forceinline__ int run_idx(unsigned sm, int c) {
    return __popc(sm & (unsigned)((2ull << c) - 1ull)) - 1;
}

// ring index map (124 ring px in 128 slots):
//  i in [0,32)   -> (x=i,    y=0)
//  i in [32,64)  -> (x=i-32, y=31)
//  i in [64,94)  -> (x=0,    y=i-63)   y=1..30
//  i in [94,124) -> (x=31,   y=i-93)   y=1..30
__device__ __forceinline__ void ring_decode(int i, int& x, int& y) {
    if (i < 32)      { x = i;      y = 0;      }
    else if (i < 64) { x = i - 32; y = 31;     }
    else if (i < 94) { x = 0;      y = i - 63; }
    else             { x = 31;     y = i - 93; }
}

// Run-based local CCL: ONE WAVE per 32x32 tile (block=256 -> 4 tiles).
// Compressed UF over run nodes (node = row*16 + runidx, 512/tile, 16KB LDS).
// After vertical merges: 4 rounds of wave-parallel pointer jumping flatten
// all trees (monotone-decreasing parents -> benign races), so later finds
// are O(1) instead of ~120cy/hop LDS chains. No barriers (wave-lockstep).
// grid (64, nimg), block 256.
__global__ void k_local(const float* __restrict__ pred, int* __restrict__ Lp,
                        int* __restrict__ Cp, int* __restrict__ nslot,
                        Scal* s, int b0) {
    const int slot = blockIdx.y;
    const float* p = pred + (size_t)(b0 + slot) * IMG_HW;
    int* L = Lp + (size_t)slot * NODES_PER_IMG;
    int* C = Cp + (size_t)slot * NODES_PER_IMG;
    const int wid = threadIdx.x >> 6, lane = threadIdx.x & 63;
    const int tile = blockIdx.x * 4 + wid;
    const int tx = (tile & 15) * 32, ty = (tile >> 4) * 32;
    const int tbase = tile * NODES_PER_TILE;
    const int r = lane;              // row index for lanes 0..31

    __shared__ int lab[4][512];
    __shared__ int lcnt[4][512];
    __shared__ int ns[4];
    if (lane == 0) ns[wid] = 0;
    int* labw = lab[wid];
    int* lcw  = lcnt[wid];

    // Phase A: build row masks via ballot; lane r keeps row r and row r-1.
    unsigned m = 0u, mp = 0u;
    for (int k = 0; k < 16; ++k) {
        const int l = k * 64 + lane;
        const float pv = p[(ty + (l >> 5)) * IMG_W + tx + (l & 31)];
        const unsigned long long bal = __ballot(pv > 0.5f);
        if ((lane >> 1) == k) m = (lane & 1) ? (unsigned)(bal >> 32) : (unsigned)bal;
        if (lane & 1) { if ((lane >> 1) == k)     mp = (unsigned)bal; }
        else          { if ((lane >> 1) == k + 1) mp = (unsigned)(bal >> 32); }
    }
    // init compressed UF arrays (8 nodes/lane, conflict-free)
#pragma unroll
    for (int k = 0; k < 8; ++k) {
        const int n = k * 64 + lane;
        labw[n] = n; lcw[n] = 0;
    }

    const unsigned sm  = m  & ~(m << 1);
    const unsigned smp = mp & ~(mp << 1);

    // Phase B: vertical merges between overlapping runs of rows r-1, r.
    if (r >= 1 && r < 32) {
        unsigned ov = m & mp;
        while (ov) {
            const int bpos = __builtin_ctz(ov);
            const int sa = run_start(m, bpos);
            const int ea = sa + run_len(m, sa) - 1;
            const int sb = run_start(mp, bpos);
            const int eb = sb + run_len(mp, sb) - 1;
            uf_merge(labw, r * 16 + run_idx(sm, sa), (r - 1) * 16 + run_idx(smp, sb));
            const int e = (ea < eb) ? ea : eb;
            ov = (e >= 31) ? 0u : (ov & ~((1u << (e + 1)) - 1u));
        }
    }

    // Pointer jumping: flatten trees (parents strictly decrease -> benign races).
#pragma unroll
    for (int rd = 0; rd < 4; ++rd) {
#pragma unroll
        for (int k = 0; k < 8; ++k) {
            const int n = k * 64 + lane;
            const int q  = ((volatile int*)labw)[n];
            const int qq = ((volatile int*)labw)[q];
            if (qq != q) labw[n] = qq;
        }
    }

    // Phase C: per-run size accumulation + boundary TOUCH + path compression.
    if (r < 32) {
        unsigned rs = sm; int j = 0;
        while (rs) {
            const int st = __builtin_ctz(rs); rs &= rs - 1;
            const int len = run_len(m, st);
            const int e = st + len - 1;
            const int node = r * 16 + j; ++j;
            const int root = uf_findv(labw, node);
            if (root != node) labw[node] = root;
            atomicAdd(&lcw[root], len);
            if (r == 0 || r == 31 || st == 0 || e == 31)
                atomicOr(&lcw[root], TOUCH);
        }
    }

    // Phase D: roots -> interior locmax, or emit packed root node.
    // Overwrites lcw[root] with the packed node id (ring phase reads it).
    int locmax = 0;
    if (r < 32) {
        unsigned rs = sm; int j = 0;
        while (rs) {
            rs &= rs - 1;
            const int node = r * 16 + j; ++j;
            if (labw[node] != node) continue;
            const int c = lcw[node];
            if (c & TOUCH) {
                const int sl = atomicAdd(&ns[wid], 1);
                const int gn = tbase + 128 + sl;
                L[gn] = gn;
                C[gn] = c & ~TOUCH;
                lcw[node] = gn;       // root -> packed id map
            } else {
                locmax = max(locmax, c);
            }
        }
    }
    for (int o = 32; o > 0; o >>= 1) locmax = max(locmax, __shfl_down(locmax, o));

    // Ring phase: write packed ring labels (2 slots per lane).
#pragma unroll
    for (int t = 0; t < 2; ++t) {
        const int i = lane + t * 64;
        if (i < 124) {
            int x, yy;
            ring_decode(i, x, yy);
            const unsigned my = (unsigned)__shfl((int)m, yy);
            int val = -1;
            if ((my >> x) & 1u) {
                const unsigned smy = my & ~(my << 1);
                const int node = yy * 16 + run_idx(smy, x);
                const int root = uf_findv(labw, node);
                val = lcw[root];      // packed id (root is boundary-touching)
            }
            L[tbase + i] = val;
        } else if (i < 128) {
            L[tbase + i] = -1;
        }
    }

    if (lane == 0) {
        if (locmax > 0) atomicMax(&s->maxcnt[b0 + slot], locmax);
        nslot[slot * TILES + tile] = ns[wid];
    }
}

// Seam merges on the packed graph: 15*512*2 = 15360 edges/image.
// grid (60, nimg), block 256.
__global__ void k_bmerge(int* __restrict__ Lp) {
    const int slot = blockIdx.y;
    int* L = Lp + (size_t)slot * NODES_PER_IMG;
    const int e = blockIdx.x * 256 + threadIdx.x;
    int a, b;
    if (e < 7680) {             // vertical seam sc (0..14), y (0..511)
        const int sc = e / 512, y = e - sc * 512;
        const int ly = y & 31;
        const int tL = (y >> 5) * 16 + sc;
        const int iL = (ly == 0) ? 31 : (ly == 31) ? 63 : (93 + ly);  // (31,ly)
        const int iR = (ly == 0) ? 0  : (ly == 31) ? 32 : (63 + ly);  // (0,ly)
        a = tL * NODES_PER_TILE + iL;
        b = (tL + 1) * NODES_PER_TILE + iR;
    } else {                    // horizontal seam sr (0..14), x (0..511)
        const int e2 = e - 7680;
        const int sr = e2 / 512, x = e2 - sr * 512;
        const int lx = x & 31;
        const int tT = sr * 16 + (x >> 5);
        a = tT * NODES_PER_TILE + 32 + lx;                 // (lx,31)
        b = (tT + 16) * NODES_PER_TILE + lx;               // (lx,0)
    }
    if (L[a] >= 0 && L[b] >= 0) uf_merge(L, a, b);
}

// Flush: listed roots (slots 128..128+ns) push size to their global root.
// grid (64, nimg), block 256 -> 16384 slots/image.
__global__ void k_lflush(const int* __restrict__ Lp, int* __restrict__ Cp,
                         const int* __restrict__ nslot) {
    const int img = blockIdx.y;
    const int* L = Lp + (size_t)img * NODES_PER_IMG;
    int* C = Cp + (size_t)img * NODES_PER_IMG;
    const int sidx = blockIdx.x * 256 + threadIdx.x;
    const int tile = sidx >> 6, sl = sidx & 63;
    if (sl >= nslot[img * TILES + tile]) return;
    const int g = tile * NODES_PER_TILE + 128 + sl;
    const int rt = uf_findv(L, g);
    if (rt != g) atomicAdd(&C[rt], C[g]);
}

// Max over global roots of the packed graph.
__global__ void k_lmax(const int* __restrict__ Lp, const int* __restrict__ Cp,
                       const int* __restrict__ nslot, Scal* s, int b0) {
    const int img = blockIdx.y;
    const int* L = Lp + (size_t)img * NODES_PER_IMG;
    const int* C = Cp + (size_t)img * NODES_PER_IMG;
    const int sidx = blockIdx.x * 256 + threadIdx.x;
    const int tile = sidx >> 6, sl = sidx & 63;
    int m = 0;
    if (sl < nslot[img * TILES + tile]) {
        const int g = tile * NODES_PER_TILE + 128 + sl;
        if (L[g] == g) m = C[g];
    }
    for (int o = 32; o > 0; o >>= 1) m = max(m, __shfl_down(m, o));
    __shared__ int sm[4];
    const int wid = threadIdx.x >> 6, lane = threadIdx.x & 63;
    if (lane == 0) sm[wid] = m;
    __syncthreads();
    if (threadIdx.x == 0) {
        for (int w = 1; w < 4; ++w) m = max(m, sm[w]);
        if (m > 0) atomicMax(&s->maxcnt[b0 + img], m);
    }
}

// Final: closed-form similarity from moments + conn + scale. 1 thread.
__global__ void k_final(const Scal* __restrict__ s, float* __restrict__ out) {
    const double N = (double)IMG_B * (double)IMG_HW;
    const float gdenf = s->gmax - s->gmin + 1e-8f;
    const float ddenf = s->dmax - s->dmin + 1e-8f;
    const double a = 1.0 / (double)gdenf, bb = 1.0 / (double)ddenf;
    const double gmin = (double)s->gmin, dmin = (double)s->dmin;
    const double S_p = s->mom[0], S_pp = s->mom[1];
    const double S_g = s->mom[2], S_gg = s->mom[3], S_pg = s->mom[4];
    const double S_d = s->mom[5], S_dd = s->mom[6], S_pd = s->mom[7];
    const double S_t = s->mom[8];
    const double sum_g = S_pp - 2.0 * a * (S_pg - gmin * S_p)
                       + a * a * (S_gg - 2.0 * gmin * S_g + gmin * gmin * N);
    const double sum_d = S_pp - 2.0 * bb * (S_pd - dmin * S_p)
                       + bb * bb * (S_dd - 2.0 * dmin * S_d + dmin * dmin * N);
    const double sim = (sum_g + sum_d + S_t) / (3.0 * N);

    const double tp = (double)IMG_HW;
    const double tmin = 0.1 * tp, tmax = 0.3 * tp;
    double conn = 0.0, scale = 0.0;
    for (int b = 0; b < IMG_B; ++b) {
        const int total = s->fgcnt[b];
        if (total > 0) conn += 1.0 - (double)s->maxcnt[b] / (double)total;
        const double ar = s->area[b];
        scale += fmax(ar - tmax, 0.0) + fmax(tmin - ar, 0.0);
    }
    conn /= (double)IMG_B;
    scale = (scale / (double)IMG_B) / tp;
    const double total = sim + 0.1 * conn + 0.05 * scale;
    out[0] = (float)(0.1 * total);
}

extern "C" void kernel_launch(void* const* d_in, const int* in_sizes, int n_in,
                              void* d_out, int out_size, void* d_ws, size_t ws_size,
                              hipStream_t stream) {
    const float* pred = (const float*)d_in[0];  // [16,1,512,512]
    const float* dem  = (const float*)d_in[1];  // [16,1,512,512]
    float* out = (float*)d_out;

    char* ws = (char*)d_ws;
    Scal* s = (Scal*)ws;
    float4* pmm  = (float4*)(ws + OFF_PMM);
    double* pblk = (double*)(ws + OFF_MOM);
    int*    pfg  = (int*)(ws + OFF_FG);
    int* scratch = (int*)(ws + OFF_SCR);
    const size_t avail_ints = (ws_size > OFF_SCR) ? (ws_size - OFF_SCR) / 4 : 0;
    // per image: packed labels + packed counts + nslot
    const size_t per_img = 2ull * NODES_PER_IMG + TILES;

    hipLaunchKernelGGL(k_feat, dim3(128, IMG_B), dim3(256), 0, stream,
                       dem, pred, pmm, pblk, pfg);
    hipLaunchKernelGGL(k_red, dim3(IMG_B + 1 + NMOM), dim3(256), 0, stream, pmm, pblk, pfg, s);

    long long chunk = (long long)(avail_ints / per_img);
    if (chunk < 1) chunk = 1;
    if (chunk > IMG_B) chunk = IMG_B;
    for (int b0 = 0; b0 < IMG_B; b0 += (int)chunk) {
        const int n = (int)((b0 + chunk <= IMG_B) ? chunk : (IMG_B - b0));
        int* Lp    = scratch;
        int* Cp    = scratch + (size_t)chunk * NODES_PER_IMG;
        int* nslot = scratch + 2ull * chunk * NODES_PER_IMG;
        hipLaunchKernelGGL(k_local,  dim3(64, n), dim3(256), 0, stream,
                           pred, Lp, Cp, nslot, s, b0);
        hipLaunchKernelGGL(k_bmerge, dim3(60, n), dim3(256), 0, stream, Lp);
        hipLaunchKernelGGL(k_lflush, dim3(64, n), dim3(256), 0, stream, Lp, Cp, nslot);
        hipLaunchKernelGGL(k_lmax,   dim3(64, n), dim3(256), 0, stream, Lp, Cp, nslot, s, b0);
    }

    hipLaunchKernelGGL(k_final, dim3(1), dim3(1), 0, stream, s, out);
}

// Round 10
// 84.064 us; speedup vs baseline: 4.8217x; 1.1856x over previous
//
#include <hip/hip_runtime.h>
#include <math.h>

#define IMG_B 16
#define IMG_H 512
#define IMG_W 512
#define IMG_HW (IMG_H * IMG_W)
#define NPART 2048            // 128 blocks/image * 16 images

// moment indices: 0:S_p 1:S_pp 2:S_g 3:S_gg 4:S_pg 5:S_d 6:S_dd 7:S_pd 8:S_t
#define NMOM 9

// 32x32 tile CCL, packed boundary graph: per tile 192 nodes
//   slots 0..127  : ring pixels (ring index map below)
//   slots 128..191: boundary-component roots (compacted)
#define TILES 256             // per image (16x16)
#define NODES_PER_TILE 192
#define NODES_PER_IMG (TILES * NODES_PER_TILE)   // 49152
#define TOUCH (1 << 30)

struct Scal {
    float gmin, gmax, dmin, dmax;
    double mom[NMOM];
    double area[IMG_B];
    int fgcnt[IMG_B];
    int maxcnt[IMG_B];
};

// ws layout (bytes):
//   0       Scal (padded to 512)
//   512     float4 pmm[NPART]            (32768)  per-block {gmn,gmx,dmn,dmx}
//   33280   double pblk[NPART][NMOM]     (147456) per-block moment partials
//   180736  int    pfg[NPART]            (8192)
//   188928  scratch: packed labels / counts / nslot
#define OFF_PMM   512
#define OFF_MOM   33280
#define OFF_FG    180736
#define OFF_SCR   188928

// Pass 1: stencil + ALL similarity moments + min/max + per-image area/fg.
// grid (128, B), block 256, 8 contiguous px/thread. No global atomics.
__global__ void k_feat(const float* __restrict__ dem, const float* __restrict__ pred,
                       float4* __restrict__ pmm, double* __restrict__ pblk,
                       int* __restrict__ pfg) {
    const int b = blockIdx.y;
    const size_t off = (size_t)b * IMG_HW;
    const float* d = dem + off;
    const float* p = pred + off;
    const int base = blockIdx.x * 2048 + threadIdx.x * 8;
    const int y = base >> 9, x0 = base & 511;

    const float4 z4 = make_float4(0.f, 0.f, 0.f, 0.f);
    float4 m0 = *(const float4*)(d + base);
    float4 m1 = *(const float4*)(d + base + 4);
    float4 u0 = z4, u1 = z4, w0 = z4, w1 = z4;
    if (y > 0)         { u0 = *(const float4*)(d + base - 512); u1 = *(const float4*)(d + base - 508); }
    if (y < IMG_H - 1) { w0 = *(const float4*)(d + base + 512); w1 = *(const float4*)(d + base + 516); }

    float uu[10], mm[10], ww[10];
    mm[0] = (x0 > 0)              ? d[base - 1]   : 0.f;
    mm[9] = (x0 != 504)           ? d[base + 8]   : 0.f;
    uu[0] = (y > 0 && x0 > 0)     ? d[base - 513] : 0.f;
    uu[9] = (y > 0 && x0 != 504)  ? d[base - 504] : 0.f;
    ww[0] = (y < 511 && x0 > 0)   ? d[base + 511] : 0.f;
    ww[9] = (y < 511 && x0 != 504)? d[base + 520] : 0.f;
    uu[1]=u0.x; uu[2]=u0.y; uu[3]=u0.z; uu[4]=u0.w; uu[5]=u1.x; uu[6]=u1.y; uu[7]=u1.z; uu[8]=u1.w;
    mm[1]=m0.x; mm[2]=m0.y; mm[3]=m0.z; mm[4]=m0.w; mm[5]=m1.x; mm[6]=m1.y; mm[7]=m1.z; mm[8]=m1.w;
    ww[1]=w0.x; ww[2]=w0.y; ww[3]=w0.z; ww[4]=w0.w; ww[5]=w1.x; ww[6]=w1.y; ww[7]=w1.z; ww[8]=w1.w;

    const float4 p0 = *(const float4*)(p + base);
    const float4 p1 = *(const float4*)(p + base + 4);
    const float pv[8] = {p0.x, p0.y, p0.z, p0.w, p1.x, p1.y, p1.z, p1.w};

    float gmn = 3.4e38f, gmx = -3.4e38f, dmn = 3.4e38f, dmx = -3.4e38f;
    float mf[NMOM];
#pragma unroll
    for (int m = 0; m < NMOM; ++m) mf[m] = 0.f;
    int fg = 0;
#pragma unroll
    for (int j = 0; j < 8; ++j) {
        const float gx = (uu[j+2] - uu[j]) + 2.f * (mm[j+2] - mm[j]) + (ww[j+2] - ww[j]);
        const float gy = (ww[j] - uu[j]) + 2.f * (ww[j+1] - uu[j+1]) + (ww[j+2] - uu[j+2]);
        const float gm = sqrtf(gx * gx + gy * gy + 1e-8f);
        const float lap = uu[j+1] + mm[j] + mm[j+2] + ww[j+1] - 4.f * mm[j+1];
        const float cv = tanhf(lap * 0.1f);
        const float pj = pv[j], dj = mm[j+1];
        gmn = fminf(gmn, gm); gmx = fmaxf(gmx, gm);
        dmn = fminf(dmn, dj); dmx = fmaxf(dmx, dj);
        fg += (pj > 0.5f) ? 1 : 0;
        const float et = pj - cv;
        mf[0] += pj;        mf[1] += pj * pj;
        mf[2] += gm;        mf[3] += gm * gm;   mf[4] += pj * gm;
        mf[5] += dj;        mf[6] += dj * dj;   mf[7] += pj * dj;
        mf[8] += et * et;
    }
    double mo[NMOM];
#pragma unroll
    for (int m = 0; m < NMOM; ++m) mo[m] = (double)mf[m];

    for (int o = 32; o > 0; o >>= 1) {
        gmn = fminf(gmn, __shfl_down(gmn, o));
        gmx = fmaxf(gmx, __shfl_down(gmx, o));
        dmn = fminf(dmn, __shfl_down(dmn, o));
        dmx = fmaxf(dmx, __shfl_down(dmx, o));
#pragma unroll
        for (int m = 0; m < NMOM; ++m) mo[m] += __shfl_down(mo[m], o);
        fg += __shfl_down(fg, o);
    }
    __shared__ float sg0[4], sg1[4], sd0[4], sd1[4];
    __shared__ double sa[4][NMOM];
    __shared__ int sf[4];
    const int wid = threadIdx.x >> 6, lane = threadIdx.x & 63;
    if (lane == 0) {
        sg0[wid] = gmn; sg1[wid] = gmx; sd0[wid] = dmn; sd1[wid] = dmx; sf[wid] = fg;
#pragma unroll
        for (int m = 0; m < NMOM; ++m) sa[wid][m] = mo[m];
    }
    __syncthreads();
    if (threadIdx.x == 0) {
        for (int w = 1; w < 4; ++w) {
            gmn = fminf(gmn, sg0[w]); gmx = fmaxf(gmx, sg1[w]);
            dmn = fminf(dmn, sd0[w]); dmx = fmaxf(dmx, sd1[w]);
            fg += sf[w];
#pragma unroll
            for (int m = 0; m < NMOM; ++m) mo[m] += sa[w][m];
        }
        const int bid = blockIdx.y * gridDim.x + blockIdx.x;
        pmm[bid] = make_float4(gmn, gmx, dmn, dmx);
#pragma unroll
        for (int m = 0; m < NMOM; ++m) pblk[(size_t)bid * NMOM + m] = mo[m];
        pfg[bid] = fg;
    }
}

// Stage-2 reduce (also inits per-image maxcnt). grid (IMG_B + 1 + NMOM).
__global__ void k_red(const float4* __restrict__ pmm, const double* __restrict__ pblk,
                      const int* __restrict__ pfg, Scal* s) {
    const int wid = threadIdx.x >> 6, lane = threadIdx.x & 63;
    if (blockIdx.x < IMG_B) {
        const int b = blockIdx.x;
        double ar = 0.0; int fg = 0;
        if (threadIdx.x < 128) {
            const int k = b * 128 + threadIdx.x;
            ar = pblk[(size_t)k * NMOM + 0];
            fg = pfg[k];
        }
        for (int o = 32; o > 0; o >>= 1) { ar += __shfl_down(ar, o); fg += __shfl_down(fg, o); }
        __shared__ double sa[4];
        __shared__ int sf[4];
        if (lane == 0) { sa[wid] = ar; sf[wid] = fg; }
        __syncthreads();
        if (threadIdx.x == 0) {
            ar += sa[1]; fg += sf[1];
            s->area[b] = ar; s->fgcnt[b] = fg;
            s->maxcnt[b] = 0;
        }
    } else if (blockIdx.x == IMG_B) {
        float gmn = 3.4e38f, gmx = -3.4e38f, dmn = 3.4e38f, dmx = -3.4e38f;
        for (int k = threadIdx.x; k < NPART; k += 256) {
            const float4 v = pmm[k];
            gmn = fminf(gmn, v.x); gmx = fmaxf(gmx, v.y);
            dmn = fminf(dmn, v.z); dmx = fmaxf(dmx, v.w);
        }
        for (int o = 32; o > 0; o >>= 1) {
            gmn = fminf(gmn, __shfl_down(gmn, o));
            gmx = fmaxf(gmx, __shfl_down(gmx, o));
            dmn = fminf(dmn, __shfl_down(dmn, o));
            dmx = fmaxf(dmx, __shfl_down(dmx, o));
        }
        __shared__ float sg0[4], sg1[4], sd0[4], sd1[4];
        if (lane == 0) { sg0[wid] = gmn; sg1[wid] = gmx; sd0[wid] = dmn; sd1[wid] = dmx; }
        __syncthreads();
        if (threadIdx.x == 0) {
            for (int w = 1; w < 4; ++w) {
                gmn = fminf(gmn, sg0[w]); gmx = fmaxf(gmx, sg1[w]);
                dmn = fminf(dmn, sd0[w]); dmx = fmaxf(dmx, sd1[w]);
            }
            s->gmin = gmn; s->gmax = gmx; s->dmin = dmn; s->dmax = dmx;
        }
    } else {
        const int m = blockIdx.x - IMG_B - 1;   // 0..NMOM-1
        double acc = 0.0;
        for (int k = threadIdx.x; k < NPART; k += 256) acc += pblk[(size_t)k * NMOM + m];
        for (int o = 32; o > 0; o >>= 1) acc += __shfl_down(acc, o);
        __shared__ double sa[4];
        if (lane == 0) sa[wid] = acc;
        __syncthreads();
        if (threadIdx.x == 0) {
            for (int w = 1; w < 4; ++w) acc += sa[w];
            s->mom[m] = acc;
        }
    }
}

// ---- union-find (LDS or global) ----
__device__ __forceinline__ int uf_findv(const int* L, int p) {
    while (true) { const int q = ((volatile const int*)L)[p]; if (q == p) return p; p = q; }
}
__device__ __forceinline__ void uf_merge(int* L, int a, int b) {
    while (true) {
        a = uf_findv(L, a);
        b = uf_findv(L, b);
        if (a == b) return;
        if (a < b) { int t = a; a = b; b = t; }
        const int old = atomicMin(&L[a], b);
        if (old == a) return;
        a = old;
    }
}

// ---- run bit helpers (m = 32-bit row mask, bit b set) ----
__device__ __forceinline__ int run_start(unsigned m, int b) {
    const unsigned below = ~m & ((b == 0) ? 0u : ((1u << b) - 1u));
    return below ? (int)(32u - (unsigned)__builtin_clz(below)) : 0;
}
__device__ __forceinline__ int run_len(unsigned m, int s) {
    const unsigned inv = ~(m >> s);
    return inv ? __builtin_ctz(inv) : (32 - s);
}
// index of the run containing set-bit column c (sm = run-start mask of m)
__device__ __forceinline__ int run_idx(unsigned sm, int c) {
    return __popc(sm & (unsigned)((2ull << c) - 1ull)) - 1;
}

// ring index map (124 ring px in 128 slots):
//  i in [0,32)   -> (x=i,    y=0)
//  i in [32,64)  -> (x=i-32, y=31)
//  i in [64,94)  -> (x=0,    y=i-63)   y=1..30
//  i in [94,124) -> (x=31,   y=i-93)   y=1..30
__device__ __forceinline__ void ring_decode(int i, int& x, int& y) {
    if (i < 32)      { x = i;      y = 0;      }
    else if (i < 64) { x = i - 32; y = 31;     }
    else if (i < 94) { x = 0;      y = i - 63; }
    else             { x = 31;     y = i - 93; }
}

// Run-based local CCL: ONE WAVE handles TWO horizontally adjacent 32x32 tiles
// (lanes 0-31 -> tile 2w rows, lanes 32-63 -> tile 2w+1 rows) so the divergent
// merge/count loops issue once for two tiles (previously half the wave idled).
// UF node id = half*512 + runidx*32 + row  -> LDS bank = row: each lane's own
// nodes live in its own bank (conflict-free C/D phases; B is 2-way worst).
// No barriers (wave-lockstep). grid (32, nimg), block 256 (4 waves = 8 tiles).
__global__ void k_local(const float* __restrict__ pred, int* __restrict__ Lp,
                        int* __restrict__ Cp, int* __restrict__ nslot,
                        Scal* s, int b0) {
    const int slot = blockIdx.y;
    const float* p = pred + (size_t)(b0 + slot) * IMG_HW;
    int* L = Lp + (size_t)slot * NODES_PER_IMG;
    int* C = Cp + (size_t)slot * NODES_PER_IMG;
    const int wid = threadIdx.x >> 6, lane = threadIdx.x & 63;
    const int pair = blockIdx.x * 4 + wid;      // 0..127
    const int tile0 = pair * 2;
    const int half = lane >> 5;                 // which tile of the pair
    const int tile = tile0 + half;
    const int tx = (tile & 15) * 32, ty = (tile >> 4) * 32;
    const int r = lane & 31;                    // my row (phases B-D) / my column (phase A)
    const int nbase = half * 512;

    __shared__ int lab[4][1024];
    __shared__ int lcnt[4][1024];
    __shared__ int ns[4][2];
    int* labw = lab[wid];
    int* lcw  = lcnt[wid];
    if (lane < 2) ns[wid][lane] = 0;

    // Phase A: 32 ballots; iteration k covers row k of BOTH tiles
    // (contiguous 256B load across the wave).
    unsigned m = 0u, mp = 0u;
    for (int k = 0; k < 32; ++k) {
        const float pv = p[(ty + k) * IMG_W + tx + r];
        const unsigned long long bal = __ballot(pv > 0.5f);
        const unsigned h = half ? (unsigned)(bal >> 32) : (unsigned)bal;
        if (k == r)     m  = h;
        if (k == r - 1) mp = h;
    }
    // init UF arrays (16 nodes/lane, bank = lane&31 -> 2-way, free)
#pragma unroll
    for (int k = 0; k < 16; ++k) {
        const int n = k * 64 + lane;
        labw[n] = n; lcw[n] = 0;
    }

    const unsigned sm  = m  & ~(m << 1);
    const unsigned smp = mp & ~(mp << 1);

    // Phase B: vertical merges between overlapping runs of rows r-1, r.
    if (r >= 1) {
        unsigned ov = m & mp;
        while (ov) {
            const int bpos = __builtin_ctz(ov);
            const int sa = run_start(m, bpos);
            const int ea = sa + run_len(m, sa) - 1;
            const int sb = run_start(mp, bpos);
            const int eb = sb + run_len(mp, sb) - 1;
            uf_merge(labw, nbase + run_idx(sm, sa) * 32 + r,
                            nbase + run_idx(smp, sb) * 32 + (r - 1));
            const int e = (ea < eb) ? ea : eb;
            ov = (e >= 31) ? 0u : (ov & ~((1u << (e + 1)) - 1u));
        }
    }

    // Phase C: per-run size accumulation + boundary TOUCH + path compression.
    {
        unsigned rs = sm; int j = 0;
        while (rs) {
            const int st = __builtin_ctz(rs); rs &= rs - 1;
            const int len = run_len(m, st);
            const int e = st + len - 1;
            const int node = nbase + j * 32 + r; ++j;
            const int root = uf_findv(labw, node);
            if (root != node) labw[node] = root;
            atomicAdd(&lcw[root], len);
            if (r == 0 || r == 31 || st == 0 || e == 31)
                atomicOr(&lcw[root], TOUCH);
        }
    }

    // Phase D: roots -> interior locmax, or emit packed root node.
    // Overwrites lcw[root] with the packed node id (ring phase reads it).
    int locmax = 0;
    {
        unsigned rs = sm; int j = 0;
        while (rs) {
            rs &= rs - 1;
            const int node = nbase + j * 32 + r; ++j;
            if (labw[node] != node) continue;
            const int c = lcw[node];
            if (c & TOUCH) {
                const int sl = atomicAdd(&ns[wid][half], 1);
                const int gn = tile * NODES_PER_TILE + 128 + sl;
                L[gn] = gn;
                C[gn] = c & ~TOUCH;
                lcw[node] = gn;       // root -> packed id map
            } else {
                locmax = max(locmax, c);
            }
        }
    }
    for (int o = 32; o > 0; o >>= 1) locmax = max(locmax, __shfl_down(locmax, o));

    // Ring phase: 124 entries per tile x 2 tiles (4 slots per lane).
#pragma unroll
    for (int t = 0; t < 4; ++t) {
        const int i = lane + t * 64;           // 0..255
        const int h = i >> 7, idx = i & 127;
        const int tb = (tile0 + h) * NODES_PER_TILE;
        if (idx < 124) {
            int x, yy;
            ring_decode(idx, x, yy);
            const unsigned my = (unsigned)__shfl((int)m, h * 32 + yy);
            int val = -1;
            if ((my >> x) & 1u) {
                const unsigned smy = my & ~(my << 1);
                const int node = h * 512 + run_idx(smy, x) * 32 + yy;
                const int root = uf_findv(labw, node);
                val = lcw[root];      // packed id (root is boundary-touching)
            }
            L[tb + idx] = val;
        } else {
            L[tb + idx] = -1;
        }
    }

    if (lane == 0 && locmax > 0) atomicMax(&s->maxcnt[b0 + slot], locmax);
    if (lane < 2) nslot[slot * TILES + tile0 + lane] = ns[wid][lane];
}

// Seam merges on the packed graph: 15*512*2 = 15360 edges/image.
// grid (60, nimg), block 256.
__global__ void k_bmerge(int* __restrict__ Lp) {
    const int slot = blockIdx.y;
    int* L = Lp + (size_t)slot * NODES_PER_IMG;
    const int e = blockIdx.x * 256 + threadIdx.x;
    int a, b;
    if (e < 7680) {             // vertical seam sc (0..14), y (0..511)
        const int sc = e / 512, y = e - sc * 512;
        const int ly = y & 31;
        const int tL = (y >> 5) * 16 + sc;
        const int iL = (ly == 0) ? 31 : (ly == 31) ? 63 : (93 + ly);  // (31,ly)
        const int iR = (ly == 0) ? 0  : (ly == 31) ? 32 : (63 + ly);  // (0,ly)
        a = tL * NODES_PER_TILE + iL;
        b = (tL + 1) * NODES_PER_TILE + iR;
    } else {                    // horizontal seam sr (0..14), x (0..511)
        const int e2 = e - 7680;
        const int sr = e2 / 512, x = e2 - sr * 512;
        const int lx = x & 31;
        const int tT = sr * 16 + (x >> 5);
        a = tT * NODES_PER_TILE + 32 + lx;                 // (lx,31)
        b = (tT + 16) * NODES_PER_TILE + lx;               // (lx,0)
    }
    if (L[a] >= 0 && L[b] >= 0) uf_merge(L, a, b);
}

// Flush: listed roots (slots 128..128+ns) push size to their global root.
// grid (64, nimg), block 256 -> 16384 slots/image.
__global__ void k_lflush(const int* __restrict__ Lp, int* __restrict__ Cp,
                         const int* __restrict__ nslot) {
    const int img = blockIdx.y;
    const int* L = Lp + (size_t)img * NODES_PER_IMG;
    int* C = Cp + (size_t)img * NODES_PER_IMG;
    const int sidx = blockIdx.x * 256 + threadIdx.x;
    const int tile = sidx >> 6, sl = sidx & 63;
    if (sl >= nslot[img * TILES + tile]) return;
    const int g = tile * NODES_PER_TILE + 128 + sl;
    const int rt = uf_findv(L, g);
    if (rt != g) atomicAdd(&C[rt], C[g]);
}

// Max over global roots of the packed graph.
__global__ void k_lmax(const int* __restrict__ Lp, const int* __restrict__ Cp,
                       const int* __restrict__ nslot, Scal* s, int b0) {
    const int img = blockIdx.y;
    const int* L = Lp + (size_t)img * NODES_PER_IMG;
    const int* C = Cp + (size_t)img * NODES_PER_IMG;
    const int sidx = blockIdx.x * 256 + threadIdx.x;
    const int tile = sidx >> 6, sl = sidx & 63;
    int m = 0;
    if (sl < nslot[img * TILES + tile]) {
        const int g = tile * NODES_PER_TILE + 128 + sl;
        if (L[g] == g) m = C[g];
    }
    for (int o = 32; o > 0; o >>= 1) m = max(m, __shfl_down(m, o));
    __shared__ int sm[4];
    const int wid = threadIdx.x >> 6, lane = threadIdx.x & 63;
    if (lane == 0) sm[wid] = m;
    __syncthreads();
    if (threadIdx.x == 0) {
        for (int w = 1; w < 4; ++w) m = max(m, sm[w]);
        if (m > 0) atomicMax(&s->maxcnt[b0 + img], m);
    }
}

// Final: closed-form similarity from moments + conn + scale. 1 thread.
__global__ void k_final(const Scal* __restrict__ s, float* __restrict__ out) {
    const double N = (double)IMG_B * (double)IMG_HW;
    const float gdenf = s->gmax - s->gmin + 1e-8f;
    const float ddenf = s->dmax - s->dmin + 1e-8f;
    const double a = 1.0 / (double)gdenf, bb = 1.0 / (double)ddenf;
    const double gmin = (double)s->gmin, dmin = (double)s->dmin;
    const double S_p = s->mom[0], S_pp = s->mom[1];
    const double S_g = s->mom[2], S_gg = s->mom[3], S_pg = s->mom[4];
    const double S_d = s->mom[5], S_dd = s->mom[6], S_pd = s->mom[7];
    const double S_t = s->mom[8];
    const double sum_g = S_pp - 2.0 * a * (S_pg - gmin * S_p)
                       + a * a * (S_gg - 2.0 * gmin * S_g + gmin * gmin * N);
    const double sum_d = S_pp - 2.0 * bb * (S_pd - dmin * S_p)
                       + bb * bb * (S_dd - 2.0 * dmin * S_d + dmin * dmin * N);
    const double sim = (sum_g + sum_d + S_t) / (3.0 * N);

    const double tp = (double)IMG_HW;
    const double tmin = 0.1 * tp, tmax = 0.3 * tp;
    double conn = 0.0, scale = 0.0;
    for (int b = 0; b < IMG_B; ++b) {
        const int total = s->fgcnt[b];
        if (total > 0) conn += 1.0 - (double)s->maxcnt[b] / (double)total;
        const double ar = s->area[b];
        scale += fmax(ar - tmax, 0.0) + fmax(tmin - ar, 0.0);
    }
    conn /= (double)IMG_B;
    scale = (scale / (double)IMG_B) / tp;
    const double total = sim + 0.1 * conn + 0.05 * scale;
    out[0] = (float)(0.1 * total);
}

extern "C" void kernel_launch(void* const* d_in, const int* in_sizes, int n_in,
                              void* d_out, int out_size, void* d_ws, size_t ws_size,
                              hipStream_t stream) {
    const float* pred = (const float*)d_in[0];  // [16,1,512,512]
    const float* dem  = (const float*)d_in[1];  // [16,1,512,512]
    float* out = (float*)d_out;

    char* ws = (char*)d_ws;
    Scal* s = (Scal*)ws;
    float4* pmm  = (float4*)(ws + OFF_PMM);
    double* pblk = (double*)(ws + OFF_MOM);
    int*    pfg  = (int*)(ws + OFF_FG);
    int* scratch = (int*)(ws + OFF_SCR);
    const size_t avail_ints = (ws_size > OFF_SCR) ? (ws_size - OFF_SCR) / 4 : 0;
    // per image: packed labels + packed counts + nslot
    const size_t per_img = 2ull * NODES_PER_IMG + TILES;

    hipLaunchKernelGGL(k_feat, dim3(128, IMG_B), dim3(256), 0, stream,
                       dem, pred, pmm, pblk, pfg);
    hipLaunchKernelGGL(k_red, dim3(IMG_B + 1 + NMOM), dim3(256), 0, stream, pmm, pblk, pfg, s);

    long long chunk = (long long)(avail_ints / per_img);
    if (chunk < 1) chunk = 1;
    if (chunk > IMG_B) chunk = IMG_B;
    for (int b0 = 0; b0 < IMG_B; b0 += (int)chunk) {
        const int n = (int)((b0 + chunk <= IMG_B) ? chunk : (IMG_B - b0));
        int* Lp    = scratch;
        int* Cp    = scratch + (size_t)chunk * NODES_PER_IMG;
        int* nslot = scratch + 2ull * chunk * NODES_PER_IMG;
        hipLaunchKernelGGL(k_local,  dim3(32, n), dim3(256), 0, stream,
                           pred, Lp, Cp, nslot, s, b0);
        hipLaunchKernelGGL(k_bmerge, dim3(60, n), dim3(256), 0, stream, Lp);
        hipLaunchKernelGGL(k_lflush, dim3(64, n), dim3(256), 0, stream, Lp, Cp, nslot);
        hipLaunchKernelGGL(k_lmax,   dim3(64, n), dim3(256), 0, stream, Lp, Cp, nslot, s, b0);
    }

    hipLaunchKernelGGL(k_final, dim3(1), dim3(1), 0, stream, s, out);
}